// Round 1
// baseline (2031.785 us; speedup 1.0000x reference)
//
#include <hip/hip_runtime.h>
#include <cstdint>
#include <cstddef>

#define DEV __device__ __forceinline__

namespace {

constexpr int BB   = 4;
constexpr int HWP  = 50176;   // 224*224
constexpr int NQ   = 12544;   // 112*112
constexpr int NKk  = 196;     // 14*14
constexpr int VD   = 384;
constexpr float EPS_GN  = 1e-5f;
constexpr float EPS_RMS = 1.1920929e-7f;

DEV float silu_f(float z) { return z / (1.f + __expf(-z)); }
DEV int rfl(int v) { return __builtin_amdgcn_readfirstlane(v); }

// 32-out-channel x 64-pixel GEMM, K=128. encL layout [k][64] in LDS.
// WT is K-major transposed weights [k][128] in global; c0u wave-uniform.
DEV void gemm32(float* acc, const float* encL, const float* __restrict__ WT,
                int p, int c0u) {
#pragma unroll 4
  for (int k = 0; k < 128; ++k) {
    float x = encL[k * 64 + p];
    const float* w = WT + (size_t)k * 128 + c0u;
#pragma unroll
    for (int i = 0; i < 32; ++i) acc[i] = fmaf(w[i], x, acc[i]);
  }
}

// Recompute enc (img 1x1 conv -> GN -> SiLU -> +proj skip -> RoPE) for one
// 64-pixel tile into LDS encL[128][64]. thread: p = pixel slot, cq = t>>6.
DEV void enc_tile(float* encL, const float* __restrict__ img, int b,
                  int py, int px, int p, int cq,
                  const float* sWc, const float* sWp, const float* sF,
                  const float* sMu, const float* sRs) {
  const float* ip = img + (size_t)b * 3 * HWP + py * 224 + px;
  float x0 = ip[0], x1 = ip[HWP], x2 = ip[2 * HWP];
  float gy = (py + 0.5f) * (1.f / 224.f);
  float gx = (px + 0.5f) * (1.f / 224.f);
#pragma unroll
  for (int j = 0; j < 16; ++j) {
    int d = cq * 16 + j;          // 0..63
    int c2 = d + 64;
    float y1 = sWc[d * 3] * x0 + sWc[d * 3 + 1] * x1 + sWc[d * 3 + 2] * x2;
    float s1 = sWp[d * 3] * x0 + sWp[d * 3 + 1] * x1 + sWp[d * 3 + 2] * x2;
    float y2 = sWc[c2 * 3] * x0 + sWc[c2 * 3 + 1] * x1 + sWc[c2 * 3 + 2] * x2;
    float s2 = sWp[c2 * 3] * x0 + sWp[c2 * 3 + 1] * x1 + sWp[c2 * 3 + 2] * x2;
    int g1 = d >> 4, g2 = g1 + 4;
    float t1 = silu_f((y1 - sMu[g1]) * sRs[g1]) + s1;
    float t2 = silu_f((y2 - sMu[g2]) * sRs[g2]) + s2;
    float f = sF[d];
    float sa, ca, sb, cb;
    __sincosf(gy * f, &sa, &ca);
    __sincosf(gx * f, &sb, &cb);
    encL[d * 64 + p]  = t1 * ca - t2 * sa;   // rot: t[d]cos - t[d+64]sin
    encL[c2 * 64 + p] = t2 * cb + t1 * sb;   // rot: t[d+64]cos + t[d]sin
  }
}

// ---------- small prep kernels ----------

__global__ void k_t2d(const float* __restrict__ src, float* __restrict__ dst,
                      int CO, int CI, const float* __restrict__ rowscale) {
  int idx = blockIdx.x * 256 + threadIdx.x;
  if (idx >= CO * CI) return;
  int co = idx / CI, ci = idx % CI;
  float v = src[idx];
  if (rowscale) v *= rowscale[ci];
  dst[(size_t)ci * CO + co] = v;
}

__global__ void k_tconv3(const float* __restrict__ src, float* __restrict__ dst) {
  int idx = blockIdx.x * 256 + threadIdx.x;
  if (idx >= 128 * 128 * 9) return;
  int c = idx / 1152;
  int k = (idx / 9) % 128;
  int tap = idx % 9;
  dst[((size_t)tap * 128 + k) * 128 + c] = src[idx];
}

__global__ void k_tfeat(const float* __restrict__ src, float* __restrict__ dst) {
  int idx = blockIdx.x * 256 + threadIdx.x;
  if (idx >= BB * VD * NKk) return;
  int b = idx / (VD * NKk);
  int d = (idx / NKk) % VD;
  int k = idx % NKk;
  dst[((size_t)(b * NKk) + k) * VD + d] = src[idx];
}

// ---------- image GN stats via 3x3 Gram ----------

__global__ __launch_bounds__(256) void k_imgstat1(
    const float* __restrict__ img, float* __restrict__ part) {
  __shared__ float lds[4][9];
  int b = blockIdx.x >> 6, blk = blockIdx.x & 63;
  int t = threadIdx.x;
  float a[9];
#pragma unroll
  for (int j = 0; j < 9; ++j) a[j] = 0.f;
  const float* ib = img + (size_t)b * 3 * HWP;
  for (int pix = blk * 784 + t; pix < blk * 784 + 784; pix += 256) {
    float x0 = ib[pix], x1 = ib[HWP + pix], x2 = ib[2 * HWP + pix];
    a[0] += x0; a[1] += x1; a[2] += x2;
    a[3] += x0 * x0; a[4] += x0 * x1; a[5] += x0 * x2;
    a[6] += x1 * x1; a[7] += x1 * x2; a[8] += x2 * x2;
  }
#pragma unroll
  for (int j = 0; j < 9; ++j)
    for (int m = 1; m < 64; m <<= 1) a[j] += __shfl_xor(a[j], m);
  if ((t & 63) == 0)
    for (int j = 0; j < 9; ++j) lds[t >> 6][j] = a[j];
  __syncthreads();
  if (t < 9)
    part[(size_t)blockIdx.x * 9 + t] =
        lds[0][t] + lds[1][t] + lds[2][t] + lds[3][t];
}

__global__ __launch_bounds__(128) void k_imgstat2(
    const float* __restrict__ part, const float* __restrict__ wimg,
    float* __restrict__ img_murs) {
  __shared__ float MG[9];
  int b = blockIdx.x, t = threadIdx.x;
  if (t < 9) {
    float s = 0.f;
    for (int i = 0; i < 64; ++i) s += part[(size_t)(b * 64 + i) * 9 + t];
    MG[t] = s;
  }
  __syncthreads();
  int c = t;  // 0..127
  float w0 = wimg[c * 3], w1 = wimg[c * 3 + 1], w2 = wimg[c * 3 + 2];
  float s1 = w0 * MG[0] + w1 * MG[1] + w2 * MG[2];
  float s2 = w0 * w0 * MG[3] + w1 * w1 * MG[6] + w2 * w2 * MG[8] +
             2.f * (w0 * w1 * MG[4] + w0 * w2 * MG[5] + w1 * w2 * MG[7]);
  for (int m = 1; m < 16; m <<= 1) {
    s1 += __shfl_xor(s1, m);
    s2 += __shfl_xor(s2, m);
  }
  if ((c & 15) == 0) {
    int g = c >> 4;
    float invN = 1.f / (16.f * HWP);
    float mu = s1 * invN;
    float var = s2 * invN - mu * mu;
    img_murs[b * 16 + g] = mu;
    img_murs[b * 16 + 8 + g] = rsqrtf(var + EPS_GN);
  }
}

// ---------- pass S: GN stats for q/k 1x1 convs ----------

__global__ __launch_bounds__(256) void k_passS(
    const float* __restrict__ img, const float* __restrict__ ropef,
    const float* __restrict__ wimg, const float* __restrict__ wimgp,
    const float* __restrict__ img_murs,
    const float* __restrict__ WqT, const float* __restrict__ WkT,
    float* __restrict__ Spart) {
  __shared__ float encL[128 * 64];
  __shared__ float sWc[384], sWp[384], sF[64], sMu[8], sRs[8];
  int t = threadIdx.x, p = t & 63, cq = t >> 6;
  int blk = blockIdx.x;
  int b = blk / 784, tile = blk % 784;
  for (int i = t; i < 384; i += 256) { sWc[i] = wimg[i]; sWp[i] = wimgp[i]; }
  if (t < 64) sF[t] = ropef[t];
  if (t < 8) { sMu[t] = img_murs[b * 16 + t]; sRs[t] = img_murs[b * 16 + 8 + t]; }
  __syncthreads();
  int pix = tile * 64 + p;
  int py = pix / 224, px = pix % 224;
  enc_tile(encL, img, b, py, px, p, cq, sWc, sWp, sF, sMu, sRs);
  __syncthreads();
  int c0u = rfl(cq * 32);
  for (int conv = 0; conv < 2; ++conv) {
    float acc[32];
#pragma unroll
    for (int i = 0; i < 32; ++i) acc[i] = 0.f;
    gemm32(acc, encL, conv == 0 ? WqT : WkT, p, c0u);
    float s1[2] = {0.f, 0.f}, s2[2] = {0.f, 0.f};
#pragma unroll
    for (int i = 0; i < 32; ++i) {
      int h = i >> 4;
      s1[h] += acc[i];
      s2[h] += acc[i] * acc[i];
    }
#pragma unroll
    for (int j = 0; j < 2; ++j) {
      for (int m = 1; m < 64; m <<= 1) {
        s1[j] += __shfl_xor(s1[j], m);
        s2[j] += __shfl_xor(s2[j], m);
      }
      if (p == 0) {
        int gf = conv * 32 + b * 8 + cq * 2 + j;
        Spart[((size_t)gf * 784 + tile) * 2]     = s1[j];
        Spart[((size_t)gf * 784 + tile) * 2 + 1] = s2[j];
      }
    }
  }
}

__global__ __launch_bounds__(256) void k_statfin(
    const float* __restrict__ part, float* __restrict__ murs,
    int nblk, float invN, float eps) {
  __shared__ float l1[4], l2[4];
  int g = blockIdx.x, t = threadIdx.x;
  float s1 = 0.f, s2 = 0.f;
  for (int i = t; i < nblk; i += 256) {
    s1 += part[((size_t)g * nblk + i) * 2];
    s2 += part[((size_t)g * nblk + i) * 2 + 1];
  }
  for (int m = 1; m < 64; m <<= 1) { s1 += __shfl_xor(s1, m); s2 += __shfl_xor(s2, m); }
  if ((t & 63) == 0) { l1[t >> 6] = s1; l2[t >> 6] = s2; }
  __syncthreads();
  if (t == 0) {
    float a = l1[0] + l1[1] + l1[2] + l1[3];
    float bq = l2[0] + l2[1] + l2[2] + l2[3];
    float mu = a * invN;
    float var = bq * invN - mu * mu;
    murs[g * 2] = mu;
    murs[g * 2 + 1] = rsqrtf(var + eps);
  }
}

// direct GN stats over src[b][c][P], group = 16 channels
__global__ __launch_bounds__(256) void k_gnstats(
    const float* __restrict__ src, float* __restrict__ murs, int P, float eps) {
  __shared__ float l1[4], l2[4];
  int b = blockIdx.x >> 3, g = blockIdx.x & 7, t = threadIdx.x;
  const float* base = src + ((size_t)(b * 128) + g * 16) * P;
  float s1 = 0.f, s2 = 0.f;
  for (int i = t; i < 16 * P; i += 256) {
    float v = base[i];
    s1 += v; s2 += v * v;
  }
  for (int m = 1; m < 64; m <<= 1) { s1 += __shfl_xor(s1, m); s2 += __shfl_xor(s2, m); }
  if ((t & 63) == 0) { l1[t >> 6] = s1; l2[t >> 6] = s2; }
  __syncthreads();
  if (t == 0) {
    float invN = 1.f / (16.f * (float)P);
    float a = l1[0] + l1[1] + l1[2] + l1[3];
    float bq = l2[0] + l2[1] + l2[2] + l2[3];
    float mu = a * invN;
    float var = bq * invN - mu * mu;
    murs[blockIdx.x * 2] = mu;
    murs[blockIdx.x * 2 + 1] = rsqrtf(var + eps);
  }
}

// ---------- pass A: apply q/k enc_blocks + both poolings ----------

__global__ __launch_bounds__(256) void k_passA(
    const float* __restrict__ img, const float* __restrict__ ropef,
    const float* __restrict__ wimg, const float* __restrict__ wimgp,
    const float* __restrict__ img_murs, const float* __restrict__ qk_murs,
    const float* __restrict__ WqT, const float* __restrict__ WkT,
    float* __restrict__ q_pool, float* __restrict__ k_pool) {
  __shared__ float encL[128 * 64];
  __shared__ float sWc[384], sWp[384], sF[64], sMu[8], sRs[8];
  __shared__ float sQmu[8], sQrs[8], sKmu[8], sKrs[8];
  int t = threadIdx.x, p = t & 63, cq = t >> 6;
  int blk = blockIdx.x;
  int b = blk / 196, tile = blk % 196;
  int ty = tile / 14, tx = tile % 14;
  for (int i = t; i < 384; i += 256) { sWc[i] = wimg[i]; sWp[i] = wimgp[i]; }
  if (t < 64) sF[t] = ropef[t];
  if (t < 8) {
    sMu[t] = img_murs[b * 16 + t];
    sRs[t] = img_murs[b * 16 + 8 + t];
    sQmu[t] = qk_murs[(b * 8 + t) * 2];
    sQrs[t] = qk_murs[(b * 8 + t) * 2 + 1];
    sKmu[t] = qk_murs[(32 + b * 8 + t) * 2];
    sKrs[t] = qk_murs[(32 + b * 8 + t) * 2 + 1];
  }
  int c0 = cq * 32, c0u = rfl(c0);
  float kacc[32];
#pragma unroll
  for (int i = 0; i < 32; ++i) kacc[i] = 0.f;
  for (int st = 0; st < 4; ++st) {
    __syncthreads();
    int py = ty * 16 + (st >> 1) * 8 + (p >> 3);
    int px = tx * 16 + (st & 1) * 8 + (p & 7);
    enc_tile(encL, img, b, py, px, p, cq, sWc, sWp, sF, sMu, sRs);
    __syncthreads();
    {  // q conv -> GN -> SiLU -> +skip -> 2x2 pool
      float acc[32];
#pragma unroll
      for (int i = 0; i < 32; ++i) acc[i] = 0.f;
      gemm32(acc, encL, WqT, p, c0u);
#pragma unroll
      for (int i = 0; i < 32; ++i) {
        int c = c0 + i, g = cq * 2 + (i >> 4);
        float tq = silu_f((acc[i] - sQmu[g]) * sQrs[g]) + encL[c * 64 + p];
        float t2 = tq + __shfl_xor(tq, 1);
        float t4 = t2 + __shfl_xor(t2, 8);
        if ((p & 9) == 0)
          q_pool[(size_t)(b * 128 + c) * NQ + (py >> 1) * 112 + (px >> 1)] =
              t4 * 0.25f;
      }
    }
    {  // k conv -> GN -> SiLU -> +skip -> accumulate 16x16 pool
      float acc[32];
#pragma unroll
      for (int i = 0; i < 32; ++i) acc[i] = 0.f;
      gemm32(acc, encL, WkT, p, c0u);
#pragma unroll
      for (int i = 0; i < 32; ++i) {
        int c = c0 + i, g = cq * 2 + (i >> 4);
        kacc[i] += silu_f((acc[i] - sKmu[g]) * sKrs[g]) + encL[c * 64 + p];
      }
    }
  }
#pragma unroll
  for (int i = 0; i < 32; ++i) {
    float v = kacc[i];
    for (int m = 1; m < 64; m <<= 1) v += __shfl_xor(v, m);
    if (p == 0)
      k_pool[(size_t)(b * 128 + c0 + i) * NKk + ty * 14 + tx] = v * (1.f / 256.f);
  }
}

// ---------- features L2 normalize ----------

__global__ void k_fn(const float* __restrict__ feat, float* __restrict__ fn) {
  int b = blockIdx.x, p = threadIdx.x;
  if (p >= NKk) return;
  const float* fb = feat + (size_t)b * VD * NKk + p;
  float s = 0.f;
  for (int c = 0; c < VD; ++c) { float v = fb[c * NKk]; s += v * v; }
  float r = rsqrtf(fmaxf(s, 1e-24f));
  float* ob = fn + (size_t)b * VD * NKk + p;
  for (int c = 0; c < VD; ++c) ob[c * NKk] = fb[c * NKk] * r;
}

// ---------- kf enc_block conv (384->128, conv + proj skip) ----------

__global__ __launch_bounds__(256) void k_kfconv(
    const float* __restrict__ fn, const float* __restrict__ KFT,
    const float* __restrict__ KFPT,
    float* __restrict__ y_kf, float* __restrict__ skip_kf) {
  __shared__ float fnL[192 * 64];
  int t = threadIdx.x, p = t & 63, cq = t >> 6;
  int b = blockIdx.x >> 2, tile = blockIdx.x & 3;
  int p0 = tile * 49;
  int c0 = cq * 32, c0u = rfl(c0);
  float accy[32], accs[32];
#pragma unroll
  for (int i = 0; i < 32; ++i) { accy[i] = 0.f; accs[i] = 0.f; }
  for (int ch = 0; ch < 2; ++ch) {
    __syncthreads();
    for (int i = t; i < 192 * 64; i += 256) {
      int kk = i >> 6, pp = i & 63;
      float v = 0.f;
      if (pp < 49) v = fn[((size_t)(b * 384) + ch * 192 + kk) * NKk + p0 + pp];
      fnL[i] = v;
    }
    __syncthreads();
#pragma unroll 2
    for (int k = 0; k < 192; ++k) {
      float x = fnL[k * 64 + p];
      const float* wy = KFT  + ((size_t)(ch * 192 + k)) * 128 + c0u;
      const float* wsk = KFPT + ((size_t)(ch * 192 + k)) * 128 + c0u;
#pragma unroll
      for (int i = 0; i < 32; ++i) {
        accy[i] = fmaf(wy[i], x, accy[i]);
        accs[i] = fmaf(wsk[i], x, accs[i]);
      }
    }
  }
  if (p < 49) {
#pragma unroll
    for (int i = 0; i < 32; ++i) {
      size_t off = (size_t)(b * 128 + c0 + i) * NKk + p0 + p;
      y_kf[off] = accy[i];
      skip_kf[off] = accs[i];
    }
  }
}

// ---------- SFT: k_final = gamma(kf)*GN(k_pool) + beta(kf) ----------

__global__ __launch_bounds__(256) void k_sft(
    const float* __restrict__ y_kf, const float* __restrict__ skip_kf,
    const float* __restrict__ kf_murs, const float* __restrict__ GT,
    const float* __restrict__ BT, const float* __restrict__ k_pool,
    const float* __restrict__ kgn_murs, float* __restrict__ k_final) {
  __shared__ float kfL[128 * 64];
  __shared__ float sMu[8], sRs[8], sGmu[8], sGrs[8];
  int t = threadIdx.x, p = t & 63, cq = t >> 6;
  int b = blockIdx.x >> 2, tile = blockIdx.x & 3;
  int p0 = tile * 49;
  if (t < 8) {
    sMu[t] = kf_murs[(b * 8 + t) * 2];
    sRs[t] = kf_murs[(b * 8 + t) * 2 + 1];
    sGmu[t] = kgn_murs[(b * 8 + t) * 2];
    sGrs[t] = kgn_murs[(b * 8 + t) * 2 + 1];
  }
  __syncthreads();
  for (int i = t; i < 128 * 64; i += 256) {
    int c = i >> 6, pp = i & 63;
    float v = 0.f;
    if (pp < 49) {
      size_t off = (size_t)(b * 128 + c) * NKk + p0 + pp;
      int g = c >> 4;
      v = silu_f((y_kf[off] - sMu[g]) * sRs[g]) + skip_kf[off];
    }
    kfL[i] = v;
  }
  __syncthreads();
  int c0 = cq * 32, c0u = rfl(c0);
  float ag[32], ab[32];
#pragma unroll
  for (int i = 0; i < 32; ++i) { ag[i] = 0.f; ab[i] = 0.f; }
  gemm32(ag, kfL, GT, p, c0u);
  gemm32(ab, kfL, BT, p, c0u);
  if (p < 49) {
#pragma unroll
    for (int i = 0; i < 32; ++i) {
      int c = c0 + i, g = c >> 4;
      size_t off = (size_t)(b * 128 + c) * NKk + p0 + p;
      float kn = (k_pool[off] - sGmu[g]) * sGrs[g];
      k_final[off] = fmaf(ag[i], kn, ab[i]);
    }
  }
}

// ---------- 3x3 conv on (GN-normalized) pooled q ----------

__global__ __launch_bounds__(256) void k_conv3(
    const float* __restrict__ q_pool, const float* __restrict__ murs2,
    const float* __restrict__ WT3, float* __restrict__ qconv) {
  __shared__ float inL[128 * 104];
  __shared__ float sMu[8], sRs[8];
  int t = threadIdx.x;
  int blk = blockIdx.x;
  int b = blk / 196, tile = blk % 196;
  int oy = (tile / 14) * 8, ox = (tile % 14) * 8;
  if (t < 8) { sMu[t] = murs2[(b * 8 + t) * 2]; sRs[t] = murs2[(b * 8 + t) * 2 + 1]; }
  __syncthreads();
  for (int idx = t; idx < 128 * 100; idx += 256) {
    int k = idx / 100, r = idx % 100;
    int iy = oy + r / 10 - 1, ix = ox + r % 10 - 1;
    float v = 0.f;
    if (iy >= 0 && iy < 112 && ix >= 0 && ix < 112) {
      v = q_pool[(size_t)(b * 128 + k) * NQ + iy * 112 + ix];
      int g = k >> 4;
      v = (v - sMu[g]) * sRs[g];
    }
    inL[k * 104 + r] = v;
  }
  __syncthreads();
  int p = t & 63, cq = t >> 6;
  int c0 = cq * 32, c0u = rfl(c0);
  int py = p >> 3, px = p & 7;
  float acc[32];
#pragma unroll
  for (int i = 0; i < 32; ++i) acc[i] = 0.f;
  for (int tap = 0; tap < 9; ++tap) {
    int base = (py + tap / 3) * 10 + (px + tap % 3);
    const float* wt = WT3 + (size_t)tap * 16384 + c0u;
#pragma unroll 2
    for (int k = 0; k < 128; ++k) {
      float x = inL[k * 104 + base];
      const float* w = wt + (size_t)k * 128;
#pragma unroll
      for (int i = 0; i < 32; ++i) acc[i] = fmaf(w[i], x, acc[i]);
    }
  }
#pragma unroll
  for (int i = 0; i < 32; ++i)
    qconv[(size_t)(b * 128 + c0 + i) * NQ + (oy + py) * 112 + ox + px] = acc[i];
}

// ---------- RMSNorm + projection (q and k) ----------

__global__ __launch_bounds__(256) void k_rmsproj(
    const float* __restrict__ src, const float* __restrict__ WTs,
    const float* __restrict__ bias, float* __restrict__ dst, int NP) {
  __shared__ float xL[128 * 64];
  __shared__ float msP[4][64];
  int t = threadIdx.x, p = t & 63, cq = t >> 6;
  int nt = (NP + 63) / 64;
  int b = blockIdx.x / nt, tile = blockIdx.x % nt;
  int p0 = tile * 64;
  float ss = 0.f;
#pragma unroll
  for (int i = 0; i < 32; ++i) {
    int c = cq * 32 + i;
    float v = (p0 + p < NP) ? src[(size_t)(b * 128 + c) * NP + p0 + p] : 0.f;
    xL[c * 64 + p] = v;
    ss += v * v;
  }
  msP[cq][p] = ss;
  __syncthreads();
  float ms = (msP[0][p] + msP[1][p] + msP[2][p] + msP[3][p]) * (1.f / 128.f);
  float rr = rsqrtf(ms + EPS_RMS);
  int c0u = rfl(cq * 32);
  float acc[32];
#pragma unroll
  for (int i = 0; i < 32; ++i) acc[i] = 0.f;
  gemm32(acc, xL, WTs, p, c0u);
  if (p0 + p < NP) {
#pragma unroll
    for (int i = 0; i < 32; ++i)
      dst[((size_t)b * NP + p0 + p) * 128 + c0u + i] = acc[i] * rr + bias[c0u + i];
  }
}

// ---------- attention: head-avg softmax weights ----------

__global__ __launch_bounds__(256) void k_attn1(
    const float* __restrict__ qp, const float* __restrict__ kp,
    float* __restrict__ attn) {
  __shared__ float sS[4][8][208];
  __shared__ float sA[32][208];
  int t = threadIdx.x, lane = t & 63, w = t >> 6;
  int b = blockIdx.x / 392, qt = blockIdx.x % 392;
  int q0 = qt * 32;
  int wu = rfl(w);
  for (int i = t; i < 32 * 208; i += 256) (&sA[0][0])[i] = 0.f;
  __syncthreads();
  for (int h = 0; h < 4; ++h) {
    for (int j = 0; j < 4; ++j) {
      int k = j * 64 + lane;
      float kr[32];
      if (k < 196) {
        const float4* k4 =
            (const float4*)(kp + (size_t)(b * NKk + k) * 128 + h * 32);
#pragma unroll
        for (int i = 0; i < 8; ++i) {
          float4 v = k4[i];
          kr[i * 4] = v.x; kr[i * 4 + 1] = v.y;
          kr[i * 4 + 2] = v.z; kr[i * 4 + 3] = v.w;
        }
      } else {
#pragma unroll
        for (int i = 0; i < 32; ++i) kr[i] = 0.f;
      }
      for (int q = 0; q < 8; ++q) {
        const float* qrow =
            qp + ((size_t)b * NQ + q0 + wu * 8 + q) * 128 + h * 32;
        float s = 0.f;
#pragma unroll
        for (int i = 0; i < 32; ++i) s = fmaf(qrow[i], kr[i], s);
        if (k < 196) sS[wu][q][k] = s * 0.17677669529663687f;  // 1/sqrt(32)
      }
    }
    for (int q = 0; q < 8; ++q) {
      float s0 = sS[wu][q][lane];
      float s1v = sS[wu][q][lane + 64];
      float s2v = sS[wu][q][lane + 128];
      float s3v = (lane < 4) ? sS[wu][q][lane + 192] : -3.0e38f;
      float m = fmaxf(fmaxf(s0, s1v), fmaxf(s2v, s3v));
      for (int mm = 1; mm < 64; mm <<= 1) m = fmaxf(m, __shfl_xor(m, mm));
      float e0 = __expf(s0 - m), e1 = __expf(s1v - m), e2 = __expf(s2v - m);
      float e3 = (lane < 4) ? __expf(s3v - m) : 0.f;
      float sum = e0 + e1 + e2 + e3;
      for (int mm = 1; mm < 64; mm <<= 1) sum += __shfl_xor(sum, mm);
      float inv = 0.25f / sum;
      int qg = wu * 8 + q;
      sA[qg][lane]       += e0 * inv;
      sA[qg][lane + 64]  += e1 * inv;
      sA[qg][lane + 128] += e2 * inv;
      if (lane < 4) sA[qg][lane + 192] += e3 * inv;
    }
  }
  __syncthreads();
  for (int i = t; i < 32 * 196; i += 256) {
    int q = i / 196, k = i % 196;
    attn[((size_t)b * NQ + q0 + q) * 196 + k] = sA[q][k];
  }
}

// ---------- attention PV: out[b][d][q] = sum_k attn[q][k] * featT[k][d] ----------

__global__ __launch_bounds__(256) void k_attn2(
    const float* __restrict__ attn, const float* __restrict__ featT,
    float* __restrict__ out) {
  __shared__ float aL[196 * 69];
  int t = threadIdx.x, p = t & 63, w = t >> 6;
  int b = blockIdx.x / 196, qt = blockIdx.x % 196;
  int q0 = qt * 64;
  for (int i = t; i < 64 * 196; i += 256) {
    int r = i / 196, k = i % 196;
    aL[k * 69 + r] = attn[((size_t)b * NQ + q0 + r) * 196 + k];
  }
  __syncthreads();
  int wu = rfl(w);
  for (int dc = 0; dc < 3; ++dc) {
    int d0 = (dc * 4 + wu) * 32;
    float acc[32];
#pragma unroll
    for (int i = 0; i < 32; ++i) acc[i] = 0.f;
#pragma unroll 2
    for (int k = 0; k < 196; ++k) {
      float x = aL[k * 69 + p];
      const float* v = featT + (size_t)(b * NKk + k) * VD + d0;
#pragma unroll
      for (int i = 0; i < 32; ++i) acc[i] = fmaf(v[i], x, acc[i]);
    }
#pragma unroll
    for (int i = 0; i < 32; ++i)
      out[((size_t)(b * VD) + d0 + i) * NQ + q0 + p] = acc[i];
  }
}

}  // namespace

extern "C" void kernel_launch(void* const* d_in, const int* in_sizes, int n_in,
                              void* d_out, int out_size, void* d_ws,
                              size_t ws_size, hipStream_t stream) {
  (void)in_sizes; (void)n_in; (void)out_size; (void)ws_size;
  const float* image        = (const float*)d_in[0];
  const float* features     = (const float*)d_in[1];
  const float* rope_f       = (const float*)d_in[2];
  const float* img_conv_w   = (const float*)d_in[3];
  const float* img_proj_w   = (const float*)d_in[4];
  const float* qenc_w       = (const float*)d_in[5];
  const float* kenc_w       = (const float*)d_in[6];
  const float* kfeat_conv_w = (const float*)d_in[7];
  const float* kfeat_proj_w = (const float*)d_in[8];
  const float* sft_gamma_w  = (const float*)d_in[9];
  const float* sft_beta_w   = (const float*)d_in[10];
  const float* block_conv_w = (const float*)d_in[11];
  const float* rms_q_w      = (const float*)d_in[12];
  const float* rms_k_w      = (const float*)d_in[13];
  const float* q_proj_w     = (const float*)d_in[14];
  const float* q_proj_b     = (const float*)d_in[15];
  const float* k_proj_w     = (const float*)d_in[16];
  const float* k_proj_b     = (const float*)d_in[17];
  float* out = (float*)d_out;
  float* ws = (float*)d_ws;

  size_t off = 0;
  auto alloc = [&](size_t n) {
    size_t r = off;
    off += (n + 63) & ~(size_t)63;
    return r;
  };
  float* WqT      = ws + alloc(16384);
  float* WkT      = ws + alloc(16384);
  float* GT       = ws + alloc(16384);
  float* BT       = ws + alloc(16384);
  float* QPT      = ws + alloc(16384);
  float* KPT      = ws + alloc(16384);
  float* KFT      = ws + alloc(49152);
  float* KFPT     = ws + alloc(49152);
  float* WT3      = ws + alloc(147456);
  float* featT    = ws + alloc((size_t)BB * VD * NKk);
  float* imgpart  = ws + alloc(BB * 64 * 9);
  float* img_murs = ws + alloc(64);
  float* Spart    = ws + alloc((size_t)64 * 784 * 2);
  float* qk_murs  = ws + alloc(128);
  float* murs2    = ws + alloc(64);
  float* kgn_murs = ws + alloc(64);
  float* kf_murs  = ws + alloc(64);
  float* fnb      = ws + alloc((size_t)BB * VD * NKk);
  float* y_kf     = ws + alloc((size_t)BB * 128 * NKk);
  float* skip_kf  = ws + alloc((size_t)BB * 128 * NKk);
  float* k_final  = ws + alloc((size_t)BB * 128 * NKk);
  float* k_pool   = ws + alloc((size_t)BB * 128 * NKk);
  float* kpb      = ws + alloc((size_t)BB * NKk * 128);
  float* R1       = ws + alloc((size_t)BB * 128 * NQ);   // q_pool, then qp
  float* R2       = ws + alloc((size_t)BB * NQ * 196);   // qconv, then attn
  // total ~71.2 MB of workspace

  // weight transposes
  k_t2d<<<64, 256, 0, stream>>>(qenc_w, WqT, 128, 128, (const float*)nullptr);
  k_t2d<<<64, 256, 0, stream>>>(kenc_w, WkT, 128, 128, (const float*)nullptr);
  k_t2d<<<64, 256, 0, stream>>>(sft_gamma_w, GT, 128, 128, (const float*)nullptr);
  k_t2d<<<64, 256, 0, stream>>>(sft_beta_w, BT, 128, 128, (const float*)nullptr);
  k_t2d<<<64, 256, 0, stream>>>(q_proj_w, QPT, 128, 128, rms_q_w);
  k_t2d<<<64, 256, 0, stream>>>(k_proj_w, KPT, 128, 128, rms_k_w);
  k_t2d<<<192, 256, 0, stream>>>(kfeat_conv_w, KFT, 128, 384, (const float*)nullptr);
  k_t2d<<<192, 256, 0, stream>>>(kfeat_proj_w, KFPT, 128, 384, (const float*)nullptr);
  k_tconv3<<<576, 256, 0, stream>>>(block_conv_w, WT3);
  k_tfeat<<<1176, 256, 0, stream>>>(features, featT);

  // image GN stats (Gram trick)
  k_imgstat1<<<BB * 64, 256, 0, stream>>>(image, imgpart);
  k_imgstat2<<<BB, 128, 0, stream>>>(imgpart, img_conv_w, img_murs);

  // q/k enc_block GN stats over full res
  k_passS<<<BB * 784, 256, 0, stream>>>(image, rope_f, img_conv_w, img_proj_w,
                                        img_murs, WqT, WkT, Spart);
  k_statfin<<<64, 256, 0, stream>>>(Spart, qk_murs, 784, 1.f / 802816.f, EPS_GN);

  // apply q/k enc_blocks + pooling
  k_passA<<<BB * 196, 256, 0, stream>>>(image, rope_f, img_conv_w, img_proj_w,
                                        img_murs, qk_murs, WqT, WkT, R1, k_pool);

  // pooled-q GN stats; k_pool GN stats
  k_gnstats<<<32, 256, 0, stream>>>(R1, murs2, NQ, EPS_GN);
  k_gnstats<<<32, 256, 0, stream>>>(k_pool, kgn_murs, NKk, EPS_GN);

  // kf branch
  k_fn<<<BB, 256, 0, stream>>>(features, fnb);
  k_kfconv<<<BB * 4, 256, 0, stream>>>(fnb, KFT, KFPT, y_kf, skip_kf);
  k_gnstats<<<32, 256, 0, stream>>>(y_kf, kf_murs, NKk, EPS_GN);
  k_sft<<<BB * 4, 256, 0, stream>>>(y_kf, skip_kf, kf_murs, GT, BT, k_pool,
                                    kgn_murs, k_final);
  k_rmsproj<<<BB * 4, 256, 0, stream>>>(k_final, KPT, k_proj_b, kpb, NKk);

  // q branch: 3x3 conv (with GN fused on load), RMS+proj
  k_conv3<<<BB * 196, 256, 0, stream>>>(R1, murs2, WT3, R2);
  k_rmsproj<<<BB * 196, 256, 0, stream>>>(R2, QPT, q_proj_b, R1, NQ);

  // attention
  k_attn1<<<BB * 392, 256, 0, stream>>>(R1, kpb, R2);
  k_attn2<<<BB * 196, 256, 0, stream>>>(R2, featT, out);
}

// Round 2
// 1097.924 us; speedup vs baseline: 1.8506x; 1.8506x over previous
//
#include <hip/hip_runtime.h>
#include <cstdint>
#include <cstddef>

#define DEV __device__ __forceinline__

namespace {

constexpr int BB   = 4;
constexpr int HWP  = 50176;   // 224*224
constexpr int NQ   = 12544;   // 112*112
constexpr int NKk  = 196;     // 14*14
constexpr int VD   = 384;
constexpr float EPS_GN  = 1e-5f;
constexpr float EPS_RMS = 1.1920929e-7f;

typedef __attribute__((ext_vector_type(4))) float f32x4;
typedef __attribute__((ext_vector_type(4))) _Float16 h16x4;

DEV float silu_f(float z) { return z / (1.f + __expf(-z)); }
DEV int rfl(int v) { return __builtin_amdgcn_readfirstlane(v); }

DEV f32x4 mfma16(h16x4 a, h16x4 b, f32x4 c) {
  return __builtin_amdgcn_mfma_f32_16x16x16f16(a, b, c, 0, 0, 0);
}

// fp32 scalar-broadcast GEMM for the small k-branch kernels (K=128, 64 px)
DEV void gemm32(float* acc, const float* encL, const float* __restrict__ WT,
                int p, int c0u) {
#pragma unroll 4
  for (int k = 0; k < 128; ++k) {
    float x = encL[k * 64 + p];
    const float* w = WT + (size_t)k * 128 + c0u;
#pragma unroll
    for (int i = 0; i < 32; ++i) acc[i] = fmaf(w[i], x, acc[i]);
  }
}

// Recompute enc (img 1x1 conv -> GN -> SiLU -> +proj skip -> RoPE) for one
// 64-pixel tile into LDS encL[64][132] f32 (pixel-major, padded).
// thread: p = pixel slot (t&63), cq = t>>6.
DEV void enc_tile(float* encL, const float* __restrict__ img, int b,
                  int py, int px, int p, int cq,
                  const float* sWc, const float* sWp, const float* sF,
                  const float* sMu, const float* sRs) {
  const float* ip = img + (size_t)b * 3 * HWP + py * 224 + px;
  float x0 = ip[0], x1 = ip[HWP], x2 = ip[2 * HWP];
  float gy = (py + 0.5f) * (1.f / 224.f);
  float gx = (px + 0.5f) * (1.f / 224.f);
#pragma unroll
  for (int jj = 0; jj < 4; ++jj) {
    f32x4 lo, hi;
#pragma unroll
    for (int u = 0; u < 4; ++u) {
      int d = cq * 16 + jj * 4 + u;
      int c2 = d + 64;
      float y1 = sWc[d * 3] * x0 + sWc[d * 3 + 1] * x1 + sWc[d * 3 + 2] * x2;
      float s1 = sWp[d * 3] * x0 + sWp[d * 3 + 1] * x1 + sWp[d * 3 + 2] * x2;
      float y2 = sWc[c2 * 3] * x0 + sWc[c2 * 3 + 1] * x1 + sWc[c2 * 3 + 2] * x2;
      float s2 = sWp[c2 * 3] * x0 + sWp[c2 * 3 + 1] * x1 + sWp[c2 * 3 + 2] * x2;
      int g1 = d >> 4, g2 = g1 + 4;
      float t1 = silu_f((y1 - sMu[g1]) * sRs[g1]) + s1;
      float t2 = silu_f((y2 - sMu[g2]) * sRs[g2]) + s2;
      float f = sF[d];
      float sa, ca, sb, cb;
      __sincosf(gy * f, &sa, &ca);
      __sincosf(gx * f, &sb, &cb);
      lo[u] = t1 * ca - t2 * sa;
      hi[u] = t2 * cb + t1 * sb;
    }
    *(f32x4*)(encL + p * 132 + cq * 16 + jj * 4) = lo;
    *(f32x4*)(encL + p * 132 + 64 + cq * 16 + jj * 4) = hi;
  }
}

// ---------- weight prep ----------

// transpose [CO][CI] -> [CI][CO] f32 (with optional per-ci scale)
__global__ void k_t2d(const float* __restrict__ src, float* __restrict__ dst,
                      int CO, int CI, const float* __restrict__ rowscale) {
  int idx = blockIdx.x * 256 + threadIdx.x;
  if (idx >= CO * CI) return;
  int co = idx / CI, ci = idx % CI;
  float v = src[idx];
  if (rowscale) v *= rowscale[ci];
  dst[(size_t)ci * CO + co] = v;
}

// pack [CO=128][CI=128] into MFMA B-frag order (fp16):
// dst[((kt*8 + ct)*64 + l)*4 + j] = W[ct*16 + (l&15)][kt*16 + 4*(l>>4)+j]
__global__ void k_pack16(const float* __restrict__ W, _Float16* __restrict__ dst,
                         const float* __restrict__ rowscale) {
  int id = blockIdx.x * 256 + threadIdx.x;
  if (id >= 16384) return;
  int j = id & 3, l = (id >> 2) & 63, tile = id >> 8;
  int ct = tile & 7, kt = tile >> 3;
  int ci = kt * 16 + 4 * (l >> 4) + j;
  int co = ct * 16 + (l & 15);
  float v = W[(size_t)co * 128 + ci];
  if (rowscale) v *= rowscale[ci];
  dst[id] = (_Float16)v;
}

// pack 3x3 conv weights [co][ci][3][3] per-tap into frag order
__global__ void k_packw3(const float* __restrict__ W, _Float16* __restrict__ dst) {
  int id = blockIdx.x * 256 + threadIdx.x;
  if (id >= 9 * 16384) return;
  int j = id & 3, l = (id >> 2) & 63, tile = (id >> 8) & 63, tap = id >> 14;
  int ct = tile & 7, kt = tile >> 3;
  int ci = kt * 16 + 4 * (l >> 4) + j;
  int co = ct * 16 + (l & 15);
  dst[id] = (_Float16)W[((size_t)co * 128 + ci) * 9 + tap];
}

// ---------- image GN stats via 3x3 Gram ----------

__global__ __launch_bounds__(256) void k_imgstat1(
    const float* __restrict__ img, float* __restrict__ part) {
  __shared__ float lds[4][9];
  int b = blockIdx.x >> 6, blk = blockIdx.x & 63;
  int t = threadIdx.x;
  float a[9];
#pragma unroll
  for (int j = 0; j < 9; ++j) a[j] = 0.f;
  const float* ib = img + (size_t)b * 3 * HWP;
  for (int pix = blk * 784 + t; pix < blk * 784 + 784; pix += 256) {
    float x0 = ib[pix], x1 = ib[HWP + pix], x2 = ib[2 * HWP + pix];
    a[0] += x0; a[1] += x1; a[2] += x2;
    a[3] += x0 * x0; a[4] += x0 * x1; a[5] += x0 * x2;
    a[6] += x1 * x1; a[7] += x1 * x2; a[8] += x2 * x2;
  }
#pragma unroll
  for (int j = 0; j < 9; ++j)
    for (int m = 1; m < 64; m <<= 1) a[j] += __shfl_xor(a[j], m);
  if ((t & 63) == 0)
    for (int j = 0; j < 9; ++j) lds[t >> 6][j] = a[j];
  __syncthreads();
  if (t < 9)
    part[(size_t)blockIdx.x * 9 + t] =
        lds[0][t] + lds[1][t] + lds[2][t] + lds[3][t];
}

__global__ __launch_bounds__(128) void k_imgstat2(
    const float* __restrict__ part, const float* __restrict__ wimg,
    float* __restrict__ img_murs) {
  __shared__ float MG[9];
  int b = blockIdx.x, t = threadIdx.x;
  if (t < 9) {
    float s = 0.f;
    for (int i = 0; i < 64; ++i) s += part[(size_t)(b * 64 + i) * 9 + t];
    MG[t] = s;
  }
  __syncthreads();
  int c = t;
  float w0 = wimg[c * 3], w1 = wimg[c * 3 + 1], w2 = wimg[c * 3 + 2];
  float s1 = w0 * MG[0] + w1 * MG[1] + w2 * MG[2];
  float s2 = w0 * w0 * MG[3] + w1 * w1 * MG[6] + w2 * w2 * MG[8] +
             2.f * (w0 * w1 * MG[4] + w0 * w2 * MG[5] + w1 * w2 * MG[7]);
  for (int m = 1; m < 16; m <<= 1) {
    s1 += __shfl_xor(s1, m);
    s2 += __shfl_xor(s2, m);
  }
  if ((c & 15) == 0) {
    int g = c >> 4;
    float invN = 1.f / (16.f * HWP);
    float mu = s1 * invN;
    float var = s2 * invN - mu * mu;
    img_murs[b * 16 + g] = mu;
    img_murs[b * 16 + 8 + g] = rsqrtf(var + EPS_GN);
  }
}

// ---------- Gram of enc (replaces old pass S) ----------

__global__ __launch_bounds__(256) void k_gram(
    const float* __restrict__ img, const float* __restrict__ ropef,
    const float* __restrict__ wimg, const float* __restrict__ wimgp,
    const float* __restrict__ img_murs,
    float* __restrict__ Gpart, float* __restrict__ mpart) {
  __shared__ __align__(16) float encL[64 * 132];
  __shared__ float sWc[384], sWp[384], sF[64], sMu[8], sRs[8];
  int t = threadIdx.x, l = t & 63, w = t >> 6;
  int b = blockIdx.x / 49, blk = blockIdx.x % 49;
  for (int i = t; i < 384; i += 256) { sWc[i] = wimg[i]; sWp[i] = wimgp[i]; }
  if (t < 64) sF[t] = ropef[t];
  if (t < 8) { sMu[t] = img_murs[b * 16 + t]; sRs[t] = img_murs[b * 16 + 8 + t]; }
  f32x4 acc[2][8];
  f32x4 macc[2];
  f32x4 z = {0.f, 0.f, 0.f, 0.f};
#pragma unroll
  for (int e = 0; e < 2; ++e) {
    macc[e] = z;
#pragma unroll
    for (int nt = 0; nt < 8; ++nt) acc[e][nt] = z;
  }
  h16x4 hone = {(_Float16)1.f, (_Float16)1.f, (_Float16)1.f, (_Float16)1.f};
  for (int s = 0; s < 16; ++s) {
    __syncthreads();
    int pix = (blk * 16 + s) * 64 + l;
    int py = pix / 224, px = pix % 224;
    enc_tile(encL, img, b, py, px, l, w, sWc, sWp, sF, sMu, sRs);
    __syncthreads();
#pragma unroll
    for (int kt = 0; kt < 4; ++kt) {
      int pb = kt * 16 + 4 * (l >> 4);
      h16x4 a[2];
#pragma unroll
      for (int e = 0; e < 2; ++e) {
        int c = (2 * w + e) * 16 + (l & 15);
        h16x4 av;
#pragma unroll
        for (int j = 0; j < 4; ++j) av[j] = (_Float16)encL[(pb + j) * 132 + c];
        a[e] = av;
        macc[e] = mfma16(av, hone, macc[e]);
      }
#pragma unroll
      for (int nt = 0; nt < 8; ++nt) {
        int c = nt * 16 + (l & 15);
        h16x4 bv;
#pragma unroll
        for (int j = 0; j < 4; ++j) bv[j] = (_Float16)encL[(pb + j) * 132 + c];
        acc[0][nt] = mfma16(a[0], bv, acc[0][nt]);
        acc[1][nt] = mfma16(a[1], bv, acc[1][nt]);
      }
    }
  }
  float* gp = Gpart + (size_t)(b * 49 + blk) * 16384;
#pragma unroll
  for (int e = 0; e < 2; ++e)
#pragma unroll
    for (int nt = 0; nt < 8; ++nt)
#pragma unroll
      for (int r = 0; r < 4; ++r) {
        int row = (2 * w + e) * 16 + 4 * (l >> 4) + r;
        int col = nt * 16 + (l & 15);
        gp[row * 128 + col] = acc[e][nt][r];
      }
  if ((l & 15) == 0) {
    float* mp = mpart + (size_t)(b * 49 + blk) * 128;
#pragma unroll
    for (int e = 0; e < 2; ++e)
#pragma unroll
      for (int r = 0; r < 4; ++r)
        mp[(2 * w + e) * 16 + 4 * (l >> 4) + r] = macc[e][r];
  }
}

__global__ void k_gred(const float* __restrict__ Gpart,
                       const float* __restrict__ mpart,
                       float* __restrict__ G, float* __restrict__ mvec) {
  int b = blockIdx.x >> 6, chunk = blockIdx.x & 63;
  int idx = chunk * 256 + threadIdx.x;
  float s = 0.f;
  for (int i = 0; i < 49; ++i) s += Gpart[(size_t)(b * 49 + i) * 16384 + idx];
  G[(size_t)b * 16384 + idx] = s;
  if (idx < 128) {
    float sm = 0.f;
    for (int i = 0; i < 49; ++i) sm += mpart[(size_t)(b * 49 + i) * 128 + idx];
    mvec[b * 128 + idx] = sm;
  }
}

// stats for q/k 1x1 convs from Gram: E[y]=w.m, E[y^2]=w^T G w
__global__ __launch_bounds__(256) void k_gstats(
    const float* __restrict__ G, const float* __restrict__ mvec,
    const float* __restrict__ qw, const float* __restrict__ kw,
    float* __restrict__ qk_murs) {
  __shared__ float red1[4], red2[4];
  int bi = blockIdx.x;               // conv*32 + b*8 + g
  int conv = bi >> 5, b = (bi >> 3) & 3, g = bi & 7;
  const float* W = conv ? kw : qw;
  int t = threadIdx.x;
  int c = g * 16 + (t >> 4);
  int i0 = (t & 15) * 8;
  const float* wc = W + (size_t)c * 128;
  const float* Gb = G + (size_t)b * 16384;
  const float* mb = mvec + b * 128;
  float s1 = 0.f, s2 = 0.f;
  for (int i = i0; i < i0 + 8; ++i) {
    float gi = 0.f;
    for (int j = 0; j < 128; ++j) gi += Gb[i * 128 + j] * wc[j];
    s2 += wc[i] * gi;
    s1 += wc[i] * mb[i];
  }
  for (int m = 1; m < 64; m <<= 1) { s1 += __shfl_xor(s1, m); s2 += __shfl_xor(s2, m); }
  if ((t & 63) == 0) { red1[t >> 6] = s1; red2[t >> 6] = s2; }
  __syncthreads();
  if (t == 0) {
    float S1 = red1[0] + red1[1] + red1[2] + red1[3];
    float S2 = red2[0] + red2[1] + red2[2] + red2[3];
    float invN = 1.f / 802816.f;
    float mu = S1 * invN;
    float var = S2 * invN - mu * mu;
    qk_murs[bi * 2] = mu;
    qk_murs[bi * 2 + 1] = rsqrtf(var + EPS_GN);
  }
}

// ---------- pass A: MFMA q/k enc_blocks + both poolings ----------

__global__ __launch_bounds__(256) void k_passA2(
    const float* __restrict__ img, const float* __restrict__ ropef,
    const float* __restrict__ wimg, const float* __restrict__ wimgp,
    const float* __restrict__ img_murs, const float* __restrict__ qk_murs,
    const _Float16* __restrict__ WqB, const _Float16* __restrict__ WkB,
    float* __restrict__ q_pool, float* __restrict__ k_pool) {
  __shared__ __align__(16) float encL[64 * 132];
  __shared__ float sWc[384], sWp[384], sF[64], sMu[8], sRs[8];
  __shared__ float sQmu[8], sQrs[8], sKmu[8], sKrs[8];
  int t = threadIdx.x, l = t & 63, w = t >> 6;
  int b = blockIdx.x / 196, tile = blockIdx.x % 196;
  int by = (tile / 14) * 16, bx = (tile % 14) * 16;
  for (int i = t; i < 384; i += 256) { sWc[i] = wimg[i]; sWp[i] = wimgp[i]; }
  if (t < 64) sF[t] = ropef[t];
  if (t < 8) {
    sMu[t] = img_murs[b * 16 + t];
    sRs[t] = img_murs[b * 16 + 8 + t];
    sQmu[t] = qk_murs[(b * 8 + t) * 2];
    sQrs[t] = qk_murs[(b * 8 + t) * 2 + 1];
    sKmu[t] = qk_murs[(32 + b * 8 + t) * 2];
    sKrs[t] = qk_murs[(32 + b * 8 + t) * 2 + 1];
  }
  h16x4 bq[8][2], bk[8][2];
#pragma unroll
  for (int kt = 0; kt < 8; ++kt)
#pragma unroll
    for (int cc = 0; cc < 2; ++cc) {
      int fi = ((kt * 8 + (2 * w + cc)) * 64 + l) * 4;
      bq[kt][cc] = *(const h16x4*)(WqB + fi);
      bk[kt][cc] = *(const h16x4*)(WkB + fi);
    }
  float kacc0 = 0.f, kacc1 = 0.f;
  f32x4 z = {0.f, 0.f, 0.f, 0.f};
  for (int st = 0; st < 4; ++st) {
    __syncthreads();
    {
      int py = by + (st >> 1) * 8 + (l >> 3);
      int px = bx + (st & 1) * 8 + (l & 7);
      enc_tile(encL, img, b, py, px, l, w, sWc, sWp, sF, sMu, sRs);
    }
    __syncthreads();
    f32x4 accQ[4][2], accK[4][2];
#pragma unroll
    for (int mt = 0; mt < 4; ++mt)
#pragma unroll
      for (int cc = 0; cc < 2; ++cc) { accQ[mt][cc] = z; accK[mt][cc] = z; }
#pragma unroll
    for (int kt = 0; kt < 8; ++kt) {
      h16x4 a[4];
#pragma unroll
      for (int mt = 0; mt < 4; ++mt) {
        f32x4 av = *(const f32x4*)(encL + (mt * 16 + (l & 15)) * 132 +
                                   kt * 16 + 4 * (l >> 4));
        h16x4 ah;
#pragma unroll
        for (int j = 0; j < 4; ++j) ah[j] = (_Float16)av[j];
        a[mt] = ah;
      }
#pragma unroll
      for (int mt = 0; mt < 4; ++mt) {
        accQ[mt][0] = mfma16(a[mt], bq[kt][0], accQ[mt][0]);
        accQ[mt][1] = mfma16(a[mt], bq[kt][1], accQ[mt][1]);
        accK[mt][0] = mfma16(a[mt], bk[kt][0], accK[mt][0]);
        accK[mt][1] = mfma16(a[mt], bk[kt][1], accK[mt][1]);
      }
    }
#pragma unroll
    for (int cc = 0; cc < 2; ++cc) {
      int g = 2 * w + cc;
      int cout = g * 16 + (l & 15);
      float qmu = sQmu[g], qrs = sQrs[g], kmu = sKmu[g], krs = sKrs[g];
      float kav = 0.f;
#pragma unroll
      for (int mt = 0; mt < 4; ++mt) {
        float qv[4];
#pragma unroll
        for (int r = 0; r < 4; ++r) {
          int m = 4 * (l >> 4) + r;
          float skip = encL[(mt * 16 + m) * 132 + cout];
          qv[r] = silu_f((accQ[mt][cc][r] - qmu) * qrs) + skip;
          kav += silu_f((accK[mt][cc][r] - kmu) * krs) + skip;
        }
        float s01 = qv[0] + qv[1], s23 = qv[2] + qv[3];
        s01 += __shfl_xor(s01, 32);
        s23 += __shfl_xor(s23, 32);
        if ((l >> 4) < 2) {
          int py2 = (by + (st >> 1) * 8 + 2 * mt) >> 1;
          int px2 = (bx + (st & 1) * 8 + (l >> 4) * 4) >> 1;
          size_t base = ((size_t)(b * NQ) + py2 * 112 + px2) * 128 + cout;
          q_pool[base] = s01 * 0.25f;
          q_pool[base + 128] = s23 * 0.25f;
        }
      }
      if (cc == 0) kacc0 += kav; else kacc1 += kav;
    }
  }
  kacc0 += __shfl_xor(kacc0, 16); kacc0 += __shfl_xor(kacc0, 32);
  kacc1 += __shfl_xor(kacc1, 16); kacc1 += __shfl_xor(kacc1, 32);
  if (l < 16) {
    k_pool[((size_t)(b * 128) + (2 * w) * 16 + l) * NKk + tile] = kacc0 * (1.f / 256.f);
    k_pool[((size_t)(b * 128) + (2 * w + 1) * 16 + l) * NKk + tile] = kacc1 * (1.f / 256.f);
  }
}

// ---------- GN stats ----------

// channel-major src[b][c][P]
__global__ __launch_bounds__(256) void k_gnstats(
    const float* __restrict__ src, float* __restrict__ murs, int P, float eps) {
  __shared__ float l1[4], l2[4];
  int b = blockIdx.x >> 3, g = blockIdx.x & 7, t = threadIdx.x;
  const float* base = src + ((size_t)(b * 128) + g * 16) * P;
  float s1 = 0.f, s2 = 0.f;
  for (int i = t; i < 16 * P; i += 256) {
    float v = base[i];
    s1 += v; s2 += v * v;
  }
  for (int m = 1; m < 64; m <<= 1) { s1 += __shfl_xor(s1, m); s2 += __shfl_xor(s2, m); }
  if ((t & 63) == 0) { l1[t >> 6] = s1; l2[t >> 6] = s2; }
  __syncthreads();
  if (t == 0) {
    float invN = 1.f / (16.f * (float)P);
    float a = l1[0] + l1[1] + l1[2] + l1[3];
    float bq = l2[0] + l2[1] + l2[2] + l2[3];
    float mu = a * invN;
    float var = bq * invN - mu * mu;
    murs[blockIdx.x * 2] = mu;
    murs[blockIdx.x * 2 + 1] = rsqrtf(var + eps);
  }
}

// pixel-major src[b][p][128]
__global__ __launch_bounds__(256) void k_gnstats_pm(
    const float* __restrict__ src, float* __restrict__ murs) {
  __shared__ float l1[4], l2[4];
  int b = blockIdx.x >> 3, g = blockIdx.x & 7, t = threadIdx.x;
  const float* base = src + (size_t)b * NQ * 128 + g * 16 + (t & 15);
  float s1 = 0.f, s2 = 0.f;
  for (int p = t >> 4; p < NQ; p += 16) {
    float v = base[(size_t)p * 128];
    s1 += v; s2 += v * v;
  }
  for (int m = 1; m < 64; m <<= 1) { s1 += __shfl_xor(s1, m); s2 += __shfl_xor(s2, m); }
  if ((t & 63) == 0) { l1[t >> 6] = s1; l2[t >> 6] = s2; }
  __syncthreads();
  if (t == 0) {
    float invN = 1.f / (16.f * (float)NQ);
    float a = l1[0] + l1[1] + l1[2] + l1[3];
    float bq = l2[0] + l2[1] + l2[2] + l2[3];
    float mu = a * invN;
    float var = bq * invN - mu * mu;
    murs[blockIdx.x * 2] = mu;
    murs[blockIdx.x * 2 + 1] = rsqrtf(var + EPS_GN);
  }
}

// ---------- features L2 normalize ----------

__global__ void k_fn(const float* __restrict__ feat, float* __restrict__ fn) {
  int b = blockIdx.x, p = threadIdx.x;
  if (p >= NKk) return;
  const float* fb = feat + (size_t)b * VD * NKk + p;
  float s = 0.f;
  for (int c = 0; c < VD; ++c) { float v = fb[c * NKk]; s += v * v; }
  float r = rsqrtf(fmaxf(s, 1e-24f));
  float* ob = fn + (size_t)b * VD * NKk + p;
  for (int c = 0; c < VD; ++c) ob[c * NKk] = fb[c * NKk] * r;
}

// ---------- kf enc_block conv (384->128, conv + proj skip) ----------

__global__ __launch_bounds__(256) void k_kfconv(
    const float* __restrict__ fn, const float* __restrict__ KFT,
    const float* __restrict__ KFPT,
    float* __restrict__ y_kf, float* __restrict__ skip_kf) {
  __shared__ float fnL[192 * 64];
  int t = threadIdx.x, p = t & 63, cq = t >> 6;
  int b = blockIdx.x >> 2, tile = blockIdx.x & 3;
  int p0 = tile * 49;
  int c0 = cq * 32, c0u = rfl(c0);
  float accy[32], accs[32];
#pragma unroll
  for (int i = 0; i < 32; ++i) { accy[i] = 0.f; accs[i] = 0.f; }
  for (int ch = 0; ch < 2; ++ch) {
    __syncthreads();
    for (int i = t; i < 192 * 64; i += 256) {
      int kk = i >> 6, pp = i & 63;
      float v = 0.f;
      if (pp < 49) v = fn[((size_t)(b * 384) + ch * 192 + kk) * NKk + p0 + pp];
      fnL[i] = v;
    }
    __syncthreads();
#pragma unroll 2
    for (int k = 0; k < 192; ++k) {
      float x = fnL[k * 64 + p];
      const float* wy = KFT + ((size_t)(ch * 192 + k)) * 128 + c0u;
      const float* wsk = KFPT + ((size_t)(ch * 192 + k)) * 128 + c0u;
#pragma unroll
      for (int i = 0; i < 32; ++i) {
        accy[i] = fmaf(wy[i], x, accy[i]);
        accs[i] = fmaf(wsk[i], x, accs[i]);
      }
    }
  }
  if (p < 49) {
#pragma unroll
    for (int i = 0; i < 32; ++i) {
      size_t off = (size_t)(b * 128 + c0 + i) * NKk + p0 + p;
      y_kf[off] = accy[i];
      skip_kf[off] = accs[i];
    }
  }
}

// ---------- SFT ----------

__global__ __launch_bounds__(256) void k_sft(
    const float* __restrict__ y_kf, const float* __restrict__ skip_kf,
    const float* __restrict__ kf_murs, const float* __restrict__ GT,
    const float* __restrict__ BT, const float* __restrict__ k_pool,
    const float* __restrict__ kgn_murs, float* __restrict__ k_final) {
  __shared__ float kfL[128 * 64];
  __shared__ float sMu[8], sRs[8], sGmu[8], sGrs[8];
  int t = threadIdx.x, p = t & 63, cq = t >> 6;
  int b = blockIdx.x >> 2, tile = blockIdx.x & 3;
  int p0 = tile * 49;
  if (t < 8) {
    sMu[t] = kf_murs[(b * 8 + t) * 2];
    sRs[t] = kf_murs[(b * 8 + t) * 2 + 1];
    sGmu[t] = kgn_murs[(b * 8 + t) * 2];
    sGrs[t] = kgn_murs[(b * 8 + t) * 2 + 1];
  }
  __syncthreads();
  for (int i = t; i < 128 * 64; i += 256) {
    int c = i >> 6, pp = i & 63;
    float v = 0.f;
    if (pp < 49) {
      size_t off = (size_t)(b * 128 + c) * NKk + p0 + pp;
      int g = c >> 4;
      v = silu_f((y_kf[off] - sMu[g]) * sRs[g]) + skip_kf[off];
    }
    kfL[i] = v;
  }
  __syncthreads();
  int c0 = cq * 32, c0u = rfl(c0);
  float ag[32], ab[32];
#pragma unroll
  for (int i = 0; i < 32; ++i) { ag[i] = 0.f; ab[i] = 0.f; }
  gemm32(ag, kfL, GT, p, c0u);
  gemm32(ab, kfL, BT, p, c0u);
  if (p < 49) {
#pragma unroll
    for (int i = 0; i < 32; ++i) {
      int c = c0 + i, g = c >> 4;
      size_t off = (size_t)(b * 128 + c) * NKk + p0 + p;
      float kn = (k_pool[off] - sGmu[g]) * sGrs[g];
      k_final[off] = fmaf(ag[i], kn, ab[i]);
    }
  }
}

// ---------- RMSNorm + projection (k side, VALU) ----------

__global__ __launch_bounds__(256) void k_rmsproj(
    const float* __restrict__ src, const float* __restrict__ WTs,
    const float* __restrict__ bias, float* __restrict__ dst, int NP) {
  __shared__ float xL[128 * 64];
  __shared__ float msP[4][64];
  int t = threadIdx.x, p = t & 63, cq = t >> 6;
  int nt = (NP + 63) / 64;
  int b = blockIdx.x / nt, tile = blockIdx.x % nt;
  int p0 = tile * 64;
  float ss = 0.f;
#pragma unroll
  for (int i = 0; i < 32; ++i) {
    int c = cq * 32 + i;
    float v = (p0 + p < NP) ? src[(size_t)(b * 128 + c) * NP + p0 + p] : 0.f;
    xL[c * 64 + p] = v;
    ss += v * v;
  }
  msP[cq][p] = ss;
  __syncthreads();
  float ms = (msP[0][p] + msP[1][p] + msP[2][p] + msP[3][p]) * (1.f / 128.f);
  float rr = rsqrtf(ms + EPS_RMS);
  int c0u = rfl(cq * 32);
  float acc[32];
#pragma unroll
  for (int i = 0; i < 32; ++i) acc[i] = 0.f;
  gemm32(acc, xL, WTs, p, c0u);
  if (p0 + p < NP) {
#pragma unroll
    for (int i = 0; i < 32; ++i)
      dst[((size_t)b * NP + p0 + p) * 128 + c0u + i] = acc[i] * rr + bias[c0u + i];
  }
}

// ---------- 3x3 conv on GN(q_pool), MFMA ----------

__global__ __launch_bounds__(256) void k_conv3m(
    const float* __restrict__ q_pool, const float* __restrict__ murs2,
    const _Float16* __restrict__ W3B, float* __restrict__ qconv,
    float* __restrict__ msq) {
  __shared__ __align__(16) _Float16 w3L[16384];
  __shared__ float sMu[8], sRs[8];
  int t = threadIdx.x, l = t & 63, w = t >> 6;
  int b = blockIdx.x / 98, reg = blockIdx.x % 98;
  int y0 = (reg / 7) * 8, x0 = (reg % 7) * 16;
  if (t < 8) { sMu[t] = murs2[(b * 8 + t) * 2]; sRs[t] = murs2[(b * 8 + t) * 2 + 1]; }
  f32x4 z = {0.f, 0.f, 0.f, 0.f};
  f32x4 acc[2][8];
#pragma unroll
  for (int rx = 0; rx < 2; ++rx)
#pragma unroll
    for (int ct = 0; ct < 8; ++ct) acc[rx][ct] = z;
  int lm = l & 15;
  int mrow = lm >> 3, mcol = lm & 7;
  for (int tap = 0; tap < 9; ++tap) {
    int dy = tap / 3 - 1, dx = tap % 3 - 1;
    __syncthreads();
    for (int i = t; i < 4096; i += 256)
      ((h16x4*)w3L)[i] = ((const h16x4*)W3B)[tap * 4096 + i];
    __syncthreads();
    int py = y0 + 2 * w + mrow + dy;
    int pxb = x0 + mcol + dx;
    bool oky = (py >= 0) && (py < 112);
#pragma unroll
    for (int kt = 0; kt < 8; ++kt) {
      float mu = sMu[kt], rs = sRs[kt];
      h16x4 a[2];
#pragma unroll
      for (int rx = 0; rx < 2; ++rx) {
        int px = pxb + rx * 8;
        bool ok = oky && (px >= 0) && (px < 112);
        h16x4 ah = {(_Float16)0.f, (_Float16)0.f, (_Float16)0.f, (_Float16)0.f};
        if (ok) {
          f32x4 v = *(const f32x4*)(q_pool + ((size_t)(b * NQ) + py * 112 + px) * 128 +
                                    kt * 16 + 4 * (l >> 4));
#pragma unroll
          for (int j = 0; j < 4; ++j) ah[j] = (_Float16)((v[j] - mu) * rs);
        }
        a[rx] = ah;
      }
#pragma unroll
      for (int ct = 0; ct < 8; ++ct) {
        h16x4 bf = ((const h16x4*)w3L)[(kt * 8 + ct) * 64 + l];
        acc[0][ct] = mfma16(a[0], bf, acc[0][ct]);
        acc[1][ct] = mfma16(a[1], bf, acc[1][ct]);
      }
    }
  }
#pragma unroll
  for (int rx = 0; rx < 2; ++rx) {
    float sq[4] = {0.f, 0.f, 0.f, 0.f};
#pragma unroll
    for (int ct = 0; ct < 8; ++ct)
#pragma unroll
      for (int r = 0; r < 4; ++r) sq[r] += acc[rx][ct][r] * acc[rx][ct][r];
#pragma unroll
    for (int r = 0; r < 4; ++r) {
      for (int m = 1; m < 16; m <<= 1) sq[r] += __shfl_xor(sq[r], m);
      int mm = 4 * (l >> 4) + r;
      int py = y0 + 2 * w + (mm >> 3), px = x0 + rx * 8 + (mm & 7);
      size_t pb = (size_t)(b * NQ) + py * 112 + px;
      if ((l & 15) == 0) msq[pb] = sq[r];
#pragma unroll
      for (int ct = 0; ct < 8; ++ct)
        qconv[pb * 128 + ct * 16 + (l & 15)] = acc[rx][ct][r];
    }
  }
}

// ---------- RMSNorm + proj (q side, MFMA) ----------

__global__ __launch_bounds__(256) void k_rmsq(
    const float* __restrict__ qconv, const _Float16* __restrict__ QPB,
    const float* __restrict__ msq, const float* __restrict__ bias,
    float* __restrict__ qp) {
  __shared__ __align__(16) _Float16 wL[16384];
  int t = threadIdx.x, l = t & 63, w = t >> 6;
  int b = blockIdx.x / 196, tile = blockIdx.x % 196;
  for (int i = t; i < 4096; i += 256)
    ((h16x4*)wL)[i] = ((const h16x4*)QPB)[i];
  __syncthreads();
  int p0 = tile * 64 + w * 16;
  f32x4 z = {0.f, 0.f, 0.f, 0.f};
  f32x4 acc[8];
#pragma unroll
  for (int ct = 0; ct < 8; ++ct) acc[ct] = z;
#pragma unroll
  for (int kt = 0; kt < 8; ++kt) {
    f32x4 av = *(const f32x4*)(qconv + ((size_t)(b * NQ) + p0 + (l & 15)) * 128 +
                               kt * 16 + 4 * (l >> 4));
    h16x4 ah;
#pragma unroll
    for (int j = 0; j < 4; ++j) ah[j] = (_Float16)av[j];
#pragma unroll
    for (int ct = 0; ct < 8; ++ct)
      acc[ct] = mfma16(ah, ((const h16x4*)wL)[(kt * 8 + ct) * 64 + l], acc[ct]);
  }
#pragma unroll
  for (int r = 0; r < 4; ++r) {
    int pix = p0 + 4 * (l >> 4) + r;
    float rr = rsqrtf(msq[(size_t)(b * NQ) + pix] * (1.f / 128.f) + EPS_RMS);
#pragma unroll
    for (int ct = 0; ct < 8; ++ct)
      qp[((size_t)(b * NQ) + pix) * 128 + ct * 16 + (l & 15)] =
          acc[ct][r] * rr + bias[ct * 16 + (l & 15)];
  }
}

// ---------- attention: QK^T + softmax + head-mean ----------

__global__ __launch_bounds__(256) void k_attn1m(
    const float* __restrict__ qp, const float* __restrict__ kpb,
    float* __restrict__ P) {
  __shared__ float sP[4][16][212];
  int t = threadIdx.x, l = t & 63, h = t >> 6;
  int b = blockIdx.x / 784, qt = blockIdx.x % 784;
  int q0 = qt * 16;
  constexpr float SC = 0.17677669529663687f;  // 1/sqrt(32)
  h16x4 aq[2];
#pragma unroll
  for (int kt = 0; kt < 2; ++kt) {
    f32x4 v = *(const f32x4*)(qp + ((size_t)(b * NQ) + q0 + (l & 15)) * 128 +
                              h * 32 + kt * 16 + 4 * (l >> 4));
    h16x4 ah;
#pragma unroll
    for (int j = 0; j < 4; ++j) ah[j] = (_Float16)v[j];
    aq[kt] = ah;
  }
  f32x4 z = {0.f, 0.f, 0.f, 0.f};
  f32x4 acc[13];
#pragma unroll
  for (int nt = 0; nt < 13; ++nt) acc[nt] = z;
#pragma unroll
  for (int nt = 0; nt < 13; ++nt) {
    int key = nt * 16 + (l & 15);
    bool ok = key < 196;
#pragma unroll
    for (int kt = 0; kt < 2; ++kt) {
      h16x4 bf = {(_Float16)0.f, (_Float16)0.f, (_Float16)0.f, (_Float16)0.f};
      if (ok) {
        f32x4 v = *(const f32x4*)(kpb + ((size_t)(b * 196) + key) * 128 +
                                  h * 32 + kt * 16 + 4 * (l >> 4));
#pragma unroll
        for (int j = 0; j < 4; ++j) bf[j] = (_Float16)v[j];
      }
      acc[nt] = mfma16(aq[kt], bf, acc[nt]);
    }
  }
#pragma unroll
  for (int r = 0; r < 4; ++r) {
    float mx = -3e38f;
#pragma unroll
    for (int nt = 0; nt < 13; ++nt) {
      bool ok = nt * 16 + (l & 15) < 196;
      float v = ok ? acc[nt][r] * SC : -3e38f;
      acc[nt][r] = v;
      mx = fmaxf(mx, v);
    }
    for (int m = 1; m < 16; m <<= 1) mx = fmaxf(mx, __shfl_xor(mx, m));
    float sum = 0.f;
#pragma unroll
    for (int nt = 0; nt < 13; ++nt) {
      bool ok = nt * 16 + (l & 15) < 196;
      float e = ok ? __expf(acc[nt][r] - mx) : 0.f;
      acc[nt][r] = e;
      sum += e;
    }
    for (int m = 1; m < 16; m <<= 1) sum += __shfl_xor(sum, m);
    float inv = 1.f / sum;
#pragma unroll
    for (int nt = 0; nt < 13; ++nt)
      sP[h][4 * (l >> 4) + r][nt * 16 + (l & 15)] = acc[nt][r] * inv;
  }
  __syncthreads();
  for (int i = t; i < 16 * 208; i += 256) {
    int q = i / 208, k = i % 208;
    float v = 0.f;
    if (k < 196)
      v = 0.25f * (sP[0][q][k] + sP[1][q][k] + sP[2][q][k] + sP[3][q][k]);
    P[((size_t)(b * NQ) + q0 + q) * 208 + k] = v;
  }
}

// ---------- attention PV (vs raw features), MFMA ----------

__global__ __launch_bounds__(256) void k_attn2m(
    const float* __restrict__ P, const float* __restrict__ feat,
    float* __restrict__ out) {
  __shared__ __align__(16) _Float16 fL[384 * 68];
  int t = threadIdx.x, l = t & 63, w = t >> 6;
  int b = blockIdx.x / 196, qt = blockIdx.x % 196;
  int qw = qt * 64 + w * 16;
  f32x4 z = {0.f, 0.f, 0.f, 0.f};
  f32x4 acc[24];
#pragma unroll
  for (int mt = 0; mt < 24; ++mt) acc[mt] = z;
  const float* Prow = P + ((size_t)(b * NQ) + qw + (l & 15)) * 208 + 4 * (l >> 4);
#pragma unroll
  for (int ch = 0; ch < 4; ++ch) {
    __syncthreads();
    for (int i = t; i < 384 * 64; i += 256) {
      int d = i >> 6, kk = i & 63;
      int key = ch * 64 + kk;
      float v = (key < 196) ? feat[((size_t)(b * 384) + d) * 196 + key] : 0.f;
      fL[d * 68 + kk] = (_Float16)v;
    }
    __syncthreads();
    const int nkt = (ch < 3) ? 4 : 1;
#pragma unroll
    for (int kc = 0; kc < 4; ++kc) {
      if (kc >= nkt) break;
      int kt = ch * 4 + kc;
      f32x4 pv = *(const f32x4*)(Prow + kt * 16);
      h16x4 bp;
#pragma unroll
      for (int j = 0; j < 4; ++j) bp[j] = (_Float16)pv[j];
#pragma unroll
      for (int mt = 0; mt < 24; ++mt) {
        h16x4 af = *(const h16x4*)(fL + (mt * 16 + (l & 15)) * 68 +
                                   kc * 16 + 4 * (l >> 4));
        acc[mt] = mfma16(af, bp, acc[mt]);
      }
    }
  }
#pragma unroll
  for (int mt = 0; mt < 24; ++mt)
#pragma unroll
    for (int r = 0; r < 4; ++r) {
      int d = mt * 16 + 4 * (l >> 4) + r;
      out[((size_t)(b * 384) + d) * NQ + qw + (l & 15)] = acc[mt][r];
    }
}

}  // namespace

extern "C" void kernel_launch(void* const* d_in, const int* in_sizes, int n_in,
                              void* d_out, int out_size, void* d_ws,
                              size_t ws_size, hipStream_t stream) {
  (void)in_sizes; (void)n_in; (void)out_size; (void)ws_size;
  const float* image        = (const float*)d_in[0];
  const float* features     = (const float*)d_in[1];
  const float* rope_f       = (const float*)d_in[2];
  const float* img_conv_w   = (const float*)d_in[3];
  const float* img_proj_w   = (const float*)d_in[4];
  const float* qenc_w       = (const float*)d_in[5];
  const float* kenc_w       = (const float*)d_in[6];
  const float* kfeat_conv_w = (const float*)d_in[7];
  const float* kfeat_proj_w = (const float*)d_in[8];
  const float* sft_gamma_w  = (const float*)d_in[9];
  const float* sft_beta_w   = (const float*)d_in[10];
  const float* block_conv_w = (const float*)d_in[11];
  const float* rms_q_w      = (const float*)d_in[12];
  const float* rms_k_w      = (const float*)d_in[13];
  const float* q_proj_w     = (const float*)d_in[14];
  const float* q_proj_b     = (const float*)d_in[15];
  const float* k_proj_w     = (const float*)d_in[16];
  const float* k_proj_b     = (const float*)d_in[17];
  float* out = (float*)d_out;
  float* ws = (float*)d_ws;

  size_t off = 0;
  auto alloc = [&](size_t n) {
    size_t r = off;
    off += (n + 63) & ~(size_t)63;
    return r;
  };
  _Float16* WqB = (_Float16*)(ws + alloc(8192));
  _Float16* WkB = (_Float16*)(ws + alloc(8192));
  _Float16* QPB = (_Float16*)(ws + alloc(8192));
  _Float16* W3B = (_Float16*)(ws + alloc(73728));
  float* KFT      = ws + alloc(49152);
  float* KFPT     = ws + alloc(49152);
  float* GT       = ws + alloc(16384);
  float* BT       = ws + alloc(16384);
  float* KPT      = ws + alloc(16384);
  float* imgpart  = ws + alloc(2304);
  float* img_murs = ws + alloc(64);
  float* qk_murs  = ws + alloc(128);
  float* murs2    = ws + alloc(64);
  float* kgn_murs = ws + alloc(64);
  float* kf_murs  = ws + alloc(64);
  float* G        = ws + alloc(65536);
  float* mvec     = ws + alloc(512);
  float* y_kf     = ws + alloc(100352);
  float* skip_kf  = ws + alloc(100352);
  float* k_final  = ws + alloc(100352);
  float* k_pool   = ws + alloc(100352);
  float* kpb      = ws + alloc(100352);
  float* msq      = ws + alloc(50176);
  float* RA       = ws + alloc((size_t)BB * NQ * 128);      // fnb -> q_pool -> qp
  float* RB       = ws + alloc((size_t)BB * NQ * 208);      // Gpart -> qconv -> P
  float* fnb    = RA;
  float* q_pool = RA;
  float* qp     = RA;
  float* Gpart  = RB;
  float* mpart  = RB + (size_t)BB * 49 * 16384;
  float* qconv  = RB;
  float* P      = RB;

  // weight prep
  k_pack16<<<64, 256, 0, stream>>>(qenc_w, WqB, nullptr);
  k_pack16<<<64, 256, 0, stream>>>(kenc_w, WkB, nullptr);
  k_pack16<<<64, 256, 0, stream>>>(q_proj_w, QPB, rms_q_w);
  k_packw3<<<576, 256, 0, stream>>>(block_conv_w, W3B);
  k_t2d<<<192, 256, 0, stream>>>(kfeat_conv_w, KFT, 128, 384, (const float*)nullptr);
  k_t2d<<<192, 256, 0, stream>>>(kfeat_proj_w, KFPT, 128, 384, (const float*)nullptr);
  k_t2d<<<64, 256, 0, stream>>>(sft_gamma_w, GT, 128, 128, (const float*)nullptr);
  k_t2d<<<64, 256, 0, stream>>>(sft_beta_w, BT, 128, 128, (const float*)nullptr);
  k_t2d<<<64, 256, 0, stream>>>(k_proj_w, KPT, 128, 128, rms_k_w);

  // image GN stats (Gram trick over 3 channels)
  k_imgstat1<<<BB * 64, 256, 0, stream>>>(image, imgpart);
  k_imgstat2<<<BB, 128, 0, stream>>>(imgpart, img_conv_w, img_murs);

  // kf branch early (fnb aliases RA before passA writes q_pool)
  k_fn<<<BB, 256, 0, stream>>>(features, fnb);
  k_kfconv<<<BB * 4, 256, 0, stream>>>(fnb, KFT, KFPT, y_kf, skip_kf);
  k_gnstats<<<32, 256, 0, stream>>>(y_kf, kf_murs, NKk, EPS_GN);

  // Gram of enc -> GN stats for q/k 1x1 convs
  k_gram<<<BB * 49, 256, 0, stream>>>(image, rope_f, img_conv_w, img_proj_w,
                                      img_murs, Gpart, mpart);
  k_gred<<<BB * 64, 256, 0, stream>>>(Gpart, mpart, G, mvec);
  k_gstats<<<64, 256, 0, stream>>>(G, mvec, qenc_w, kenc_w, qk_murs);

  // apply q/k enc_blocks + pooling (MFMA)
  k_passA2<<<BB * 196, 256, 0, stream>>>(image, rope_f, img_conv_w, img_proj_w,
                                         img_murs, qk_murs, WqB, WkB,
                                         q_pool, k_pool);

  k_gnstats_pm<<<32, 256, 0, stream>>>(q_pool, murs2);
  k_gnstats<<<32, 256, 0, stream>>>(k_pool, kgn_murs, NKk, EPS_GN);

  // k side (tiny, VALU)
  k_sft<<<BB * 4, 256, 0, stream>>>(y_kf, skip_kf, kf_murs, GT, BT, k_pool,
                                    kgn_murs, k_final);
  k_rmsproj<<<BB * 4, 256, 0, stream>>>(k_final, KPT, k_proj_b, kpb, NKk);

  // q side (MFMA)
  k_conv3m<<<BB * 98, 256, 0, stream>>>(q_pool, murs2, W3B, qconv, msq);
  k_rmsq<<<BB * 196, 256, 0, stream>>>(qconv, QPB, msq, q_proj_b, qp);

  // attention
  k_attn1m<<<BB * 784, 256, 0, stream>>>(qp, kpb, P);
  k_attn2m<<<BB * 196, 256, 0, stream>>>(P, features, out);
}

// Round 3
// 852.084 us; speedup vs baseline: 2.3845x; 1.2885x over previous
//
#include <hip/hip_runtime.h>
#include <cstdint>
#include <cstddef>

#define DEV __device__ __forceinline__

namespace {

constexpr int BB   = 4;
constexpr int HWP  = 50176;   // 224*224
constexpr int NQ   = 12544;   // 112*112
constexpr int NKk  = 196;     // 14*14
constexpr int VD   = 384;
constexpr float EPS_GN  = 1e-5f;
constexpr float EPS_RMS = 1.1920929e-7f;

typedef __attribute__((ext_vector_type(4))) float f32x4;
typedef __attribute__((ext_vector_type(4))) _Float16 h16x4;

DEV float silu_f(float z) { return z / (1.f + __expf(-z)); }
DEV int rfl(int v) { return __builtin_amdgcn_readfirstlane(v); }

DEV f32x4 mfma16(h16x4 a, h16x4 b, f32x4 c) {
  return __builtin_amdgcn_mfma_f32_16x16x16f16(a, b, c, 0, 0, 0);
}

// fp32 scalar-broadcast GEMM for the small k-branch kernels (K=128, 64 px)
DEV void gemm32(float* acc, const float* encL, const float* __restrict__ WT,
                int p, int c0u) {
#pragma unroll 4
  for (int k = 0; k < 128; ++k) {
    float x = encL[k * 64 + p];
    const float* w = WT + (size_t)k * 128 + c0u;
#pragma unroll
    for (int i = 0; i < 32; ++i) acc[i] = fmaf(w[i], x, acc[i]);
  }
}

// Recompute enc (img 1x1 conv -> GN -> SiLU -> +proj skip -> RoPE) for one
// 64-pixel tile into LDS encL[64][132] f32 (pixel-major, padded).
DEV void enc_tile(float* encL, const float* __restrict__ img, int b,
                  int py, int px, int p, int cq,
                  const float* sWc, const float* sWp, const float* sF,
                  const float* sMu, const float* sRs) {
  const float* ip = img + (size_t)b * 3 * HWP + py * 224 + px;
  float x0 = ip[0], x1 = ip[HWP], x2 = ip[2 * HWP];
  float gy = (py + 0.5f) * (1.f / 224.f);
  float gx = (px + 0.5f) * (1.f / 224.f);
#pragma unroll
  for (int jj = 0; jj < 4; ++jj) {
    f32x4 lo, hi;
#pragma unroll
    for (int u = 0; u < 4; ++u) {
      int d = cq * 16 + jj * 4 + u;
      int c2 = d + 64;
      float y1 = sWc[d * 3] * x0 + sWc[d * 3 + 1] * x1 + sWc[d * 3 + 2] * x2;
      float s1 = sWp[d * 3] * x0 + sWp[d * 3 + 1] * x1 + sWp[d * 3 + 2] * x2;
      float y2 = sWc[c2 * 3] * x0 + sWc[c2 * 3 + 1] * x1 + sWc[c2 * 3 + 2] * x2;
      float s2 = sWp[c2 * 3] * x0 + sWp[c2 * 3 + 1] * x1 + sWp[c2 * 3 + 2] * x2;
      int g1 = d >> 4, g2 = g1 + 4;
      float t1 = silu_f((y1 - sMu[g1]) * sRs[g1]) + s1;
      float t2 = silu_f((y2 - sMu[g2]) * sRs[g2]) + s2;
      float f = sF[d];
      float sa, ca, sb, cb;
      __sincosf(gy * f, &sa, &ca);
      __sincosf(gx * f, &sb, &cb);
      lo[u] = t1 * ca - t2 * sa;
      hi[u] = t2 * cb + t1 * sb;
    }
    *(f32x4*)(encL + p * 132 + cq * 16 + jj * 4) = lo;
    *(f32x4*)(encL + p * 132 + 64 + cq * 16 + jj * 4) = hi;
  }
}

// ---------- fused weight prep (one launch) ----------
// layout of work items:
//  [0,16384)        WqB  = pack16(qenc_w)
//  [16384,32768)    WkB  = pack16(kenc_w)
//  [32768,49152)    QPB  = pack16(q_proj_w, rms_q_w)
//  [49152,196608)   W3B  = packw3(block_conv_w)
//  [196608,245760)  KFT  = t2d(kfeat_conv_w, 128x384)
//  [245760,294912)  KFPT = t2d(kfeat_proj_w, 128x384)
//  [294912,311296)  GT   = t2d(sft_gamma_w, 128x128)
//  [311296,327680)  BT   = t2d(sft_beta_w, 128x128)
//  [327680,344064)  KPT  = t2d(k_proj_w, 128x128, rms_k_w)
DEV void pack16_one(int id, const float* W, const float* rowscale,
                    _Float16* dst) {
  int j = id & 3, l = (id >> 2) & 63, tile = id >> 8;
  int ct = tile & 7, kt = tile >> 3;
  int ci = kt * 16 + 4 * (l >> 4) + j;
  int co = ct * 16 + (l & 15);
  float v = W[(size_t)co * 128 + ci];
  if (rowscale) v *= rowscale[ci];
  dst[id] = (_Float16)v;
}
DEV void t2d_one(int idx, const float* src, float* dst, int CO, int CI,
                 const float* rowscale) {
  int co = idx / CI, ci = idx % CI;
  float v = src[idx];
  if (rowscale) v *= rowscale[ci];
  dst[(size_t)ci * CO + co] = v;
}

__global__ __launch_bounds__(256) void k_prep(
    const float* __restrict__ qenc_w, const float* __restrict__ kenc_w,
    const float* __restrict__ q_proj_w, const float* __restrict__ rms_q_w,
    const float* __restrict__ block_conv_w,
    const float* __restrict__ kfeat_conv_w, const float* __restrict__ kfeat_proj_w,
    const float* __restrict__ sft_gamma_w, const float* __restrict__ sft_beta_w,
    const float* __restrict__ k_proj_w, const float* __restrict__ rms_k_w,
    _Float16* __restrict__ WqB, _Float16* __restrict__ WkB,
    _Float16* __restrict__ QPB, _Float16* __restrict__ W3B,
    float* __restrict__ KFT, float* __restrict__ KFPT,
    float* __restrict__ GT, float* __restrict__ BT, float* __restrict__ KPT) {
  int idx = blockIdx.x * 256 + threadIdx.x;
  if (idx < 16384) {
    pack16_one(idx, qenc_w, nullptr, WqB);
  } else if (idx < 32768) {
    pack16_one(idx - 16384, kenc_w, nullptr, WkB);
  } else if (idx < 49152) {
    pack16_one(idx - 32768, q_proj_w, rms_q_w, QPB);
  } else if (idx < 196608) {
    int id = idx - 49152;
    int j = id & 3, l = (id >> 2) & 63, tile = (id >> 8) & 63, tap = id >> 14;
    int ct = tile & 7, kt = tile >> 3;
    int ci = kt * 16 + 4 * (l >> 4) + j;
    int co = ct * 16 + (l & 15);
    W3B[id] = (_Float16)block_conv_w[((size_t)co * 128 + ci) * 9 + tap];
  } else if (idx < 245760) {
    t2d_one(idx - 196608, kfeat_conv_w, KFT, 128, 384, nullptr);
  } else if (idx < 294912) {
    t2d_one(idx - 245760, kfeat_proj_w, KFPT, 128, 384, nullptr);
  } else if (idx < 311296) {
    t2d_one(idx - 294912, sft_gamma_w, GT, 128, 128, nullptr);
  } else if (idx < 327680) {
    t2d_one(idx - 311296, sft_beta_w, BT, 128, 128, nullptr);
  } else if (idx < 344064) {
    t2d_one(idx - 327680, k_proj_w, KPT, 128, 128, rms_k_w);
  }
}

// ---------- image GN stats via 3x3 Gram ----------

__global__ __launch_bounds__(256) void k_imgstat1(
    const float* __restrict__ img, float* __restrict__ part) {
  __shared__ float lds[4][9];
  int b = blockIdx.x >> 6, blk = blockIdx.x & 63;
  int t = threadIdx.x;
  float a[9];
#pragma unroll
  for (int j = 0; j < 9; ++j) a[j] = 0.f;
  const float* ib = img + (size_t)b * 3 * HWP;
  for (int pix = blk * 784 + t; pix < blk * 784 + 784; pix += 256) {
    float x0 = ib[pix], x1 = ib[HWP + pix], x2 = ib[2 * HWP + pix];
    a[0] += x0; a[1] += x1; a[2] += x2;
    a[3] += x0 * x0; a[4] += x0 * x1; a[5] += x0 * x2;
    a[6] += x1 * x1; a[7] += x1 * x2; a[8] += x2 * x2;
  }
#pragma unroll
  for (int j = 0; j < 9; ++j)
    for (int m = 1; m < 64; m <<= 1) a[j] += __shfl_xor(a[j], m);
  if ((t & 63) == 0)
    for (int j = 0; j < 9; ++j) lds[t >> 6][j] = a[j];
  __syncthreads();
  if (t < 9)
    part[(size_t)blockIdx.x * 9 + t] =
        lds[0][t] + lds[1][t] + lds[2][t] + lds[3][t];
}

__global__ __launch_bounds__(128) void k_imgstat2(
    const float* __restrict__ part, const float* __restrict__ wimg,
    float* __restrict__ img_murs) {
  __shared__ float MG[9];
  int b = blockIdx.x, t = threadIdx.x;
  if (t < 9) {
    float s = 0.f;
    for (int i = 0; i < 64; ++i) s += part[(size_t)(b * 64 + i) * 9 + t];
    MG[t] = s;
  }
  __syncthreads();
  int c = t;
  float w0 = wimg[c * 3], w1 = wimg[c * 3 + 1], w2 = wimg[c * 3 + 2];
  float s1 = w0 * MG[0] + w1 * MG[1] + w2 * MG[2];
  float s2 = w0 * w0 * MG[3] + w1 * w1 * MG[6] + w2 * w2 * MG[8] +
             2.f * (w0 * w1 * MG[4] + w0 * w2 * MG[5] + w1 * w2 * MG[7]);
  for (int m = 1; m < 16; m <<= 1) {
    s1 += __shfl_xor(s1, m);
    s2 += __shfl_xor(s2, m);
  }
  if ((c & 15) == 0) {
    int g = c >> 4;
    float invN = 1.f / (16.f * HWP);
    float mu = s1 * invN;
    float var = s2 * invN - mu * mu;
    img_murs[b * 16 + g] = mu;
    img_murs[b * 16 + 8 + g] = rsqrtf(var + EPS_GN);
  }
}

// ---------- Gram of enc ----------

__global__ __launch_bounds__(256) void k_gram(
    const float* __restrict__ img, const float* __restrict__ ropef,
    const float* __restrict__ wimg, const float* __restrict__ wimgp,
    const float* __restrict__ img_murs,
    float* __restrict__ Gpart, float* __restrict__ mpart) {
  __shared__ __align__(16) float encL[64 * 132];
  __shared__ float sWc[384], sWp[384], sF[64], sMu[8], sRs[8];
  int t = threadIdx.x, l = t & 63, w = t >> 6;
  int b = blockIdx.x / 98, blk = blockIdx.x % 98;
  for (int i = t; i < 384; i += 256) { sWc[i] = wimg[i]; sWp[i] = wimgp[i]; }
  if (t < 64) sF[t] = ropef[t];
  if (t < 8) { sMu[t] = img_murs[b * 16 + t]; sRs[t] = img_murs[b * 16 + 8 + t]; }
  f32x4 acc[2][8];
  f32x4 macc[2];
  f32x4 z = {0.f, 0.f, 0.f, 0.f};
#pragma unroll
  for (int e = 0; e < 2; ++e) {
    macc[e] = z;
#pragma unroll
    for (int nt = 0; nt < 8; ++nt) acc[e][nt] = z;
  }
  h16x4 hone = {(_Float16)1.f, (_Float16)1.f, (_Float16)1.f, (_Float16)1.f};
  for (int s = 0; s < 8; ++s) {
    __syncthreads();
    int pix = (blk * 8 + s) * 64 + l;
    int py = pix / 224, px = pix % 224;
    enc_tile(encL, img, b, py, px, l, w, sWc, sWp, sF, sMu, sRs);
    __syncthreads();
#pragma unroll
    for (int kt = 0; kt < 4; ++kt) {
      int pb = kt * 16 + 4 * (l >> 4);
      h16x4 a[2];
#pragma unroll
      for (int e = 0; e < 2; ++e) {
        int c = (2 * w + e) * 16 + (l & 15);
        h16x4 av;
#pragma unroll
        for (int j = 0; j < 4; ++j) av[j] = (_Float16)encL[(pb + j) * 132 + c];
        a[e] = av;
        macc[e] = mfma16(av, hone, macc[e]);
      }
#pragma unroll
      for (int nt = 0; nt < 8; ++nt) {
        int c = nt * 16 + (l & 15);
        h16x4 bv;
#pragma unroll
        for (int j = 0; j < 4; ++j) bv[j] = (_Float16)encL[(pb + j) * 132 + c];
        acc[0][nt] = mfma16(a[0], bv, acc[0][nt]);
        acc[1][nt] = mfma16(a[1], bv, acc[1][nt]);
      }
    }
  }
  float* gp = Gpart + (size_t)(b * 98 + blk) * 16384;
#pragma unroll
  for (int e = 0; e < 2; ++e)
#pragma unroll
    for (int nt = 0; nt < 8; ++nt)
#pragma unroll
      for (int r = 0; r < 4; ++r) {
        int row = (2 * w + e) * 16 + 4 * (l >> 4) + r;
        int col = nt * 16 + (l & 15);
        gp[row * 128 + col] = acc[e][nt][r];
      }
  if ((l & 15) == 0) {
    float* mp = mpart + (size_t)(b * 98 + blk) * 128;
#pragma unroll
    for (int e = 0; e < 2; ++e)
#pragma unroll
      for (int r = 0; r < 4; ++r)
        mp[(2 * w + e) * 16 + 4 * (l >> 4) + r] = macc[e][r];
  }
}

__global__ void k_gred(const float* __restrict__ Gpart,
                       const float* __restrict__ mpart,
                       float* __restrict__ G, float* __restrict__ mvec) {
  int b = blockIdx.x >> 6, chunk = blockIdx.x & 63;
  int idx = chunk * 256 + threadIdx.x;
  float s = 0.f;
  for (int i = 0; i < 98; ++i) s += Gpart[(size_t)(b * 98 + i) * 16384 + idx];
  G[(size_t)b * 16384 + idx] = s;
  if (idx < 128) {
    float sm = 0.f;
    for (int i = 0; i < 98; ++i) sm += mpart[(size_t)(b * 98 + i) * 128 + idx];
    mvec[b * 128 + idx] = sm;
  }
}

// stats for q/k 1x1 convs from Gram: E[y]=w.m, E[y^2]=w^T G w
__global__ __launch_bounds__(256) void k_gstats(
    const float* __restrict__ G, const float* __restrict__ mvec,
    const float* __restrict__ qw, const float* __restrict__ kw,
    float* __restrict__ qk_murs) {
  __shared__ float red1[4], red2[4];
  int bi = blockIdx.x;               // conv*32 + b*8 + g
  int conv = bi >> 5, b = (bi >> 3) & 3, g = bi & 7;
  const float* W = conv ? kw : qw;
  int t = threadIdx.x;
  int c = g * 16 + (t >> 4);
  int i0 = (t & 15) * 8;
  const float* wc = W + (size_t)c * 128;
  const float* Gb = G + (size_t)b * 16384;
  const float* mb = mvec + b * 128;
  float s1 = 0.f, s2 = 0.f;
  for (int i = i0; i < i0 + 8; ++i) {
    float gi = 0.f;
    for (int j = 0; j < 128; ++j) gi += Gb[i * 128 + j] * wc[j];
    s2 += wc[i] * gi;
    s1 += wc[i] * mb[i];
  }
  for (int m = 1; m < 64; m <<= 1) { s1 += __shfl_xor(s1, m); s2 += __shfl_xor(s2, m); }
  if ((t & 63) == 0) { red1[t >> 6] = s1; red2[t >> 6] = s2; }
  __syncthreads();
  if (t == 0) {
    float S1 = red1[0] + red1[1] + red1[2] + red1[3];
    float S2 = red2[0] + red2[1] + red2[2] + red2[3];
    float invN = 1.f / 802816.f;
    float mu = S1 * invN;
    float var = S2 * invN - mu * mu;
    qk_murs[bi * 2] = mu;
    qk_murs[bi * 2 + 1] = rsqrtf(var + EPS_GN);
  }
}

// ---------- pass A: MFMA q/k enc_blocks + poolings + fused q-pool stats ----------

__global__ __launch_bounds__(256) void k_passA2(
    const float* __restrict__ img, const float* __restrict__ ropef,
    const float* __restrict__ wimg, const float* __restrict__ wimgp,
    const float* __restrict__ img_murs, const float* __restrict__ qk_murs,
    const _Float16* __restrict__ WqB, const _Float16* __restrict__ WkB,
    float* __restrict__ q_pool, float* __restrict__ k_pool,
    float* __restrict__ Qpart) {
  __shared__ __align__(16) float encL[64 * 132];
  __shared__ float sWc[384], sWp[384], sF[64], sMu[8], sRs[8];
  __shared__ float sQmu[8], sQrs[8], sKmu[8], sKrs[8];
  int t = threadIdx.x, l = t & 63, w = t >> 6;
  int b = blockIdx.x / 196, tile = blockIdx.x % 196;
  int by = (tile / 14) * 16, bx = (tile % 14) * 16;
  for (int i = t; i < 384; i += 256) { sWc[i] = wimg[i]; sWp[i] = wimgp[i]; }
  if (t < 64) sF[t] = ropef[t];
  if (t < 8) {
    sMu[t] = img_murs[b * 16 + t];
    sRs[t] = img_murs[b * 16 + 8 + t];
    sQmu[t] = qk_murs[(b * 8 + t) * 2];
    sQrs[t] = qk_murs[(b * 8 + t) * 2 + 1];
    sKmu[t] = qk_murs[(32 + b * 8 + t) * 2];
    sKrs[t] = qk_murs[(32 + b * 8 + t) * 2 + 1];
  }
  h16x4 bq[8][2], bk[8][2];
#pragma unroll
  for (int kt = 0; kt < 8; ++kt)
#pragma unroll
    for (int cc = 0; cc < 2; ++cc) {
      int fi = ((kt * 8 + (2 * w + cc)) * 64 + l) * 4;
      bq[kt][cc] = *(const h16x4*)(WqB + fi);
      bk[kt][cc] = *(const h16x4*)(WkB + fi);
    }
  float kacc0 = 0.f, kacc1 = 0.f;
  float qs1[2] = {0.f, 0.f}, qs2[2] = {0.f, 0.f};
  f32x4 z = {0.f, 0.f, 0.f, 0.f};
  for (int st = 0; st < 4; ++st) {
    __syncthreads();
    {
      int py = by + (st >> 1) * 8 + (l >> 3);
      int px = bx + (st & 1) * 8 + (l & 7);
      enc_tile(encL, img, b, py, px, l, w, sWc, sWp, sF, sMu, sRs);
    }
    __syncthreads();
    f32x4 accQ[4][2], accK[4][2];
#pragma unroll
    for (int mt = 0; mt < 4; ++mt)
#pragma unroll
      for (int cc = 0; cc < 2; ++cc) { accQ[mt][cc] = z; accK[mt][cc] = z; }
#pragma unroll
    for (int kt = 0; kt < 8; ++kt) {
      h16x4 a[4];
#pragma unroll
      for (int mt = 0; mt < 4; ++mt) {
        f32x4 av = *(const f32x4*)(encL + (mt * 16 + (l & 15)) * 132 +
                                   kt * 16 + 4 * (l >> 4));
        h16x4 ah;
#pragma unroll
        for (int j = 0; j < 4; ++j) ah[j] = (_Float16)av[j];
        a[mt] = ah;
      }
#pragma unroll
      for (int mt = 0; mt < 4; ++mt) {
        accQ[mt][0] = mfma16(a[mt], bq[kt][0], accQ[mt][0]);
        accQ[mt][1] = mfma16(a[mt], bq[kt][1], accQ[mt][1]);
        accK[mt][0] = mfma16(a[mt], bk[kt][0], accK[mt][0]);
        accK[mt][1] = mfma16(a[mt], bk[kt][1], accK[mt][1]);
      }
    }
#pragma unroll
    for (int cc = 0; cc < 2; ++cc) {
      int g = 2 * w + cc;
      int cout = g * 16 + (l & 15);
      float qmu = sQmu[g], qrs = sQrs[g], kmu = sKmu[g], krs = sKrs[g];
      float kav = 0.f;
#pragma unroll
      for (int mt = 0; mt < 4; ++mt) {
        float qv[4];
#pragma unroll
        for (int r = 0; r < 4; ++r) {
          int m = 4 * (l >> 4) + r;
          float skip = encL[(mt * 16 + m) * 132 + cout];
          qv[r] = silu_f((accQ[mt][cc][r] - qmu) * qrs) + skip;
          kav += silu_f((accK[mt][cc][r] - kmu) * krs) + skip;
        }
        float s01 = qv[0] + qv[1], s23 = qv[2] + qv[3];
        s01 += __shfl_xor(s01, 32);
        s23 += __shfl_xor(s23, 32);
        if ((l >> 4) < 2) {
          int py2 = (by + (st >> 1) * 8 + 2 * mt) >> 1;
          int px2 = (bx + (st & 1) * 8 + (l >> 4) * 4) >> 1;
          size_t base = ((size_t)(b * NQ) + py2 * 112 + px2) * 128 + cout;
          float pv0 = s01 * 0.25f, pv1 = s23 * 0.25f;
          q_pool[base] = pv0;
          q_pool[base + 128] = pv1;
          qs1[cc] += pv0 + pv1;
          qs2[cc] += pv0 * pv0 + pv1 * pv1;
        }
      }
      if (cc == 0) kacc0 += kav; else kacc1 += kav;
    }
  }
  kacc0 += __shfl_xor(kacc0, 16); kacc0 += __shfl_xor(kacc0, 32);
  kacc1 += __shfl_xor(kacc1, 16); kacc1 += __shfl_xor(kacc1, 32);
  if (l < 16) {
    k_pool[((size_t)(b * 128) + (2 * w) * 16 + l) * NKk + tile] = kacc0 * (1.f / 256.f);
    k_pool[((size_t)(b * 128) + (2 * w + 1) * 16 + l) * NKk + tile] = kacc1 * (1.f / 256.f);
  }
#pragma unroll
  for (int cc = 0; cc < 2; ++cc) {
    float a1 = qs1[cc], a2 = qs2[cc];
    for (int m = 1; m < 64; m <<= 1) {
      a1 += __shfl_xor(a1, m);
      a2 += __shfl_xor(a2, m);
    }
    if (l == 0) {
      Qpart[(size_t)blockIdx.x * 16 + (2 * w + cc) * 2] = a1;
      Qpart[(size_t)blockIdx.x * 16 + (2 * w + cc) * 2 + 1] = a2;
    }
  }
}

// reduce Qpart -> murs2 (pooled-q GN stats)
__global__ __launch_bounds__(256) void k_qstatfin(
    const float* __restrict__ Qpart, float* __restrict__ murs2) {
  __shared__ float l1[4], l2[4];
  int b = blockIdx.x >> 3, g = blockIdx.x & 7, t = threadIdx.x;
  float s1 = 0.f, s2 = 0.f;
  if (t < 196) {
    s1 = Qpart[(size_t)(b * 196 + t) * 16 + g * 2];
    s2 = Qpart[(size_t)(b * 196 + t) * 16 + g * 2 + 1];
  }
  for (int m = 1; m < 64; m <<= 1) { s1 += __shfl_xor(s1, m); s2 += __shfl_xor(s2, m); }
  if ((t & 63) == 0) { l1[t >> 6] = s1; l2[t >> 6] = s2; }
  __syncthreads();
  if (t == 0) {
    float a = l1[0] + l1[1] + l1[2] + l1[3];
    float bq = l2[0] + l2[1] + l2[2] + l2[3];
    float invN = 1.f / (16.f * (float)NQ);
    float mu = a * invN;
    float var = bq * invN - mu * mu;
    murs2[blockIdx.x * 2] = mu;
    murs2[blockIdx.x * 2 + 1] = rsqrtf(var + EPS_GN);
  }
}

// ---------- GN stats (channel-major src[b][c][P]) ----------

__global__ __launch_bounds__(256) void k_gnstats(
    const float* __restrict__ src, float* __restrict__ murs, int P, float eps) {
  __shared__ float l1[4], l2[4];
  int b = blockIdx.x >> 3, g = blockIdx.x & 7, t = threadIdx.x;
  const float* base = src + ((size_t)(b * 128) + g * 16) * P;
  float s1 = 0.f, s2 = 0.f;
  for (int i = t; i < 16 * P; i += 256) {
    float v = base[i];
    s1 += v; s2 += v * v;
  }
  for (int m = 1; m < 64; m <<= 1) { s1 += __shfl_xor(s1, m); s2 += __shfl_xor(s2, m); }
  if ((t & 63) == 0) { l1[t >> 6] = s1; l2[t >> 6] = s2; }
  __syncthreads();
  if (t == 0) {
    float invN = 1.f / (16.f * (float)P);
    float a = l1[0] + l1[1] + l1[2] + l1[3];
    float bq = l2[0] + l2[1] + l2[2] + l2[3];
    float mu = a * invN;
    float var = bq * invN - mu * mu;
    murs[blockIdx.x * 2] = mu;
    murs[blockIdx.x * 2 + 1] = rsqrtf(var + eps);
  }
}

// ---------- features L2 normalize ----------

__global__ void k_fn(const float* __restrict__ feat, float* __restrict__ fn) {
  int b = blockIdx.x, p = threadIdx.x;
  if (p >= NKk) return;
  const float* fb = feat + (size_t)b * VD * NKk + p;
  float s = 0.f;
  for (int c = 0; c < VD; ++c) { float v = fb[c * NKk]; s += v * v; }
  float r = rsqrtf(fmaxf(s, 1e-24f));
  float* ob = fn + (size_t)b * VD * NKk + p;
  for (int c = 0; c < VD; ++c) ob[c * NKk] = fb[c * NKk] * r;
}

// ---------- kf enc_block conv (384->128, conv + proj skip) ----------

__global__ __launch_bounds__(256) void k_kfconv(
    const float* __restrict__ fn, const float* __restrict__ KFT,
    const float* __restrict__ KFPT,
    float* __restrict__ y_kf, float* __restrict__ skip_kf) {
  __shared__ float fnL[192 * 64];
  int t = threadIdx.x, p = t & 63, cq = t >> 6;
  int b = blockIdx.x >> 2, tile = blockIdx.x & 3;
  int p0 = tile * 49;
  int c0 = cq * 32, c0u = rfl(c0);
  float accy[32], accs[32];
#pragma unroll
  for (int i = 0; i < 32; ++i) { accy[i] = 0.f; accs[i] = 0.f; }
  for (int ch = 0; ch < 2; ++ch) {
    __syncthreads();
    for (int i = t; i < 192 * 64; i += 256) {
      int kk = i >> 6, pp = i & 63;
      float v = 0.f;
      if (pp < 49) v = fn[((size_t)(b * 384) + ch * 192 + kk) * NKk + p0 + pp];
      fnL[i] = v;
    }
    __syncthreads();
#pragma unroll 2
    for (int k = 0; k < 192; ++k) {
      float x = fnL[k * 64 + p];
      const float* wy = KFT + ((size_t)(ch * 192 + k)) * 128 + c0u;
      const float* wsk = KFPT + ((size_t)(ch * 192 + k)) * 128 + c0u;
#pragma unroll
      for (int i = 0; i < 32; ++i) {
        accy[i] = fmaf(wy[i], x, accy[i]);
        accs[i] = fmaf(wsk[i], x, accs[i]);
      }
    }
  }
  if (p < 49) {
#pragma unroll
    for (int i = 0; i < 32; ++i) {
      size_t off = (size_t)(b * 128 + c0 + i) * NKk + p0 + p;
      y_kf[off] = accy[i];
      skip_kf[off] = accs[i];
    }
  }
}

// ---------- SFT ----------

__global__ __launch_bounds__(256) void k_sft(
    const float* __restrict__ y_kf, const float* __restrict__ skip_kf,
    const float* __restrict__ kf_murs, const float* __restrict__ GT,
    const float* __restrict__ BT, const float* __restrict__ k_pool,
    const float* __restrict__ kgn_murs, float* __restrict__ k_final) {
  __shared__ float kfL[128 * 64];
  __shared__ float sMu[8], sRs[8], sGmu[8], sGrs[8];
  int t = threadIdx.x, p = t & 63, cq = t >> 6;
  int b = blockIdx.x >> 2, tile = blockIdx.x & 3;
  int p0 = tile * 49;
  if (t < 8) {
    sMu[t] = kf_murs[(b * 8 + t) * 2];
    sRs[t] = kf_murs[(b * 8 + t) * 2 + 1];
    sGmu[t] = kgn_murs[(b * 8 + t) * 2];
    sGrs[t] = kgn_murs[(b * 8 + t) * 2 + 1];
  }
  __syncthreads();
  for (int i = t; i < 128 * 64; i += 256) {
    int c = i >> 6, pp = i & 63;
    float v = 0.f;
    if (pp < 49) {
      size_t off = (size_t)(b * 128 + c) * NKk + p0 + pp;
      int g = c >> 4;
      v = silu_f((y_kf[off] - sMu[g]) * sRs[g]) + skip_kf[off];
    }
    kfL[i] = v;
  }
  __syncthreads();
  int c0 = cq * 32, c0u = rfl(c0);
  float ag[32], ab[32];
#pragma unroll
  for (int i = 0; i < 32; ++i) { ag[i] = 0.f; ab[i] = 0.f; }
  gemm32(ag, kfL, GT, p, c0u);
  gemm32(ab, kfL, BT, p, c0u);
  if (p < 49) {
#pragma unroll
    for (int i = 0; i < 32; ++i) {
      int c = c0 + i, g = c >> 4;
      size_t off = (size_t)(b * 128 + c) * NKk + p0 + p;
      float kn = (k_pool[off] - sGmu[g]) * sGrs[g];
      k_final[off] = fmaf(ag[i], kn, ab[i]);
    }
  }
}

// ---------- RMSNorm + projection (k side, VALU) ----------

__global__ __launch_bounds__(256) void k_rmsproj(
    const float* __restrict__ src, const float* __restrict__ WTs,
    const float* __restrict__ bias, float* __restrict__ dst, int NP) {
  __shared__ float xL[128 * 64];
  __shared__ float msP[4][64];
  int t = threadIdx.x, p = t & 63, cq = t >> 6;
  int nt = (NP + 63) / 64;
  int b = blockIdx.x / nt, tile = blockIdx.x % nt;
  int p0 = tile * 64;
  float ss = 0.f;
#pragma unroll
  for (int i = 0; i < 32; ++i) {
    int c = cq * 32 + i;
    float v = (p0 + p < NP) ? src[(size_t)(b * 128 + c) * NP + p0 + p] : 0.f;
    xL[c * 64 + p] = v;
    ss += v * v;
  }
  msP[cq][p] = ss;
  __syncthreads();
  float ms = (msP[0][p] + msP[1][p] + msP[2][p] + msP[3][p]) * (1.f / 128.f);
  float rr = rsqrtf(ms + EPS_RMS);
  int c0u = rfl(cq * 32);
  float acc[32];
#pragma unroll
  for (int i = 0; i < 32; ++i) acc[i] = 0.f;
  gemm32(acc, xL, WTs, p, c0u);
  if (p0 + p < NP) {
#pragma unroll
    for (int i = 0; i < 32; ++i)
      dst[((size_t)b * NP + p0 + p) * 128 + c0u + i] = acc[i] * rr + bias[c0u + i];
  }
}

// ---------- 3x3 conv on GN(q_pool), MFMA ----------

__global__ __launch_bounds__(256) void k_conv3m(
    const float* __restrict__ q_pool, const float* __restrict__ murs2,
    const _Float16* __restrict__ W3B, float* __restrict__ qconv,
    float* __restrict__ msq) {
  __shared__ __align__(16) _Float16 w3L[16384];
  __shared__ float sMu[8], sRs[8];
  int t = threadIdx.x, l = t & 63, w = t >> 6;
  int b = blockIdx.x / 98, reg = blockIdx.x % 98;
  int y0 = (reg / 7) * 8, x0 = (reg % 7) * 16;
  if (t < 8) { sMu[t] = murs2[(b * 8 + t) * 2]; sRs[t] = murs2[(b * 8 + t) * 2 + 1]; }
  f32x4 z = {0.f, 0.f, 0.f, 0.f};
  f32x4 acc[2][8];
#pragma unroll
  for (int rx = 0; rx < 2; ++rx)
#pragma unroll
    for (int ct = 0; ct < 8; ++ct) acc[rx][ct] = z;
  int lm = l & 15;
  int mrow = lm >> 3, mcol = lm & 7;
  for (int tap = 0; tap < 9; ++tap) {
    int dy = tap / 3 - 1, dx = tap % 3 - 1;
    __syncthreads();
    for (int i = t; i < 4096; i += 256)
      ((h16x4*)w3L)[i] = ((const h16x4*)W3B)[tap * 4096 + i];
    __syncthreads();
    int py = y0 + 2 * w + mrow + dy;
    int pxb = x0 + mcol + dx;
    bool oky = (py >= 0) && (py < 112);
#pragma unroll
    for (int kt = 0; kt < 8; ++kt) {
      float mu = sMu[kt], rs = sRs[kt];
      h16x4 a[2];
#pragma unroll
      for (int rx = 0; rx < 2; ++rx) {
        int px = pxb + rx * 8;
        bool ok = oky && (px >= 0) && (px < 112);
        h16x4 ah = {(_Float16)0.f, (_Float16)0.f, (_Float16)0.f, (_Float16)0.f};
        if (ok) {
          f32x4 v = *(const f32x4*)(q_pool + ((size_t)(b * NQ) + py * 112 + px) * 128 +
                                    kt * 16 + 4 * (l >> 4));
#pragma unroll
          for (int j = 0; j < 4; ++j) ah[j] = (_Float16)((v[j] - mu) * rs);
        }
        a[rx] = ah;
      }
#pragma unroll
      for (int ct = 0; ct < 8; ++ct) {
        h16x4 bf = ((const h16x4*)w3L)[(kt * 8 + ct) * 64 + l];
        acc[0][ct] = mfma16(a[0], bf, acc[0][ct]);
        acc[1][ct] = mfma16(a[1], bf, acc[1][ct]);
      }
    }
  }
#pragma unroll
  for (int rx = 0; rx < 2; ++rx) {
    float sq[4] = {0.f, 0.f, 0.f, 0.f};
#pragma unroll
    for (int ct = 0; ct < 8; ++ct)
#pragma unroll
      for (int r = 0; r < 4; ++r) sq[r] += acc[rx][ct][r] * acc[rx][ct][r];
#pragma unroll
    for (int r = 0; r < 4; ++r) {
      for (int m = 1; m < 16; m <<= 1) sq[r] += __shfl_xor(sq[r], m);
      int mm = 4 * (l >> 4) + r;
      int py = y0 + 2 * w + (mm >> 3), px = x0 + rx * 8 + (mm & 7);
      size_t pb = (size_t)(b * NQ) + py * 112 + px;
      if ((l & 15) == 0) msq[pb] = sq[r];
#pragma unroll
      for (int ct = 0; ct < 8; ++ct)
        qconv[pb * 128 + ct * 16 + (l & 15)] = acc[rx][ct][r];
    }
  }
}

// ---------- RMSNorm + proj (q side, MFMA) ----------

__global__ __launch_bounds__(256) void k_rmsq(
    const float* __restrict__ qconv, const _Float16* __restrict__ QPB,
    const float* __restrict__ msq, const float* __restrict__ bias,
    float* __restrict__ qp) {
  __shared__ __align__(16) _Float16 wL[16384];
  int t = threadIdx.x, l = t & 63, w = t >> 6;
  int b = blockIdx.x / 196, tile = blockIdx.x % 196;
  for (int i = t; i < 4096; i += 256)
    ((h16x4*)wL)[i] = ((const h16x4*)QPB)[i];
  __syncthreads();
  int p0 = tile * 64 + w * 16;
  f32x4 z = {0.f, 0.f, 0.f, 0.f};
  f32x4 acc[8];
#pragma unroll
  for (int ct = 0; ct < 8; ++ct) acc[ct] = z;
#pragma unroll
  for (int kt = 0; kt < 8; ++kt) {
    f32x4 av = *(const f32x4*)(qconv + ((size_t)(b * NQ) + p0 + (l & 15)) * 128 +
                               kt * 16 + 4 * (l >> 4));
    h16x4 ah;
#pragma unroll
    for (int j = 0; j < 4; ++j) ah[j] = (_Float16)av[j];
#pragma unroll
    for (int ct = 0; ct < 8; ++ct)
      acc[ct] = mfma16(ah, ((const h16x4*)wL)[(kt * 8 + ct) * 64 + l], acc[ct]);
  }
#pragma unroll
  for (int r = 0; r < 4; ++r) {
    int pix = p0 + 4 * (l >> 4) + r;
    float rr = rsqrtf(msq[(size_t)(b * NQ) + pix] * (1.f / 128.f) + EPS_RMS);
#pragma unroll
    for (int ct = 0; ct < 8; ++ct)
      qp[((size_t)(b * NQ) + pix) * 128 + ct * 16 + (l & 15)] =
          acc[ct][r] * rr + bias[ct * 16 + (l & 15)];
  }
}

// ---------- attention: QK^T + softmax + head-mean ----------

__global__ __launch_bounds__(256) void k_attn1m(
    const float* __restrict__ qp, const float* __restrict__ kpb,
    float* __restrict__ P) {
  __shared__ float sP[4][16][212];
  int t = threadIdx.x, l = t & 63, h = t >> 6;
  int b = blockIdx.x / 784, qt = blockIdx.x % 784;
  int q0 = qt * 16;
  constexpr float SC = 0.17677669529663687f;  // 1/sqrt(32)
  h16x4 aq[2];
#pragma unroll
  for (int kt = 0; kt < 2; ++kt) {
    f32x4 v = *(const f32x4*)(qp + ((size_t)(b * NQ) + q0 + (l & 15)) * 128 +
                              h * 32 + kt * 16 + 4 * (l >> 4));
    h16x4 ah;
#pragma unroll
    for (int j = 0; j < 4; ++j) ah[j] = (_Float16)v[j];
    aq[kt] = ah;
  }
  f32x4 z = {0.f, 0.f, 0.f, 0.f};
  f32x4 acc[13];
#pragma unroll
  for (int nt = 0; nt < 13; ++nt) acc[nt] = z;
#pragma unroll
  for (int nt = 0; nt < 13; ++nt) {
    int key = nt * 16 + (l & 15);
    bool ok = key < 196;
#pragma unroll
    for (int kt = 0; kt < 2; ++kt) {
      h16x4 bf = {(_Float16)0.f, (_Float16)0.f, (_Float16)0.f, (_Float16)0.f};
      if (ok) {
        f32x4 v = *(const f32x4*)(kpb + ((size_t)(b * 196) + key) * 128 +
                                  h * 32 + kt * 16 + 4 * (l >> 4));
#pragma unroll
        for (int j = 0; j < 4; ++j) bf[j] = (_Float16)v[j];
      }
      acc[nt] = mfma16(aq[kt], bf, acc[nt]);
    }
  }
#pragma unroll
  for (int r = 0; r < 4; ++r) {
    float mx = -3e38f;
#pragma unroll
    for (int nt = 0; nt < 13; ++nt) {
      bool ok = nt * 16 + (l & 15) < 196;
      float v = ok ? acc[nt][r] * SC : -3e38f;
      acc[nt][r] = v;
      mx = fmaxf(mx, v);
    }
    for (int m = 1; m < 16; m <<= 1) mx = fmaxf(mx, __shfl_xor(mx, m));
    float sum = 0.f;
#pragma unroll
    for (int nt = 0; nt < 13; ++nt) {
      bool ok = nt * 16 + (l & 15) < 196;
      float e = ok ? __expf(acc[nt][r] - mx) : 0.f;
      acc[nt][r] = e;
      sum += e;
    }
    for (int m = 1; m < 16; m <<= 1) sum += __shfl_xor(sum, m);
    float inv = 1.f / sum;
#pragma unroll
    for (int nt = 0; nt < 13; ++nt)
      sP[h][4 * (l >> 4) + r][nt * 16 + (l & 15)] = acc[nt][r] * inv;
  }
  __syncthreads();
  for (int i = t; i < 16 * 208; i += 256) {
    int q = i / 208, k = i % 208;
    float v = 0.f;
    if (k < 196)
      v = 0.25f * (sP[0][q][k] + sP[1][q][k] + sP[2][q][k] + sP[3][q][k]);
    P[((size_t)(b * NQ) + q0 + q) * 208 + k] = v;
  }
}

// ---------- attention PV (vs raw features), MFMA ----------

__global__ __launch_bounds__(256) void k_attn2m(
    const float* __restrict__ P, const float* __restrict__ feat,
    float* __restrict__ out) {
  __shared__ __align__(16) _Float16 fL[384 * 68];
  int t = threadIdx.x, l = t & 63, w = t >> 6;
  int b = blockIdx.x / 196, qt = blockIdx.x % 196;
  int qw = qt * 64 + w * 16;
  f32x4 z = {0.f, 0.f, 0.f, 0.f};
  f32x4 acc[24];
#pragma unroll
  for (int mt = 0; mt < 24; ++mt) acc[mt] = z;
  const float* Prow = P + ((size_t)(b * NQ) + qw + (l & 15)) * 208 + 4 * (l >> 4);
#pragma unroll
  for (int ch = 0; ch < 4; ++ch) {
    __syncthreads();
    for (int i = t; i < 384 * 64; i += 256) {
      int d = i >> 6, kk = i & 63;
      int key = ch * 64 + kk;
      float v = (key < 196) ? feat[((size_t)(b * 384) + d) * 196 + key] : 0.f;
      fL[d * 68 + kk] = (_Float16)v;
    }
    __syncthreads();
    const int nkt = (ch < 3) ? 4 : 1;
#pragma unroll
    for (int kc = 0; kc < 4; ++kc) {
      if (kc >= nkt) break;
      int kt = ch * 4 + kc;
      f32x4 pv = *(const f32x4*)(Prow + kt * 16);
      h16x4 bp;
#pragma unroll
      for (int j = 0; j < 4; ++j) bp[j] = (_Float16)pv[j];
#pragma unroll
      for (int mt = 0; mt < 24; ++mt) {
        h16x4 af = *(const h16x4*)(fL + (mt * 16 + (l & 15)) * 68 +
                                   kc * 16 + 4 * (l >> 4));
        acc[mt] = mfma16(af, bp, acc[mt]);
      }
    }
  }
#pragma unroll
  for (int mt = 0; mt < 24; ++mt)
#pragma unroll
    for (int r = 0; r < 4; ++r) {
      int d = mt * 16 + 4 * (l >> 4) + r;
      out[((size_t)(b * 384) + d) * NQ + qw + (l & 15)] = acc[mt][r];
    }
}

}  // namespace

extern "C" void kernel_launch(void* const* d_in, const int* in_sizes, int n_in,
                              void* d_out, int out_size, void* d_ws,
                              size_t ws_size, hipStream_t stream) {
  (void)in_sizes; (void)n_in; (void)out_size; (void)ws_size;
  const float* image        = (const float*)d_in[0];
  const float* features     = (const float*)d_in[1];
  const float* rope_f       = (const float*)d_in[2];
  const float* img_conv_w   = (const float*)d_in[3];
  const float* img_proj_w   = (const float*)d_in[4];
  const float* qenc_w       = (const float*)d_in[5];
  const float* kenc_w       = (const float*)d_in[6];
  const float* kfeat_conv_w = (const float*)d_in[7];
  const float* kfeat_proj_w = (const float*)d_in[8];
  const float* sft_gamma_w  = (const float*)d_in[9];
  const float* sft_beta_w   = (const float*)d_in[10];
  const float* block_conv_w = (const float*)d_in[11];
  const float* rms_q_w      = (const float*)d_in[12];
  const float* rms_k_w      = (const float*)d_in[13];
  const float* q_proj_w     = (const float*)d_in[14];
  const float* q_proj_b     = (const float*)d_in[15];
  const float* k_proj_w     = (const float*)d_in[16];
  const float* k_proj_b     = (const float*)d_in[17];
  float* out = (float*)d_out;
  float* ws = (float*)d_ws;

  size_t off = 0;
  auto alloc = [&](size_t n) {
    size_t r = off;
    off += (n + 63) & ~(size_t)63;
    return r;
  };
  _Float16* WqB = (_Float16*)(ws + alloc(8192));
  _Float16* WkB = (_Float16*)(ws + alloc(8192));
  _Float16* QPB = (_Float16*)(ws + alloc(8192));
  _Float16* W3B = (_Float16*)(ws + alloc(73728));
  float* KFT      = ws + alloc(49152);
  float* KFPT     = ws + alloc(49152);
  float* GT       = ws + alloc(16384);
  float* BT       = ws + alloc(16384);
  float* KPT      = ws + alloc(16384);
  float* imgpart  = ws + alloc(2304);
  float* img_murs = ws + alloc(64);
  float* qk_murs  = ws + alloc(128);
  float* murs2    = ws + alloc(64);
  float* kgn_murs = ws + alloc(64);
  float* kf_murs  = ws + alloc(64);
  float* G        = ws + alloc(65536);
  float* mvec     = ws + alloc(512);
  float* Qpart    = ws + alloc((size_t)BB * 196 * 16);
  float* y_kf     = ws + alloc(100352);
  float* skip_kf  = ws + alloc(100352);
  float* k_final  = ws + alloc(100352);
  float* k_pool   = ws + alloc(100352);
  float* kpb      = ws + alloc(100352);
  float* msq      = ws + alloc(50176);
  float* RA       = ws + alloc((size_t)BB * NQ * 128);      // fnb -> q_pool -> qp
  float* RB       = ws + alloc((size_t)BB * NQ * 208);      // Gpart -> qconv -> P
  float* fnb    = RA;
  float* q_pool = RA;
  float* qp     = RA;
  float* Gpart  = RB;
  float* mpart  = RB + (size_t)BB * 98 * 16384;
  float* qconv  = RB;
  float* P      = RB;

  // fused weight prep (one launch)
  k_prep<<<1344, 256, 0, stream>>>(qenc_w, kenc_w, q_proj_w, rms_q_w,
                                   block_conv_w, kfeat_conv_w, kfeat_proj_w,
                                   sft_gamma_w, sft_beta_w, k_proj_w, rms_k_w,
                                   WqB, WkB, QPB, W3B, KFT, KFPT, GT, BT, KPT);

  // image GN stats (Gram trick over 3 channels)
  k_imgstat1<<<BB * 64, 256, 0, stream>>>(image, imgpart);
  k_imgstat2<<<BB, 128, 0, stream>>>(imgpart, img_conv_w, img_murs);

  // kf branch early (fnb aliases RA before passA writes q_pool)
  k_fn<<<BB, 256, 0, stream>>>(features, fnb);
  k_kfconv<<<BB * 4, 256, 0, stream>>>(fnb, KFT, KFPT, y_kf, skip_kf);
  k_gnstats<<<32, 256, 0, stream>>>(y_kf, kf_murs, NKk, EPS_GN);

  // Gram of enc -> GN stats for q/k 1x1 convs
  k_gram<<<BB * 98, 256, 0, stream>>>(image, rope_f, img_conv_w, img_proj_w,
                                      img_murs, Gpart, mpart);
  k_gred<<<BB * 64, 256, 0, stream>>>(Gpart, mpart, G, mvec);
  k_gstats<<<64, 256, 0, stream>>>(G, mvec, qenc_w, kenc_w, qk_murs);

  // apply q/k enc_blocks + pooling (MFMA) + fused pooled-q stats partials
  k_passA2<<<BB * 196, 256, 0, stream>>>(image, rope_f, img_conv_w, img_proj_w,
                                         img_murs, qk_murs, WqB, WkB,
                                         q_pool, k_pool, Qpart);
  k_qstatfin<<<32, 256, 0, stream>>>(Qpart, murs2);
  k_gnstats<<<32, 256, 0, stream>>>(k_pool, kgn_murs, NKk, EPS_GN);

  // k side (tiny, VALU)
  k_sft<<<BB * 4, 256, 0, stream>>>(y_kf, skip_kf, kf_murs, GT, BT, k_pool,
                                    kgn_murs, k_final);
  k_rmsproj<<<BB * 4, 256, 0, stream>>>(k_final, KPT, k_proj_b, kpb, NKk);

  // q side (MFMA)
  k_conv3m<<<BB * 98, 256, 0, stream>>>(q_pool, murs2, W3B, qconv, msq);
  k_rmsq<<<BB * 196, 256, 0, stream>>>(qconv, QPB, msq, q_proj_b, qp);

  // attention
  k_attn1m<<<BB * 784, 256, 0, stream>>>(qp, kpb, P);
  k_attn2m<<<BB * 196, 256, 0, stream>>>(P, features, out);
}

// Round 5
// 726.677 us; speedup vs baseline: 2.7960x; 1.1726x over previous
//
#include <hip/hip_runtime.h>
#include <cstdint>
#include <cstddef>

#define DEV __device__ __forceinline__

namespace {

constexpr int BB   = 4;
constexpr int HWP  = 50176;   // 224*224
constexpr int NQ   = 12544;   // 112*112
constexpr int NKk  = 196;     // 14*14
constexpr int VD   = 384;
constexpr float EPS_GN  = 1e-5f;
constexpr float EPS_RMS = 1.1920929e-7f;

typedef __attribute__((ext_vector_type(4))) float f32x4;
typedef __attribute__((ext_vector_type(4))) _Float16 h16x4;

DEV float silu_f(float z) { return z / (1.f + __expf(-z)); }
DEV int rfl(int v) { return __builtin_amdgcn_readfirstlane(v); }

DEV f32x4 mfma16(h16x4 a, h16x4 b, f32x4 c) {
  return __builtin_amdgcn_mfma_f32_16x16x16f16(a, b, c, 0, 0, 0);
}

// fp32 scalar-broadcast GEMM for the small k-branch kernels (K=128, 64 px)
DEV void gemm32(float* acc, const float* encL, const float* __restrict__ WT,
                int p, int c0u) {
#pragma unroll 4
  for (int k = 0; k < 128; ++k) {
    float x = encL[k * 64 + p];
    const float* w = WT + (size_t)k * 128 + c0u;
#pragma unroll
    for (int i = 0; i < 32; ++i) acc[i] = fmaf(w[i], x, acc[i]);
  }
}

// Recompute enc (img 1x1 conv -> GN -> SiLU -> +proj skip -> RoPE) for one
// 64-pixel tile into LDS encL[64][132] f32 (pixel-major, padded).
// RoPE cos/sin come from precomputed tables cosT/sinT[224][64].
DEV void enc_tile(float* encL, const float* __restrict__ img, int b,
                  int py, int px, int p, int cq,
                  const float* sWc, const float* sWp,
                  const float* __restrict__ cosT, const float* __restrict__ sinT,
                  const float* sMu, const float* sRs) {
  const float* ip = img + (size_t)b * 3 * HWP + py * 224 + px;
  float x0 = ip[0], x1 = ip[HWP], x2 = ip[2 * HWP];
  const float* cy = cosT + py * 64 + cq * 16;
  const float* sy = sinT + py * 64 + cq * 16;
  const float* cx = cosT + px * 64 + cq * 16;
  const float* sx = sinT + px * 64 + cq * 16;
#pragma unroll
  for (int jj = 0; jj < 4; ++jj) {
    f32x4 cyv = *(const f32x4*)(cy + jj * 4);
    f32x4 syv = *(const f32x4*)(sy + jj * 4);
    f32x4 cxv = *(const f32x4*)(cx + jj * 4);
    f32x4 sxv = *(const f32x4*)(sx + jj * 4);
    f32x4 lo, hi;
#pragma unroll
    for (int u = 0; u < 4; ++u) {
      int d = cq * 16 + jj * 4 + u;
      int c2 = d + 64;
      float y1 = sWc[d * 3] * x0 + sWc[d * 3 + 1] * x1 + sWc[d * 3 + 2] * x2;
      float s1 = sWp[d * 3] * x0 + sWp[d * 3 + 1] * x1 + sWp[d * 3 + 2] * x2;
      float y2 = sWc[c2 * 3] * x0 + sWc[c2 * 3 + 1] * x1 + sWc[c2 * 3 + 2] * x2;
      float s2 = sWp[c2 * 3] * x0 + sWp[c2 * 3 + 1] * x1 + sWp[c2 * 3 + 2] * x2;
      int g1 = d >> 4, g2 = g1 + 4;
      float t1 = silu_f((y1 - sMu[g1]) * sRs[g1]) + s1;
      float t2 = silu_f((y2 - sMu[g2]) * sRs[g2]) + s2;
      lo[u] = t1 * cyv[u] - t2 * syv[u];
      hi[u] = t2 * cxv[u] + t1 * sxv[u];
    }
    *(f32x4*)(encL + p * 132 + cq * 16 + jj * 4) = lo;
    *(f32x4*)(encL + p * 132 + 64 + cq * 16 + jj * 4) = hi;
  }
}

// ---------- fused weight prep (one launch) ----------
// work-item layout:
//  [0,16384)            WqB  = pack16(qenc_w)
//  [16384,32768)        WkB  = pack16(kenc_w)
//  [32768,49152)        QPB  = pack16(q_proj_w, rms_q_w)
//  [49152,196608)       W3B  = packw3(block_conv_w)
//  [196608,245760)      KFT  = t2d(kfeat_conv_w, 128x384)
//  [245760,294912)      KFPT = t2d(kfeat_proj_w, 128x384)
//  [294912,311296)      GT   = t2d(sft_gamma_w)
//  [311296,327680)      BT   = t2d(sft_beta_w)
//  [327680,344064)      KPT  = t2d(k_proj_w, rms_k_w)
//  [344064,358400)      cosT/sinT rope tables (224x64)
//  [358400,677888)      featB = features packed into MFMA A-frag order fp16
//                       (BB*13*24*64*4 = 319488 items, one fp16 each)
DEV void pack16_one(int id, const float* W, const float* rowscale,
                    _Float16* dst) {
  int j = id & 3, l = (id >> 2) & 63, tile = id >> 8;
  int ct = tile & 7, kt = tile >> 3;
  int ci = kt * 16 + 4 * (l >> 4) + j;
  int co = ct * 16 + (l & 15);
  float v = W[(size_t)co * 128 + ci];
  if (rowscale) v *= rowscale[ci];
  dst[id] = (_Float16)v;
}
DEV void t2d_one(int idx, const float* src, float* dst, int CO, int CI,
                 const float* rowscale) {
  int co = idx / CI, ci = idx % CI;
  float v = src[idx];
  if (rowscale) v *= rowscale[ci];
  dst[(size_t)ci * CO + co] = v;
}

__global__ __launch_bounds__(256) void k_prep(
    const float* __restrict__ qenc_w, const float* __restrict__ kenc_w,
    const float* __restrict__ q_proj_w, const float* __restrict__ rms_q_w,
    const float* __restrict__ block_conv_w,
    const float* __restrict__ kfeat_conv_w, const float* __restrict__ kfeat_proj_w,
    const float* __restrict__ sft_gamma_w, const float* __restrict__ sft_beta_w,
    const float* __restrict__ k_proj_w, const float* __restrict__ rms_k_w,
    const float* __restrict__ ropef, const float* __restrict__ feat,
    _Float16* __restrict__ WqB, _Float16* __restrict__ WkB,
    _Float16* __restrict__ QPB, _Float16* __restrict__ W3B,
    float* __restrict__ KFT, float* __restrict__ KFPT,
    float* __restrict__ GT, float* __restrict__ BT, float* __restrict__ KPT,
    float* __restrict__ cosT, float* __restrict__ sinT,
    _Float16* __restrict__ featB) {
  int idx = blockIdx.x * 256 + threadIdx.x;
  if (idx < 16384) {
    pack16_one(idx, qenc_w, nullptr, WqB);
  } else if (idx < 32768) {
    pack16_one(idx - 16384, kenc_w, nullptr, WkB);
  } else if (idx < 49152) {
    pack16_one(idx - 32768, q_proj_w, rms_q_w, QPB);
  } else if (idx < 196608) {
    int id = idx - 49152;
    int j = id & 3, l = (id >> 2) & 63, tile = (id >> 8) & 63, tap = id >> 14;
    int ct = tile & 7, kt = tile >> 3;
    int ci = kt * 16 + 4 * (l >> 4) + j;
    int co = ct * 16 + (l & 15);
    W3B[id] = (_Float16)block_conv_w[((size_t)co * 128 + ci) * 9 + tap];
  } else if (idx < 245760) {
    t2d_one(idx - 196608, kfeat_conv_w, KFT, 128, 384, nullptr);
  } else if (idx < 294912) {
    t2d_one(idx - 245760, kfeat_proj_w, KFPT, 128, 384, nullptr);
  } else if (idx < 311296) {
    t2d_one(idx - 294912, sft_gamma_w, GT, 128, 128, nullptr);
  } else if (idx < 327680) {
    t2d_one(idx - 311296, sft_beta_w, BT, 128, 128, nullptr);
  } else if (idx < 344064) {
    t2d_one(idx - 327680, k_proj_w, KPT, 128, 128, rms_k_w);
  } else if (idx < 358400) {
    int id = idx - 344064;            // pos*64 + d
    int pos = id >> 6, d = id & 63;
    float a = (pos + 0.5f) * (1.f / 224.f) * ropef[d];
    float s, c;
    __sincosf(a, &s, &c);
    cosT[id] = c;
    sinT[id] = s;
  } else if (idx < 677888) {
    int id = idx - 358400;            // (((b*13+kt)*24+dt)*64+l)*4+j
    int j = id & 3, l = (id >> 2) & 63;
    int rest = id >> 8;
    int dt = rest % 24;
    int kt = (rest / 24) % 13;
    int b = rest / (24 * 13);
    int key = kt * 16 + 4 * (l >> 4) + j;
    int d = dt * 16 + (l & 15);
    float v = (key < 196) ? feat[((size_t)(b * 384) + d) * 196 + key] : 0.f;
    featB[id] = (_Float16)v;
  }
}

// ---------- image GN stats via 3x3 Gram ----------

__global__ __launch_bounds__(256) void k_imgstat1(
    const float* __restrict__ img, float* __restrict__ part) {
  __shared__ float lds[4][9];
  int b = blockIdx.x >> 6, blk = blockIdx.x & 63;
  int t = threadIdx.x;
  float a[9];
#pragma unroll
  for (int j = 0; j < 9; ++j) a[j] = 0.f;
  const float* ib = img + (size_t)b * 3 * HWP;
  for (int pix = blk * 784 + t; pix < blk * 784 + 784; pix += 256) {
    float x0 = ib[pix], x1 = ib[HWP + pix], x2 = ib[2 * HWP + pix];
    a[0] += x0; a[1] += x1; a[2] += x2;
    a[3] += x0 * x0; a[4] += x0 * x1; a[5] += x0 * x2;
    a[6] += x1 * x1; a[7] += x1 * x2; a[8] += x2 * x2;
  }
#pragma unroll
  for (int j = 0; j < 9; ++j)
    for (int m = 1; m < 64; m <<= 1) a[j] += __shfl_xor(a[j], m);
  if ((t & 63) == 0)
    for (int j = 0; j < 9; ++j) lds[t >> 6][j] = a[j];
  __syncthreads();
  if (t < 9)
    part[(size_t)blockIdx.x * 9 + t] =
        lds[0][t] + lds[1][t] + lds[2][t] + lds[3][t];
}

__global__ __launch_bounds__(128) void k_imgstat2(
    const float* __restrict__ part, const float* __restrict__ wimg,
    float* __restrict__ img_murs) {
  __shared__ float MG[9];
  int b = blockIdx.x, t = threadIdx.x;
  if (t < 9) {
    float s = 0.f;
    for (int i = 0; i < 64; ++i) s += part[(size_t)(b * 64 + i) * 9 + t];
    MG[t] = s;
  }
  __syncthreads();
  int c = t;
  float w0 = wimg[c * 3], w1 = wimg[c * 3 + 1], w2 = wimg[c * 3 + 2];
  float s1 = w0 * MG[0] + w1 * MG[1] + w2 * MG[2];
  float s2 = w0 * w0 * MG[3] + w1 * w1 * MG[6] + w2 * w2 * MG[8] +
             2.f * (w0 * w1 * MG[4] + w0 * w2 * MG[5] + w1 * w2 * MG[7]);
  for (int m = 1; m < 16; m <<= 1) {
    s1 += __shfl_xor(s1, m);
    s2 += __shfl_xor(s2, m);
  }
  if ((c & 15) == 0) {
    int g = c >> 4;
    float invN = 1.f / (16.f * HWP);
    float mu = s1 * invN;
    float var = s2 * invN - mu * mu;
    img_murs[b * 16 + g] = mu;
    img_murs[b * 16 + 8 + g] = rsqrtf(var + EPS_GN);
  }
}

// ---------- Gram of enc ----------

__global__ __launch_bounds__(256) void k_gram(
    const float* __restrict__ img, const float* __restrict__ cosT,
    const float* __restrict__ sinT,
    const float* __restrict__ wimg, const float* __restrict__ wimgp,
    const float* __restrict__ img_murs,
    float* __restrict__ Gpart, float* __restrict__ mpart) {
  __shared__ __align__(16) float encL[64 * 132];
  __shared__ float sWc[384], sWp[384], sMu[8], sRs[8];
  int t = threadIdx.x, l = t & 63, w = t >> 6;
  int b = blockIdx.x / 98, blk = blockIdx.x % 98;
  for (int i = t; i < 384; i += 256) { sWc[i] = wimg[i]; sWp[i] = wimgp[i]; }
  if (t < 8) { sMu[t] = img_murs[b * 16 + t]; sRs[t] = img_murs[b * 16 + 8 + t]; }
  f32x4 acc[2][8];
  f32x4 macc[2];
  f32x4 z = {0.f, 0.f, 0.f, 0.f};
#pragma unroll
  for (int e = 0; e < 2; ++e) {
    macc[e] = z;
#pragma unroll
    for (int nt = 0; nt < 8; ++nt) acc[e][nt] = z;
  }
  h16x4 hone = {(_Float16)1.f, (_Float16)1.f, (_Float16)1.f, (_Float16)1.f};
  for (int s = 0; s < 8; ++s) {
    __syncthreads();
    int pix = (blk * 8 + s) * 64 + l;
    int py = pix / 224, px = pix % 224;
    enc_tile(encL, img, b, py, px, l, w, sWc, sWp, cosT, sinT, sMu, sRs);
    __syncthreads();
#pragma unroll
    for (int kt = 0; kt < 4; ++kt) {
      int pb = kt * 16 + 4 * (l >> 4);
      h16x4 a[2];
#pragma unroll
      for (int e = 0; e < 2; ++e) {
        int c = (2 * w + e) * 16 + (l & 15);
        h16x4 av;
#pragma unroll
        for (int j = 0; j < 4; ++j) av[j] = (_Float16)encL[(pb + j) * 132 + c];
        a[e] = av;
        macc[e] = mfma16(av, hone, macc[e]);
      }
#pragma unroll
      for (int nt = 0; nt < 8; ++nt) {
        int c = nt * 16 + (l & 15);
        h16x4 bv;
#pragma unroll
        for (int j = 0; j < 4; ++j) bv[j] = (_Float16)encL[(pb + j) * 132 + c];
        acc[0][nt] = mfma16(a[0], bv, acc[0][nt]);
        acc[1][nt] = mfma16(a[1], bv, acc[1][nt]);
      }
    }
  }
  float* gp = Gpart + (size_t)(b * 98 + blk) * 16384;
#pragma unroll
  for (int e = 0; e < 2; ++e)
#pragma unroll
    for (int nt = 0; nt < 8; ++nt)
#pragma unroll
      for (int r = 0; r < 4; ++r) {
        int row = (2 * w + e) * 16 + 4 * (l >> 4) + r;
        int col = nt * 16 + (l & 15);
        gp[row * 128 + col] = acc[e][nt][r];
      }
  if ((l & 15) == 0) {
    float* mp = mpart + (size_t)(b * 98 + blk) * 128;
#pragma unroll
    for (int e = 0; e < 2; ++e)
#pragma unroll
      for (int r = 0; r < 4; ++r)
        mp[(2 * w + e) * 16 + 4 * (l >> 4) + r] = macc[e][r];
  }
}

__global__ void k_gred(const float* __restrict__ Gpart,
                       const float* __restrict__ mpart,
                       float* __restrict__ G, float* __restrict__ mvec) {
  int b = blockIdx.x >> 6, chunk = blockIdx.x & 63;
  int idx = chunk * 256 + threadIdx.x;
  float s = 0.f;
  for (int i = 0; i < 98; ++i) s += Gpart[(size_t)(b * 98 + i) * 16384 + idx];
  G[(size_t)b * 16384 + idx] = s;
  if (idx < 128) {
    float sm = 0.f;
    for (int i = 0; i < 98; ++i) sm += mpart[(size_t)(b * 98 + i) * 128 + idx];
    mvec[b * 128 + idx] = sm;
  }
}

// stats for q/k 1x1 convs from Gram: E[y]=w.m, E[y^2]=w^T G w
__global__ __launch_bounds__(256) void k_gstats(
    const float* __restrict__ G, const float* __restrict__ mvec,
    const float* __restrict__ qw, const float* __restrict__ kw,
    float* __restrict__ qk_murs) {
  __shared__ float red1[4], red2[4];
  int bi = blockIdx.x;               // conv*32 + b*8 + g
  int conv = bi >> 5, b = (bi >> 3) & 3, g = bi & 7;
  const float* W = conv ? kw : qw;
  int t = threadIdx.x;
  int c = g * 16 + (t >> 4);
  int i0 = (t & 15) * 8;
  const float* wc = W + (size_t)c * 128;
  const float* Gb = G + (size_t)b * 16384;
  const float* mb = mvec + b * 128;
  float s1 = 0.f, s2 = 0.f;
  for (int i = i0; i < i0 + 8; ++i) {
    float gi = 0.f;
    for (int j = 0; j < 128; ++j) gi += Gb[i * 128 + j] * wc[j];
    s2 += wc[i] * gi;
    s1 += wc[i] * mb[i];
  }
  for (int m = 1; m < 64; m <<= 1) { s1 += __shfl_xor(s1, m); s2 += __shfl_xor(s2, m); }
  if ((t & 63) == 0) { red1[t >> 6] = s1; red2[t >> 6] = s2; }
  __syncthreads();
  if (t == 0) {
    float S1 = red1[0] + red1[1] + red1[2] + red1[3];
    float S2 = red2[0] + red2[1] + red2[2] + red2[3];
    float invN = 1.f / 802816.f;
    float mu = S1 * invN;
    float var = S2 * invN - mu * mu;
    qk_murs[bi * 2] = mu;
    qk_murs[bi * 2 + 1] = rsqrtf(var + EPS_GN);
  }
}

// ---------- pass A: MFMA q/k enc_blocks + poolings + fused q-pool stats ----------

__global__ __launch_bounds__(256) void k_passA2(
    const float* __restrict__ img, const float* __restrict__ cosT,
    const float* __restrict__ sinT,
    const float* __restrict__ wimg, const float* __restrict__ wimgp,
    const float* __restrict__ img_murs, const float* __restrict__ qk_murs,
    const _Float16* __restrict__ WqB, const _Float16* __restrict__ WkB,
    float* __restrict__ q_pool, float* __restrict__ k_pool,
    float* __restrict__ Qpart) {
  __shared__ __align__(16) float encL[64 * 132];
  __shared__ float sWc[384], sWp[384], sMu[8], sRs[8];
  __shared__ float sQmu[8], sQrs[8], sKmu[8], sKrs[8];
  int t = threadIdx.x, l = t & 63, w = t >> 6;
  int b = blockIdx.x / 196, tile = blockIdx.x % 196;
  int by = (tile / 14) * 16, bx = (tile % 14) * 16;
  for (int i = t; i < 384; i += 256) { sWc[i] = wimg[i]; sWp[i] = wimgp[i]; }
  if (t < 8) {
    sMu[t] = img_murs[b * 16 + t];
    sRs[t] = img_murs[b * 16 + 8 + t];
    sQmu[t] = qk_murs[(b * 8 + t) * 2];
    sQrs[t] = qk_murs[(b * 8 + t) * 2 + 1];
    sKmu[t] = qk_murs[(32 + b * 8 + t) * 2];
    sKrs[t] = qk_murs[(32 + b * 8 + t) * 2 + 1];
  }
  h16x4 bq[8][2], bk[8][2];
#pragma unroll
  for (int kt = 0; kt < 8; ++kt)
#pragma unroll
    for (int cc = 0; cc < 2; ++cc) {
      int fi = ((kt * 8 + (2 * w + cc)) * 64 + l) * 4;
      bq[kt][cc] = *(const h16x4*)(WqB + fi);
      bk[kt][cc] = *(const h16x4*)(WkB + fi);
    }
  float kacc0 = 0.f, kacc1 = 0.f;
  float qs1[2] = {0.f, 0.f}, qs2[2] = {0.f, 0.f};
  f32x4 z = {0.f, 0.f, 0.f, 0.f};
  for (int st = 0; st < 4; ++st) {
    __syncthreads();
    {
      int py = by + (st >> 1) * 8 + (l >> 3);
      int px = bx + (st & 1) * 8 + (l & 7);
      enc_tile(encL, img, b, py, px, l, w, sWc, sWp, cosT, sinT, sMu, sRs);
    }
    __syncthreads();
    f32x4 accQ[4][2], accK[4][2];
#pragma unroll
    for (int mt = 0; mt < 4; ++mt)
#pragma unroll
      for (int cc = 0; cc < 2; ++cc) { accQ[mt][cc] = z; accK[mt][cc] = z; }
#pragma unroll
    for (int kt = 0; kt < 8; ++kt) {
      h16x4 a[4];
#pragma unroll
      for (int mt = 0; mt < 4; ++mt) {
        f32x4 av = *(const f32x4*)(encL + (mt * 16 + (l & 15)) * 132 +
                                   kt * 16 + 4 * (l >> 4));
        h16x4 ah;
#pragma unroll
        for (int j = 0; j < 4; ++j) ah[j] = (_Float16)av[j];
        a[mt] = ah;
      }
#pragma unroll
      for (int mt = 0; mt < 4; ++mt) {
        accQ[mt][0] = mfma16(a[mt], bq[kt][0], accQ[mt][0]);
        accQ[mt][1] = mfma16(a[mt], bq[kt][1], accQ[mt][1]);
        accK[mt][0] = mfma16(a[mt], bk[kt][0], accK[mt][0]);
        accK[mt][1] = mfma16(a[mt], bk[kt][1], accK[mt][1]);
      }
    }
#pragma unroll
    for (int cc = 0; cc < 2; ++cc) {
      int g = 2 * w + cc;
      int cout = g * 16 + (l & 15);
      float qmu = sQmu[g], qrs = sQrs[g], kmu = sKmu[g], krs = sKrs[g];
      float kav = 0.f;
#pragma unroll
      for (int mt = 0; mt < 4; ++mt) {
        float qv[4];
#pragma unroll
        for (int r = 0; r < 4; ++r) {
          int m = 4 * (l >> 4) + r;
          float skip = encL[(mt * 16 + m) * 132 + cout];
          qv[r] = silu_f((accQ[mt][cc][r] - qmu) * qrs) + skip;
          kav += silu_f((accK[mt][cc][r] - kmu) * krs) + skip;
        }
        float s01 = qv[0] + qv[1], s23 = qv[2] + qv[3];
        s01 += __shfl_xor(s01, 32);
        s23 += __shfl_xor(s23, 32);
        if ((l >> 4) < 2) {
          int py2 = (by + (st >> 1) * 8 + 2 * mt) >> 1;
          int px2 = (bx + (st & 1) * 8 + (l >> 4) * 4) >> 1;
          size_t base = ((size_t)(b * NQ) + py2 * 112 + px2) * 128 + cout;
          float pv0 = s01 * 0.25f, pv1 = s23 * 0.25f;
          q_pool[base] = pv0;
          q_pool[base + 128] = pv1;
          qs1[cc] += pv0 + pv1;
          qs2[cc] += pv0 * pv0 + pv1 * pv1;
        }
      }
      if (cc == 0) kacc0 += kav; else kacc1 += kav;
    }
  }
  kacc0 += __shfl_xor(kacc0, 16); kacc0 += __shfl_xor(kacc0, 32);
  kacc1 += __shfl_xor(kacc1, 16); kacc1 += __shfl_xor(kacc1, 32);
  if (l < 16) {
    k_pool[((size_t)(b * 128) + (2 * w) * 16 + l) * NKk + tile] = kacc0 * (1.f / 256.f);
    k_pool[((size_t)(b * 128) + (2 * w + 1) * 16 + l) * NKk + tile] = kacc1 * (1.f / 256.f);
  }
#pragma unroll
  for (int cc = 0; cc < 2; ++cc) {
    float a1 = qs1[cc], a2 = qs2[cc];
    for (int m = 1; m < 64; m <<= 1) {
      a1 += __shfl_xor(a1, m);
      a2 += __shfl_xor(a2, m);
    }
    if (l == 0) {
      Qpart[(size_t)blockIdx.x * 16 + (2 * w + cc) * 2] = a1;
      Qpart[(size_t)blockIdx.x * 16 + (2 * w + cc) * 2 + 1] = a2;
    }
  }
}

// reduce Qpart -> murs2 (pooled-q GN stats)
__global__ __launch_bounds__(256) void k_qstatfin(
    const float* __restrict__ Qpart, float* __restrict__ murs2) {
  __shared__ float l1[4], l2[4];
  int b = blockIdx.x >> 3, g = blockIdx.x & 7, t = threadIdx.x;
  float s1 = 0.f, s2 = 0.f;
  if (t < 196) {
    s1 = Qpart[(size_t)(b * 196 + t) * 16 + g * 2];
    s2 = Qpart[(size_t)(b * 196 + t) * 16 + g * 2 + 1];
  }
  for (int m = 1; m < 64; m <<= 1) { s1 += __shfl_xor(s1, m); s2 += __shfl_xor(s2, m); }
  if ((t & 63) == 0) { l1[t >> 6] = s1; l2[t >> 6] = s2; }
  __syncthreads();
  if (t == 0) {
    float a = l1[0] + l1[1] + l1[2] + l1[3];
    float bq = l2[0] + l2[1] + l2[2] + l2[3];
    float invN = 1.f / (16.f * (float)NQ);
    float mu = a * invN;
    float var = bq * invN - mu * mu;
    murs2[blockIdx.x * 2] = mu;
    murs2[blockIdx.x * 2 + 1] = rsqrtf(var + EPS_GN);
  }
}

// ---------- GN stats (channel-major src[b][c][P]) ----------

__global__ __launch_bounds__(256) void k_gnstats(
    const float* __restrict__ src, float* __restrict__ murs, int P, float eps) {
  __shared__ float l1[4], l2[4];
  int b = blockIdx.x >> 3, g = blockIdx.x & 7, t = threadIdx.x;
  const float* base = src + ((size_t)(b * 128) + g * 16) * P;
  float s1 = 0.f, s2 = 0.f;
  for (int i = t; i < 16 * P; i += 256) {
    float v = base[i];
    s1 += v; s2 += v * v;
  }
  for (int m = 1; m < 64; m <<= 1) { s1 += __shfl_xor(s1, m); s2 += __shfl_xor(s2, m); }
  if ((t & 63) == 0) { l1[t >> 6] = s1; l2[t >> 6] = s2; }
  __syncthreads();
  if (t == 0) {
    float invN = 1.f / (16.f * (float)P);
    float a = l1[0] + l1[1] + l1[2] + l1[3];
    float bq = l2[0] + l2[1] + l2[2] + l2[3];
    float mu = a * invN;
    float var = bq * invN - mu * mu;
    murs[blockIdx.x * 2] = mu;
    murs[blockIdx.x * 2 + 1] = rsqrtf(var + eps);
  }
}

// ---------- features L2 normalize ----------

__global__ void k_fn(const float* __restrict__ feat, float* __restrict__ fn) {
  int b = blockIdx.x, p = threadIdx.x;
  if (p >= NKk) return;
  const float* fb = feat + (size_t)b * VD * NKk + p;
  float s = 0.f;
  for (int c = 0; c < VD; ++c) { float v = fb[c * NKk]; s += v * v; }
  float r = rsqrtf(fmaxf(s, 1e-24f));
  float* ob = fn + (size_t)b * VD * NKk + p;
  for (int c = 0; c < VD; ++c) ob[c * NKk] = fb[c * NKk] * r;
}

// ---------- kf enc_block conv (384->128, conv + proj skip) ----------

__global__ __launch_bounds__(256) void k_kfconv(
    const float* __restrict__ fn, const float* __restrict__ KFT,
    const float* __restrict__ KFPT,
    float* __restrict__ y_kf, float* __restrict__ skip_kf) {
  __shared__ float fnL[192 * 64];
  int t = threadIdx.x, p = t & 63, cq = t >> 6;
  int b = blockIdx.x >> 2, tile = blockIdx.x & 3;
  int p0 = tile * 49;
  int c0 = cq * 32, c0u = rfl(c0);
  float accy[32], accs[32];
#pragma unroll
  for (int i = 0; i < 32; ++i) { accy[i] = 0.f; accs[i] = 0.f; }
  for (int ch = 0; ch < 2; ++ch) {
    __syncthreads();
    for (int i = t; i < 192 * 64; i += 256) {
      int kk = i >> 6, pp = i & 63;
      float v = 0.f;
      if (pp < 49) v = fn[((size_t)(b * 384) + ch * 192 + kk) * NKk + p0 + pp];
      fnL[i] = v;
    }
    __syncthreads();
#pragma unroll 2
    for (int k = 0; k < 192; ++k) {
      float x = fnL[k * 64 + p];
      const float* wy = KFT + ((size_t)(ch * 192 + k)) * 128 + c0u;
      const float* wsk = KFPT + ((size_t)(ch * 192 + k)) * 128 + c0u;
#pragma unroll
      for (int i = 0; i < 32; ++i) {
        accy[i] = fmaf(wy[i], x, accy[i]);
        accs[i] = fmaf(wsk[i], x, accs[i]);
      }
    }
  }
  if (p < 49) {
#pragma unroll
    for (int i = 0; i < 32; ++i) {
      size_t off = (size_t)(b * 128 + c0 + i) * NKk + p0 + p;
      y_kf[off] = accy[i];
      skip_kf[off] = accs[i];
    }
  }
}

// ---------- SFT ----------

__global__ __launch_bounds__(256) void k_sft(
    const float* __restrict__ y_kf, const float* __restrict__ skip_kf,
    const float* __restrict__ kf_murs, const float* __restrict__ GT,
    const float* __restrict__ BT, const float* __restrict__ k_pool,
    const float* __restrict__ kgn_murs, float* __restrict__ k_final) {
  __shared__ float kfL[128 * 64];
  __shared__ float sMu[8], sRs[8], sGmu[8], sGrs[8];
  int t = threadIdx.x, p = t & 63, cq = t >> 6;
  int b = blockIdx.x >> 2, tile = blockIdx.x & 3;
  int p0 = tile * 49;
  if (t < 8) {
    sMu[t] = kf_murs[(b * 8 + t) * 2];
    sRs[t] = kf_murs[(b * 8 + t) * 2 + 1];
    sGmu[t] = kgn_murs[(b * 8 + t) * 2];
    sGrs[t] = kgn_murs[(b * 8 + t) * 2 + 1];
  }
  __syncthreads();
  for (int i = t; i < 128 * 64; i += 256) {
    int c = i >> 6, pp = i & 63;
    float v = 0.f;
    if (pp < 49) {
      size_t off = (size_t)(b * 128 + c) * NKk + p0 + pp;
      int g = c >> 4;
      v = silu_f((y_kf[off] - sMu[g]) * sRs[g]) + skip_kf[off];
    }
    kfL[i] = v;
  }
  __syncthreads();
  int c0 = cq * 32, c0u = rfl(c0);
  float ag[32], ab[32];
#pragma unroll
  for (int i = 0; i < 32; ++i) { ag[i] = 0.f; ab[i] = 0.f; }
  gemm32(ag, kfL, GT, p, c0u);
  gemm32(ab, kfL, BT, p, c0u);
  if (p < 49) {
#pragma unroll
    for (int i = 0; i < 32; ++i) {
      int c = c0 + i, g = c >> 4;
      size_t off = (size_t)(b * 128 + c) * NKk + p0 + p;
      float kn = (k_pool[off] - sGmu[g]) * sGrs[g];
      k_final[off] = fmaf(ag[i], kn, ab[i]);
    }
  }
}

// ---------- RMSNorm + projection (k side, VALU) ----------

__global__ __launch_bounds__(256) void k_rmsproj(
    const float* __restrict__ src, const float* __restrict__ WTs,
    const float* __restrict__ bias, float* __restrict__ dst, int NP) {
  __shared__ float xL[128 * 64];
  __shared__ float msP[4][64];
  int t = threadIdx.x, p = t & 63, cq = t >> 6;
  int nt = (NP + 63) / 64;
  int b = blockIdx.x / nt, tile = blockIdx.x % nt;
  int p0 = tile * 64;
  float ss = 0.f;
#pragma unroll
  for (int i = 0; i < 32; ++i) {
    int c = cq * 32 + i;
    float v = (p0 + p < NP) ? src[(size_t)(b * 128 + c) * NP + p0 + p] : 0.f;
    xL[c * 64 + p] = v;
    ss += v * v;
  }
  msP[cq][p] = ss;
  __syncthreads();
  float ms = (msP[0][p] + msP[1][p] + msP[2][p] + msP[3][p]) * (1.f / 128.f);
  float rr = rsqrtf(ms + EPS_RMS);
  int c0u = rfl(cq * 32);
  float acc[32];
#pragma unroll
  for (int i = 0; i < 32; ++i) acc[i] = 0.f;
  gemm32(acc, xL, WTs, p, c0u);
  if (p0 + p < NP) {
#pragma unroll
    for (int i = 0; i < 32; ++i)
      dst[((size_t)b * NP + p0 + p) * 128 + c0u + i] = acc[i] * rr + bias[c0u + i];
  }
}

// ---------- 3x3 conv on GN(q_pool), MFMA ----------

__global__ __launch_bounds__(256) void k_conv3m(
    const float* __restrict__ q_pool, const float* __restrict__ murs2,
    const _Float16* __restrict__ W3B, float* __restrict__ qconv,
    float* __restrict__ msq) {
  __shared__ __align__(16) _Float16 w3L[16384];
  __shared__ float sMu[8], sRs[8];
  int t = threadIdx.x, l = t & 63, w = t >> 6;
  int b = blockIdx.x / 98, reg = blockIdx.x % 98;
  int y0 = (reg / 7) * 8, x0 = (reg % 7) * 16;
  if (t < 8) { sMu[t] = murs2[(b * 8 + t) * 2]; sRs[t] = murs2[(b * 8 + t) * 2 + 1]; }
  f32x4 z = {0.f, 0.f, 0.f, 0.f};
  f32x4 acc[2][8];
#pragma unroll
  for (int rx = 0; rx < 2; ++rx)
#pragma unroll
    for (int ct = 0; ct < 8; ++ct) acc[rx][ct] = z;
  int lm = l & 15;
  int mrow = lm >> 3, mcol = lm & 7;
  for (int tap = 0; tap < 9; ++tap) {
    int dy = tap / 3 - 1, dx = tap % 3 - 1;
    __syncthreads();
    for (int i = t; i < 4096; i += 256)
      ((h16x4*)w3L)[i] = ((const h16x4*)W3B)[tap * 4096 + i];
    __syncthreads();
    int py = y0 + 2 * w + mrow + dy;
    int pxb = x0 + mcol + dx;
    bool oky = (py >= 0) && (py < 112);
#pragma unroll
    for (int kt = 0; kt < 8; ++kt) {
      float mu = sMu[kt], rs = sRs[kt];
      h16x4 a[2];
#pragma unroll
      for (int rx = 0; rx < 2; ++rx) {
        int px = pxb + rx * 8;
        bool ok = oky && (px >= 0) && (px < 112);
        h16x4 ah = {(_Float16)0.f, (_Float16)0.f, (_Float16)0.f, (_Float16)0.f};
        if (ok) {
          f32x4 v = *(const f32x4*)(q_pool + ((size_t)(b * NQ) + py * 112 + px) * 128 +
                                    kt * 16 + 4 * (l >> 4));
#pragma unroll
          for (int j = 0; j < 4; ++j) ah[j] = (_Float16)((v[j] - mu) * rs);
        }
        a[rx] = ah;
      }
#pragma unroll
      for (int ct = 0; ct < 8; ++ct) {
        h16x4 bf = ((const h16x4*)w3L)[(kt * 8 + ct) * 64 + l];
        acc[0][ct] = mfma16(a[0], bf, acc[0][ct]);
        acc[1][ct] = mfma16(a[1], bf, acc[1][ct]);
      }
    }
  }
#pragma unroll
  for (int rx = 0; rx < 2; ++rx) {
    float sq[4] = {0.f, 0.f, 0.f, 0.f};
#pragma unroll
    for (int ct = 0; ct < 8; ++ct)
#pragma unroll
      for (int r = 0; r < 4; ++r) sq[r] += acc[rx][ct][r] * acc[rx][ct][r];
#pragma unroll
    for (int r = 0; r < 4; ++r) {
      for (int m = 1; m < 16; m <<= 1) sq[r] += __shfl_xor(sq[r], m);
      int mm = 4 * (l >> 4) + r;
      int py = y0 + 2 * w + (mm >> 3), px = x0 + rx * 8 + (mm & 7);
      size_t pb = (size_t)(b * NQ) + py * 112 + px;
      if ((l & 15) == 0) msq[pb] = sq[r];
#pragma unroll
      for (int ct = 0; ct < 8; ++ct)
        qconv[pb * 128 + ct * 16 + (l & 15)] = acc[rx][ct][r];
    }
  }
}

// ---------- RMSNorm + proj (q side, MFMA) ----------

__global__ __launch_bounds__(256) void k_rmsq(
    const float* __restrict__ qconv, const _Float16* __restrict__ QPB,
    const float* __restrict__ msq, const float* __restrict__ bias,
    float* __restrict__ qp) {
  __shared__ __align__(16) _Float16 wL[16384];
  int t = threadIdx.x, l = t & 63, w = t >> 6;
  int b = blockIdx.x / 196, tile = blockIdx.x % 196;
  for (int i = t; i < 4096; i += 256)
    ((h16x4*)wL)[i] = ((const h16x4*)QPB)[i];
  __syncthreads();
  int p0 = tile * 64 + w * 16;
  f32x4 z = {0.f, 0.f, 0.f, 0.f};
  f32x4 acc[8];
#pragma unroll
  for (int ct = 0; ct < 8; ++ct) acc[ct] = z;
#pragma unroll
  for (int kt = 0; kt < 8; ++kt) {
    f32x4 av = *(const f32x4*)(qconv + ((size_t)(b * NQ) + p0 + (l & 15)) * 128 +
                               kt * 16 + 4 * (l >> 4));
    h16x4 ah;
#pragma unroll
    for (int j = 0; j < 4; ++j) ah[j] = (_Float16)av[j];
#pragma unroll
    for (int ct = 0; ct < 8; ++ct)
      acc[ct] = mfma16(ah, ((const h16x4*)wL)[(kt * 8 + ct) * 64 + l], acc[ct]);
  }
#pragma unroll
  for (int r = 0; r < 4; ++r) {
    int pix = p0 + 4 * (l >> 4) + r;
    float rr = rsqrtf(msq[(size_t)(b * NQ) + pix] * (1.f / 128.f) + EPS_RMS);
#pragma unroll
    for (int ct = 0; ct < 8; ++ct)
      qp[((size_t)(b * NQ) + pix) * 128 + ct * 16 + (l & 15)] =
          acc[ct][r] * rr + bias[ct * 16 + (l & 15)];
  }
}

// ---------- attention: QK^T + softmax + head-mean -> packed fp16 P ----------

__global__ __launch_bounds__(256) void k_attn1m(
    const float* __restrict__ qp, const float* __restrict__ kpb,
    _Float16* __restrict__ Ph) {
  __shared__ float sP[4][16][212];
  int t = threadIdx.x, l = t & 63, h = t >> 6;
  int b = blockIdx.x / 784, qt = blockIdx.x % 784;
  int q0 = qt * 16;
  constexpr float SC = 0.17677669529663687f;  // 1/sqrt(32)
  h16x4 aq[2];
#pragma unroll
  for (int kt = 0; kt < 2; ++kt) {
    f32x4 v = *(const f32x4*)(qp + ((size_t)(b * NQ) + q0 + (l & 15)) * 128 +
                              h * 32 + kt * 16 + 4 * (l >> 4));
    h16x4 ah;
#pragma unroll
    for (int j = 0; j < 4; ++j) ah[j] = (_Float16)v[j];
    aq[kt] = ah;
  }
  f32x4 z = {0.f, 0.f, 0.f, 0.f};
  f32x4 acc[13];
#pragma unroll
  for (int nt = 0; nt < 13; ++nt) acc[nt] = z;
#pragma unroll
  for (int nt = 0; nt < 13; ++nt) {
    int key = nt * 16 + (l & 15);
    bool ok = key < 196;
#pragma unroll
    for (int kt = 0; kt < 2; ++kt) {
      h16x4 bf = {(_Float16)0.f, (_Float16)0.f, (_Float16)0.f, (_Float16)0.f};
      if (ok) {
        f32x4 v = *(const f32x4*)(kpb + ((size_t)(b * 196) + key) * 128 +
                                  h * 32 + kt * 16 + 4 * (l >> 4));
#pragma unroll
        for (int j = 0; j < 4; ++j) bf[j] = (_Float16)v[j];
      }
      acc[nt] = mfma16(aq[kt], bf, acc[nt]);
    }
  }
#pragma unroll
  for (int r = 0; r < 4; ++r) {
    float mx = -3e38f;
#pragma unroll
    for (int nt = 0; nt < 13; ++nt) {
      bool ok = nt * 16 + (l & 15) < 196;
      float v = ok ? acc[nt][r] * SC : -3e38f;
      acc[nt][r] = v;
      mx = fmaxf(mx, v);
    }
    for (int m = 1; m < 16; m <<= 1) mx = fmaxf(mx, __shfl_xor(mx, m));
    float sum = 0.f;
#pragma unroll
    for (int nt = 0; nt < 13; ++nt) {
      bool ok = nt * 16 + (l & 15) < 196;
      float e = ok ? __expf(acc[nt][r] - mx) : 0.f;
      acc[nt][r] = e;
      sum += e;
    }
    for (int m = 1; m < 16; m <<= 1) sum += __shfl_xor(sum, m);
    float inv = 1.f / sum;
#pragma unroll
    for (int nt = 0; nt < 13; ++nt)
      sP[h][4 * (l >> 4) + r][nt * 16 + (l & 15)] = acc[nt][r] * inv;
  }
  __syncthreads();
  // head-mean + pack into MFMA B-frag order:
  // Ph[((b*784+qt)*13 + kt)*64 + l][j] = P[q=(l&15)][k=kt*16+4*(l>>4)+j]
  _Float16* pb = Ph + (size_t)(b * 784 + qt) * 13 * 256;
  for (int i = t; i < 832; i += 256) {
    int kt = i >> 6, ll = i & 63;
    int q = ll & 15, kb = kt * 16 + 4 * (ll >> 4);
    h16x4 v;
#pragma unroll
    for (int j = 0; j < 4; ++j) {
      int k = kb + j;
      float s = 0.25f * (sP[0][q][k] + sP[1][q][k] + sP[2][q][k] + sP[3][q][k]);
      v[j] = (_Float16)s;
    }
    *(h16x4*)(pb + (size_t)i * 4) = v;
  }
}

// ---------- attention PV: pure fragment streaming, no LDS ----------

__global__ __launch_bounds__(256) void k_attn2m(
    const _Float16* __restrict__ Ph, const _Float16* __restrict__ featB,
    float* __restrict__ out) {
  int t = threadIdx.x, l = t & 63, w = t >> 6;
  int b = blockIdx.x / 196, qt = blockIdx.x % 196;
  int q16 = qt * 4 + w;             // this wave's 16-query tile
  f32x4 z = {0.f, 0.f, 0.f, 0.f};
  f32x4 acc[24];
#pragma unroll
  for (int dt = 0; dt < 24; ++dt) acc[dt] = z;
  const h16x4* PB = (const h16x4*)Ph + ((size_t)(b * 784 + q16) * 13) * 64 + l;
  const h16x4* FB = (const h16x4*)featB + (size_t)b * 13 * 24 * 64 + l;
  for (int kt = 0; kt < 13; ++kt) {
    h16x4 bp = PB[kt * 64];
    const h16x4* fb = FB + kt * 24 * 64;
#pragma unroll
    for (int dt = 0; dt < 24; ++dt)
      acc[dt] = mfma16(fb[(size_t)dt * 64], bp, acc[dt]);
  }
  int qg = q16 * 16 + (l & 15);
#pragma unroll
  for (int dt = 0; dt < 24; ++dt)
#pragma unroll
    for (int r = 0; r < 4; ++r) {
      int d = dt * 16 + 4 * (l >> 4) + r;
      out[((size_t)(b * 384) + d) * NQ + qg] = acc[dt][r];
    }
}

}  // namespace

extern "C" void kernel_launch(void* const* d_in, const int* in_sizes, int n_in,
                              void* d_out, int out_size, void* d_ws,
                              size_t ws_size, hipStream_t stream) {
  (void)in_sizes; (void)n_in; (void)out_size; (void)ws_size;
  const float* image        = (const float*)d_in[0];
  const float* features     = (const float*)d_in[1];
  const float* rope_f       = (const float*)d_in[2];
  const float* img_conv_w   = (const float*)d_in[3];
  const float* img_proj_w   = (const float*)d_in[4];
  const float* qenc_w       = (const float*)d_in[5];
  const float* kenc_w       = (const float*)d_in[6];
  const float* kfeat_conv_w = (const float*)d_in[7];
  const float* kfeat_proj_w = (const float*)d_in[8];
  const float* sft_gamma_w  = (const float*)d_in[9];
  const float* sft_beta_w   = (const float*)d_in[10];
  const float* block_conv_w = (const float*)d_in[11];
  const float* rms_q_w      = (const float*)d_in[12];
  const float* rms_k_w      = (const float*)d_in[13];
  const float* q_proj_w     = (const float*)d_in[14];
  const float* q_proj_b     = (const float*)d_in[15];
  const float* k_proj_w     = (const float*)d_in[16];
  const float* k_proj_b     = (const float*)d_in[17];
  float* out = (float*)d_out;
  float* ws = (float*)d_ws;

  size_t off = 0;
  auto alloc = [&](size_t n) {
    size_t r = off;
    off += (n + 63) & ~(size_t)63;
    return r;
  };
  _Float16* WqB  = (_Float16*)(ws + alloc(8192));
  _Float16* WkB  = (_Float16*)(ws + alloc(8192));
  _Float16* QPB  = (_Float16*)(ws + alloc(8192));
  _Float16* W3B  = (_Float16*)(ws + alloc(73728));
  float* KFT      = ws + alloc(49152);
  float* KFPT     = ws + alloc(49152);
  float* GT       = ws + alloc(16384);
  float* BT       = ws + alloc(16384);
  float* KPT      = ws + alloc(16384);
  float* cosT     = ws + alloc(14336);
  float* sinT     = ws + alloc(14336);
  _Float16* featB = (_Float16*)(ws + alloc(159744));  // 319488 fp16
  float* imgpart  = ws + alloc(2304);
  float* img_murs = ws + alloc(64);
  float* qk_murs  = ws + alloc(128);
  float* murs2    = ws + alloc(64);
  float* kgn_murs = ws + alloc(64);
  float* kf_murs  = ws + alloc(64);
  float* G        = ws + alloc(65536);
  float* mvec     = ws + alloc(512);
  float* Qpart    = ws + alloc((size_t)BB * 196 * 16);
  float* y_kf     = ws + alloc(100352);
  float* skip_kf  = ws + alloc(100352);
  float* k_final  = ws + alloc(100352);
  float* k_pool   = ws + alloc(100352);
  float* kpb      = ws + alloc(100352);
  float* msq      = ws + alloc(50176);
  float* RA = ws + alloc((size_t)BB * NQ * 128);                   // fnb->q_pool->qp
  float* RB = ws + alloc((size_t)BB * 98 * 16384 + BB * 98 * 128); // Gpart->qconv->Ph
  float* fnb    = RA;
  float* q_pool = RA;
  float* qp     = RA;
  float* Gpart  = RB;
  float* mpart  = RB + (size_t)BB * 98 * 16384;
  float* qconv  = RB;
  _Float16* Ph  = (_Float16*)RB;

  // fused weight/table/feature prep (one launch, 677888 items)
  k_prep<<<2648, 256, 0, stream>>>(qenc_w, kenc_w, q_proj_w, rms_q_w,
                                   block_conv_w, kfeat_conv_w, kfeat_proj_w,
                                   sft_gamma_w, sft_beta_w, k_proj_w, rms_k_w,
                                   rope_f, features,
                                   WqB, WkB, QPB, W3B, KFT, KFPT, GT, BT, KPT,
                                   cosT, sinT, featB);

  // image GN stats (Gram trick over 3 channels)
  k_imgstat1<<<BB * 64, 256, 0, stream>>>(image, imgpart);
  k_imgstat2<<<BB, 128, 0, stream>>>(imgpart, img_conv_w, img_murs);

  // kf branch early (fnb aliases RA before passA writes q_pool)
  k_fn<<<BB, 256, 0, stream>>>(features, fnb);
  k_kfconv<<<BB * 4, 256, 0, stream>>>(fnb, KFT, KFPT, y_kf, skip_kf);
  k_gnstats<<<32, 256, 0, stream>>>(y_kf, kf_murs, NKk, EPS_GN);

  // Gram of enc -> GN stats for q/k 1x1 convs
  k_gram<<<BB * 98, 256, 0, stream>>>(image, cosT, sinT, img_conv_w,
                                      img_proj_w, img_murs, Gpart, mpart);
  k_gred<<<BB * 64, 256, 0, stream>>>(Gpart, mpart, G, mvec);
  k_gstats<<<64, 256, 0, stream>>>(G, mvec, qenc_w, kenc_w, qk_murs);

  // apply q/k enc_blocks + pooling (MFMA) + fused pooled-q stats partials
  k_passA2<<<BB * 196, 256, 0, stream>>>(image, cosT, sinT, img_conv_w,
                                         img_proj_w, img_murs, qk_murs,
                                         WqB, WkB, q_pool, k_pool, Qpart);
  k_qstatfin<<<32, 256, 0, stream>>>(Qpart, murs2);
  k_gnstats<<<32, 256, 0, stream>>>(k_pool, kgn_murs, NKk, EPS_GN);

  // k side (tiny, VALU)
  k_sft<<<BB * 4, 256, 0, stream>>>(y_kf, skip_kf, kf_murs, GT, BT, k_pool,
                                    kgn_murs, k_final);
  k_rmsproj<<<BB * 4, 256, 0, stream>>>(k_final, KPT, k_proj_b, kpb, NKk);

  // q side (MFMA)
  k_conv3m<<<BB * 98, 256, 0, stream>>>(q_pool, murs2, W3B, qconv, msq);
  k_rmsq<<<BB * 196, 256, 0, stream>>>(qconv, QPB, msq, q_proj_b, qp);

  // attention
  k_attn1m<<<BB * 784, 256, 0, stream>>>(qp, kpb, Ph);
  k_attn2m<<<BB * 196, 256, 0, stream>>>(Ph, featB, out);
}

// Round 6
// 653.928 us; speedup vs baseline: 3.1070x; 1.1112x over previous
//
#include <hip/hip_runtime.h>
#include <cstdint>
#include <cstddef>

#define DEV __device__ __forceinline__

namespace {

constexpr int BB   = 4;
constexpr int HWP  = 50176;   // 224*224
constexpr int NQ   = 12544;   // 112*112
constexpr int NKk  = 196;     // 14*14
constexpr int VD   = 384;
constexpr float EPS_GN  = 1e-5f;
constexpr float EPS_RMS = 1.1920929e-7f;

typedef __attribute__((ext_vector_type(4))) float f32x4;
typedef __attribute__((ext_vector_type(4))) _Float16 h16x4;

DEV float silu_f(float z) { return z / (1.f + __expf(-z)); }
DEV int rfl(int v) { return __builtin_amdgcn_readfirstlane(v); }

DEV f32x4 mfma16(h16x4 a, h16x4 b, f32x4 c) {
  return __builtin_amdgcn_mfma_f32_16x16x16f16(a, b, c, 0, 0, 0);
}

// fp32 scalar-broadcast GEMM for the small k-branch kernels (K=128, 64 px)
DEV void gemm32(float* acc, const float* encL, const float* __restrict__ WT,
                int p, int c0u) {
#pragma unroll 4
  for (int k = 0; k < 128; ++k) {
    float x = encL[k * 64 + p];
    const float* w = WT + (size_t)k * 128 + c0u;
#pragma unroll
    for (int i = 0; i < 32; ++i) acc[i] = fmaf(w[i], x, acc[i]);
  }
}

// ---------- fused weight prep (one launch) ----------
DEV void pack16_one(int id, const float* W, const float* rowscale,
                    _Float16* dst) {
  int j = id & 3, l = (id >> 2) & 63, tile = id >> 8;
  int ct = tile & 7, kt = tile >> 3;
  int ci = kt * 16 + 4 * (l >> 4) + j;
  int co = ct * 16 + (l & 15);
  float v = W[(size_t)co * 128 + ci];
  if (rowscale) v *= rowscale[ci];
  dst[id] = (_Float16)v;
}
DEV void t2d_one(int idx, const float* src, float* dst, int CO, int CI,
                 const float* rowscale) {
  int co = idx / CI, ci = idx % CI;
  float v = src[idx];
  if (rowscale) v *= rowscale[ci];
  dst[(size_t)ci * CO + co] = v;
}

__global__ __launch_bounds__(256) void k_prep(
    const float* __restrict__ qenc_w, const float* __restrict__ kenc_w,
    const float* __restrict__ q_proj_w, const float* __restrict__ rms_q_w,
    const float* __restrict__ block_conv_w,
    const float* __restrict__ kfeat_conv_w, const float* __restrict__ kfeat_proj_w,
    const float* __restrict__ sft_gamma_w, const float* __restrict__ sft_beta_w,
    const float* __restrict__ k_proj_w, const float* __restrict__ rms_k_w,
    const float* __restrict__ ropef, const float* __restrict__ feat,
    _Float16* __restrict__ WqB, _Float16* __restrict__ WkB,
    _Float16* __restrict__ QPB, _Float16* __restrict__ W3B,
    float* __restrict__ KFT, float* __restrict__ KFPT,
    float* __restrict__ GT, float* __restrict__ BT, float* __restrict__ KPT,
    float* __restrict__ cosT, float* __restrict__ sinT,
    _Float16* __restrict__ featB) {
  int idx = blockIdx.x * 256 + threadIdx.x;
  if (idx < 16384) {
    pack16_one(idx, qenc_w, nullptr, WqB);
  } else if (idx < 32768) {
    pack16_one(idx - 16384, kenc_w, nullptr, WkB);
  } else if (idx < 49152) {
    pack16_one(idx - 32768, q_proj_w, rms_q_w, QPB);
  } else if (idx < 196608) {
    int id = idx - 49152;
    int j = id & 3, l = (id >> 2) & 63, tile = (id >> 8) & 63, tap = id >> 14;
    int ct = tile & 7, kt = tile >> 3;
    int ci = kt * 16 + 4 * (l >> 4) + j;
    int co = ct * 16 + (l & 15);
    W3B[id] = (_Float16)block_conv_w[((size_t)co * 128 + ci) * 9 + tap];
  } else if (idx < 245760) {
    t2d_one(idx - 196608, kfeat_conv_w, KFT, 128, 384, nullptr);
  } else if (idx < 294912) {
    t2d_one(idx - 245760, kfeat_proj_w, KFPT, 128, 384, nullptr);
  } else if (idx < 311296) {
    t2d_one(idx - 294912, sft_gamma_w, GT, 128, 128, nullptr);
  } else if (idx < 327680) {
    t2d_one(idx - 311296, sft_beta_w, BT, 128, 128, nullptr);
  } else if (idx < 344064) {
    t2d_one(idx - 327680, k_proj_w, KPT, 128, 128, rms_k_w);
  } else if (idx < 358400) {
    int id = idx - 344064;            // pos*64 + d
    int pos = id >> 6, d = id & 63;
    float a = (pos + 0.5f) * (1.f / 224.f) * ropef[d];
    float s, c;
    __sincosf(a, &s, &c);
    cosT[id] = c;
    sinT[id] = s;
  } else if (idx < 677888) {
    int id = idx - 358400;            // (((b*13+kt)*24+dt)*64+l)*4+j
    int j = id & 3, l = (id >> 2) & 63;
    int rest = id >> 8;
    int dt = rest % 24;
    int kt = (rest / 24) % 13;
    int b = rest / (24 * 13);
    int key = kt * 16 + 4 * (l >> 4) + j;
    int d = dt * 16 + (l & 15);
    float v = (key < 196) ? feat[((size_t)(b * 384) + d) * 196 + key] : 0.f;
    featB[id] = (_Float16)v;
  }
}

// ---------- image GN stats via 3x3 Gram ----------

__global__ __launch_bounds__(256) void k_imgstat1(
    const float* __restrict__ img, float* __restrict__ part) {
  __shared__ float lds[4][9];
  int b = blockIdx.x >> 6, blk = blockIdx.x & 63;
  int t = threadIdx.x;
  float a[9];
#pragma unroll
  for (int j = 0; j < 9; ++j) a[j] = 0.f;
  const float* ib = img + (size_t)b * 3 * HWP;
  for (int pix = blk * 784 + t; pix < blk * 784 + 784; pix += 256) {
    float x0 = ib[pix], x1 = ib[HWP + pix], x2 = ib[2 * HWP + pix];
    a[0] += x0; a[1] += x1; a[2] += x2;
    a[3] += x0 * x0; a[4] += x0 * x1; a[5] += x0 * x2;
    a[6] += x1 * x1; a[7] += x1 * x2; a[8] += x2 * x2;
  }
#pragma unroll
  for (int j = 0; j < 9; ++j)
    for (int m = 1; m < 64; m <<= 1) a[j] += __shfl_xor(a[j], m);
  if ((t & 63) == 0)
    for (int j = 0; j < 9; ++j) lds[t >> 6][j] = a[j];
  __syncthreads();
  if (t < 9)
    part[(size_t)blockIdx.x * 9 + t] =
        lds[0][t] + lds[1][t] + lds[2][t] + lds[3][t];
}

__global__ __launch_bounds__(128) void k_imgstat2(
    const float* __restrict__ part, const float* __restrict__ wimg,
    float* __restrict__ img_murs) {
  __shared__ float MG[9];
  int b = blockIdx.x, t = threadIdx.x;
  if (t < 9) {
    float s = 0.f;
    for (int i = 0; i < 64; ++i) s += part[(size_t)(b * 64 + i) * 9 + t];
    MG[t] = s;
  }
  __syncthreads();
  int c = t;
  float w0 = wimg[c * 3], w1 = wimg[c * 3 + 1], w2 = wimg[c * 3 + 2];
  float s1 = w0 * MG[0] + w1 * MG[1] + w2 * MG[2];
  float s2 = w0 * w0 * MG[3] + w1 * w1 * MG[6] + w2 * w2 * MG[8] +
             2.f * (w0 * w1 * MG[4] + w0 * w2 * MG[5] + w1 * w2 * MG[7]);
  for (int m = 1; m < 16; m <<= 1) {
    s1 += __shfl_xor(s1, m);
    s2 += __shfl_xor(s2, m);
  }
  if ((c & 15) == 0) {
    int g = c >> 4;
    float invN = 1.f / (16.f * HWP);
    float mu = s1 * invN;
    float var = s2 * invN - mu * mu;
    img_murs[b * 16 + g] = mu;
    img_murs[b * 16 + 8 + g] = rsqrtf(var + EPS_GN);
  }
}

// ---------- enc producer + Gram + enc_frag materialization ----------
// 392 blocks (BB x 98), each handles 8 subtiles of 64 pixels.
// fragP: pixel-major MFMA A-frag layout (padded stride 65 h16x4) -> encF global
// fragC: channel-major frag layout -> Gram MFMA operands
__global__ __launch_bounds__(256) void k_gram(
    const float* __restrict__ img, const float* __restrict__ cosT,
    const float* __restrict__ sinT,
    const float* __restrict__ wimg, const float* __restrict__ wimgp,
    const float* __restrict__ img_murs,
    _Float16* __restrict__ encF,
    float* __restrict__ Gpart, float* __restrict__ mpart) {
  __shared__ __align__(16) _Float16 fragP[2080 * 4];   // [kt*4+mt][lane(65 pad)][j]
  __shared__ __align__(16) _Float16 fragC[8192];       // [pk][ct][lane][j]
  __shared__ float sWc[384], sWp[384], sMu[8], sRs[8];
  int t = threadIdx.x, l = t & 63, w = t >> 6;
  int b = blockIdx.x / 98, blk = blockIdx.x % 98;
  for (int i = t; i < 384; i += 256) { sWc[i] = wimg[i]; sWp[i] = wimgp[i]; }
  if (t < 8) { sMu[t] = img_murs[b * 16 + t]; sRs[t] = img_murs[b * 16 + 8 + t]; }
  f32x4 acc[2][8];
  f32x4 macc[2];
  f32x4 z = {0.f, 0.f, 0.f, 0.f};
#pragma unroll
  for (int e = 0; e < 2; ++e) {
    macc[e] = z;
#pragma unroll
    for (int nt = 0; nt < 8; ++nt) acc[e][nt] = z;
  }
  h16x4 hone = {(_Float16)1.f, (_Float16)1.f, (_Float16)1.f, (_Float16)1.f};
  int mt = l >> 4;
  int laneCbase = 16 * ((l & 15) >> 2);
  int jC = (l & 15) & 3;
  for (int s = 0; s < 8; ++s) {
    int sub = blk * 8 + s;
    int tile = sub >> 2, st = sub & 3;
    int py = (tile / 14) * 16 + ((st >> 1) << 3) + (l >> 3);
    int px = (tile % 14) * 16 + ((st & 1) << 3) + (l & 7);
    __syncthreads();
    {  // producer: thread owns pixel l, channels w*16..w*16+15 (+64 pair)
      const float* ip = img + (size_t)b * 3 * HWP + py * 224 + px;
      float x0 = ip[0], x1 = ip[HWP], x2 = ip[2 * HWP];
      const float* cy = cosT + py * 64 + w * 16;
      const float* sy = sinT + py * 64 + w * 16;
      const float* cx = cosT + px * 64 + w * 16;
      const float* sx = sinT + px * 64 + w * 16;
#pragma unroll
      for (int jj = 0; jj < 4; ++jj) {
        f32x4 cyv = *(const f32x4*)(cy + jj * 4);
        f32x4 syv = *(const f32x4*)(sy + jj * 4);
        f32x4 cxv = *(const f32x4*)(cx + jj * 4);
        f32x4 sxv = *(const f32x4*)(sx + jj * 4);
        h16x4 lo4, hi4;
#pragma unroll
        for (int u = 0; u < 4; ++u) {
          int d = w * 16 + jj * 4 + u;
          int c2 = d + 64;
          float y1 = sWc[d * 3] * x0 + sWc[d * 3 + 1] * x1 + sWc[d * 3 + 2] * x2;
          float s1 = sWp[d * 3] * x0 + sWp[d * 3 + 1] * x1 + sWp[d * 3 + 2] * x2;
          float y2 = sWc[c2 * 3] * x0 + sWc[c2 * 3 + 1] * x1 + sWc[c2 * 3 + 2] * x2;
          float s2 = sWp[c2 * 3] * x0 + sWp[c2 * 3 + 1] * x1 + sWp[c2 * 3 + 2] * x2;
          int g1 = d >> 4, g2 = g1 + 4;
          float t1 = silu_f((y1 - sMu[g1]) * sRs[g1]) + s1;
          float t2 = silu_f((y2 - sMu[g2]) * sRs[g2]) + s2;
          lo4[u] = (_Float16)(t1 * cyv[u] - t2 * syv[u]);
          hi4[u] = (_Float16)(t2 * cxv[u] + t1 * sxv[u]);
        }
        int lane = (l & 15) + 16 * jj;
        *(h16x4*)&fragP[((w * 4 + mt) * 65 + lane) * 4]       = lo4;
        *(h16x4*)&fragP[(((w + 4) * 4 + mt) * 65 + lane) * 4] = hi4;
#pragma unroll
        for (int u = 0; u < 4; ++u) {
          int laneC = jj * 4 + u + laneCbase;
          fragC[((mt * 8 + w) * 64 + laneC) * 4 + jC]     = lo4[u];
          fragC[((mt * 8 + w + 4) * 64 + laneC) * 4 + jC] = hi4[u];
        }
      }
    }
    __syncthreads();
    // stream fragP -> global encF (coalesced b64)
    _Float16* ef = encF + ((size_t)(b * 784) + sub) * 8192;
    for (int i = t; i < 2048; i += 256) {
      int kt = i >> 8, m2 = (i >> 6) & 3, ln = i & 63;
      *(h16x4*)(ef + (size_t)i * 4) =
          *(const h16x4*)&fragP[((kt * 4 + m2) * 65 + ln) * 4];
    }
    // Gram MFMA from fragC (conflict-free b64 reads)
#pragma unroll
    for (int pk = 0; pk < 4; ++pk) {
      h16x4 a0 = *(const h16x4*)&fragC[((pk * 8 + 2 * w) * 64 + l) * 4];
      h16x4 a1 = *(const h16x4*)&fragC[((pk * 8 + 2 * w + 1) * 64 + l) * 4];
      macc[0] = mfma16(a0, hone, macc[0]);
      macc[1] = mfma16(a1, hone, macc[1]);
#pragma unroll
      for (int nt = 0; nt < 8; ++nt) {
        h16x4 bv = *(const h16x4*)&fragC[((pk * 8 + nt) * 64 + l) * 4];
        acc[0][nt] = mfma16(a0, bv, acc[0][nt]);
        acc[1][nt] = mfma16(a1, bv, acc[1][nt]);
      }
    }
  }
  float* gp = Gpart + (size_t)(b * 98 + blk) * 16384;
#pragma unroll
  for (int e = 0; e < 2; ++e)
#pragma unroll
    for (int nt = 0; nt < 8; ++nt)
#pragma unroll
      for (int r = 0; r < 4; ++r) {
        int row = (2 * w + e) * 16 + 4 * (l >> 4) + r;
        int col = nt * 16 + (l & 15);
        gp[row * 128 + col] = acc[e][nt][r];
      }
  if ((l & 15) == 0) {
    float* mp = mpart + (size_t)(b * 98 + blk) * 128;
#pragma unroll
    for (int e = 0; e < 2; ++e)
#pragma unroll
      for (int r = 0; r < 4; ++r)
        mp[(2 * w + e) * 16 + 4 * (l >> 4) + r] = macc[e][r];
  }
}

__global__ void k_gred(const float* __restrict__ Gpart,
                       const float* __restrict__ mpart,
                       float* __restrict__ G, float* __restrict__ mvec) {
  int b = blockIdx.x >> 6, chunk = blockIdx.x & 63;
  int idx = chunk * 256 + threadIdx.x;
  float s = 0.f;
  for (int i = 0; i < 98; ++i) s += Gpart[(size_t)(b * 98 + i) * 16384 + idx];
  G[(size_t)b * 16384 + idx] = s;
  if (idx < 128) {
    float sm = 0.f;
    for (int i = 0; i < 98; ++i) sm += mpart[(size_t)(b * 98 + i) * 128 + idx];
    mvec[b * 128 + idx] = sm;
  }
}

// stats for q/k 1x1 convs from Gram: E[y]=w.m, E[y^2]=w^T G w
__global__ __launch_bounds__(256) void k_gstats(
    const float* __restrict__ G, const float* __restrict__ mvec,
    const float* __restrict__ qw, const float* __restrict__ kw,
    float* __restrict__ qk_murs) {
  __shared__ float red1[4], red2[4];
  int bi = blockIdx.x;               // conv*32 + b*8 + g
  int conv = bi >> 5, b = (bi >> 3) & 3, g = bi & 7;
  const float* W = conv ? kw : qw;
  int t = threadIdx.x;
  int c = g * 16 + (t >> 4);
  int i0 = (t & 15) * 8;
  const float* wc = W + (size_t)c * 128;
  const float* Gb = G + (size_t)b * 16384;
  const float* mb = mvec + b * 128;
  float s1 = 0.f, s2 = 0.f;
  for (int i = i0; i < i0 + 8; ++i) {
    float gi = 0.f;
    for (int j = 0; j < 128; ++j) gi += Gb[i * 128 + j] * wc[j];
    s2 += wc[i] * gi;
    s1 += wc[i] * mb[i];
  }
  for (int m = 1; m < 64; m <<= 1) { s1 += __shfl_xor(s1, m); s2 += __shfl_xor(s2, m); }
  if ((t & 63) == 0) { red1[t >> 6] = s1; red2[t >> 6] = s2; }
  __syncthreads();
  if (t == 0) {
    float S1 = red1[0] + red1[1] + red1[2] + red1[3];
    float S2 = red2[0] + red2[1] + red2[2] + red2[3];
    float invN = 1.f / 802816.f;
    float mu = S1 * invN;
    float var = S2 * invN - mu * mu;
    qk_murs[bi * 2] = mu;
    qk_murs[bi * 2 + 1] = rsqrtf(var + EPS_GN);
  }
}

// ---------- pass A: q/k enc_blocks from encF (no LDS, no barriers) ----------
// grid = BB*784 (one 64-pixel subtile per block)
__global__ __launch_bounds__(256) void k_passA2(
    const _Float16* __restrict__ encF, const float* __restrict__ qk_murs,
    const _Float16* __restrict__ WqB, const _Float16* __restrict__ WkB,
    float* __restrict__ q_pool, float* __restrict__ kpp,
    float* __restrict__ Qpart) {
  int t = threadIdx.x, l = t & 63;
  int wu = rfl(t >> 6);
  int bi = blockIdx.x;
  int b = bi / 784, sub = bi % 784;
  int tile = sub >> 2, st = sub & 3;
  int by = (tile / 14) * 16, bx = (tile % 14) * 16;
  float qmu[2], qrs[2], kmu[2], krs[2];
#pragma unroll
  for (int cc = 0; cc < 2; ++cc) {
    int g = 2 * wu + cc;
    qmu[cc] = qk_murs[(b * 8 + g) * 2];
    qrs[cc] = qk_murs[(b * 8 + g) * 2 + 1];
    kmu[cc] = qk_murs[(32 + b * 8 + g) * 2];
    krs[cc] = qk_murs[(32 + b * 8 + g) * 2 + 1];
  }
  const h16x4* EF = (const h16x4*)encF + ((size_t)(b * 784) + sub) * 2048;
  f32x4 z = {0.f, 0.f, 0.f, 0.f};
  f32x4 accQ[4][2], accK[4][2];
#pragma unroll
  for (int mt = 0; mt < 4; ++mt)
#pragma unroll
    for (int cc = 0; cc < 2; ++cc) { accQ[mt][cc] = z; accK[mt][cc] = z; }
  for (int kt = 0; kt < 8; ++kt) {
    h16x4 a[4];
#pragma unroll
    for (int mt = 0; mt < 4; ++mt) a[mt] = EF[(kt * 4 + mt) * 64 + l];
    int fi = (kt * 8 + 2 * wu) * 64 + l;
    h16x4 bq0 = *(const h16x4*)(WqB + (size_t)fi * 4);
    h16x4 bq1 = *(const h16x4*)(WqB + (size_t)(fi + 64) * 4);
    h16x4 bk0 = *(const h16x4*)(WkB + (size_t)fi * 4);
    h16x4 bk1 = *(const h16x4*)(WkB + (size_t)(fi + 64) * 4);
#pragma unroll
    for (int mt = 0; mt < 4; ++mt) {
      accQ[mt][0] = mfma16(a[mt], bq0, accQ[mt][0]);
      accQ[mt][1] = mfma16(a[mt], bq1, accQ[mt][1]);
      accK[mt][0] = mfma16(a[mt], bk0, accK[mt][0]);
      accK[mt][1] = mfma16(a[mt], bk1, accK[mt][1]);
    }
  }
  const _Float16* EH = encF + ((size_t)(b * 784) + sub) * 8192;
  int cl = l & 15;
  int clo = 16 * (cl >> 2), cj = cl & 3;
  float kacc0 = 0.f, kacc1 = 0.f;
  float qs1[2] = {0.f, 0.f}, qs2[2] = {0.f, 0.f};
#pragma unroll
  for (int cc = 0; cc < 2; ++cc) {
    int g = 2 * wu + cc;
    int cout = g * 16 + cl;
    float kav = 0.f;
#pragma unroll
    for (int mt = 0; mt < 4; ++mt) {
      float qv[4];
#pragma unroll
      for (int r = 0; r < 4; ++r) {
        int m = 4 * (l >> 4) + r;
        float skip = (float)EH[((g * 4 + mt) * 64 + m + clo) * 4 + cj];
        qv[r] = silu_f((accQ[mt][cc][r] - qmu[cc]) * qrs[cc]) + skip;
        kav += silu_f((accK[mt][cc][r] - kmu[cc]) * krs[cc]) + skip;
      }
      float s01 = qv[0] + qv[1], s23 = qv[2] + qv[3];
      s01 += __shfl_xor(s01, 32);
      s23 += __shfl_xor(s23, 32);
      if ((l >> 4) < 2) {
        int py2 = (by + (st >> 1) * 8 + 2 * mt) >> 1;
        int px2 = (bx + (st & 1) * 8 + (l >> 4) * 4) >> 1;
        size_t base = ((size_t)(b * NQ) + py2 * 112 + px2) * 128 + cout;
        float pv0 = s01 * 0.25f, pv1 = s23 * 0.25f;
        q_pool[base] = pv0;
        q_pool[base + 128] = pv1;
        qs1[cc] += pv0 + pv1;
        qs2[cc] += pv0 * pv0 + pv1 * pv1;
      }
    }
    if (cc == 0) kacc0 = kav; else kacc1 = kav;
  }
  kacc0 += __shfl_xor(kacc0, 16); kacc0 += __shfl_xor(kacc0, 32);
  kacc1 += __shfl_xor(kacc1, 16); kacc1 += __shfl_xor(kacc1, 32);
  if (l < 16) {
    kpp[(size_t)bi * 128 + (2 * wu) * 16 + l]       = kacc0;
    kpp[(size_t)bi * 128 + (2 * wu + 1) * 16 + l]   = kacc1;
  }
#pragma unroll
  for (int cc = 0; cc < 2; ++cc) {
    float a1 = qs1[cc], a2 = qs2[cc];
    for (int m = 1; m < 64; m <<= 1) {
      a1 += __shfl_xor(a1, m);
      a2 += __shfl_xor(a2, m);
    }
    if (l == 0) {
      Qpart[(size_t)bi * 16 + (2 * wu + cc) * 2] = a1;
      Qpart[(size_t)bi * 16 + (2 * wu + cc) * 2 + 1] = a2;
    }
  }
}

// reduce kpp subtile partials -> k_pool[b][c][tile]
__global__ __launch_bounds__(256) void k_kpred(
    const float* __restrict__ kpp, float* __restrict__ k_pool) {
  int idx = blockIdx.x * 256 + threadIdx.x;
  if (idx >= BB * 128 * NKk) return;
  int b = idx / (128 * NKk);
  int rem = idx % (128 * NKk);
  int c = rem / NKk, tile = rem % NKk;
  const float* base = kpp + ((size_t)(b * 196 + tile) * 4) * 128 + c;
  float s = base[0] + base[128] + base[256] + base[384];
  k_pool[idx] = s * (1.f / 256.f);
}

// reduce Qpart -> murs2 (pooled-q GN stats)
__global__ __launch_bounds__(256) void k_qstatfin(
    const float* __restrict__ Qpart, float* __restrict__ murs2) {
  __shared__ float l1[4], l2[4];
  int b = blockIdx.x >> 3, g = blockIdx.x & 7, t = threadIdx.x;
  float s1 = 0.f, s2 = 0.f;
  for (int i = t; i < 784; i += 256) {
    s1 += Qpart[((size_t)(b * 784) + i) * 16 + g * 2];
    s2 += Qpart[((size_t)(b * 784) + i) * 16 + g * 2 + 1];
  }
  for (int m = 1; m < 64; m <<= 1) { s1 += __shfl_xor(s1, m); s2 += __shfl_xor(s2, m); }
  if ((t & 63) == 0) { l1[t >> 6] = s1; l2[t >> 6] = s2; }
  __syncthreads();
  if (t == 0) {
    float a = l1[0] + l1[1] + l1[2] + l1[3];
    float bq = l2[0] + l2[1] + l2[2] + l2[3];
    float invN = 1.f / (16.f * (float)NQ);
    float mu = a * invN;
    float var = bq * invN - mu * mu;
    murs2[blockIdx.x * 2] = mu;
    murs2[blockIdx.x * 2 + 1] = rsqrtf(var + EPS_GN);
  }
}

// ---------- GN stats (channel-major src[b][c][P]) ----------

__global__ __launch_bounds__(256) void k_gnstats(
    const float* __restrict__ src, float* __restrict__ murs, int P, float eps) {
  __shared__ float l1[4], l2[4];
  int b = blockIdx.x >> 3, g = blockIdx.x & 7, t = threadIdx.x;
  const float* base = src + ((size_t)(b * 128) + g * 16) * P;
  float s1 = 0.f, s2 = 0.f;
  for (int i = t; i < 16 * P; i += 256) {
    float v = base[i];
    s1 += v; s2 += v * v;
  }
  for (int m = 1; m < 64; m <<= 1) { s1 += __shfl_xor(s1, m); s2 += __shfl_xor(s2, m); }
  if ((t & 63) == 0) { l1[t >> 6] = s1; l2[t >> 6] = s2; }
  __syncthreads();
  if (t == 0) {
    float invN = 1.f / (16.f * (float)P);
    float a = l1[0] + l1[1] + l1[2] + l1[3];
    float bq = l2[0] + l2[1] + l2[2] + l2[3];
    float mu = a * invN;
    float var = bq * invN - mu * mu;
    murs[blockIdx.x * 2] = mu;
    murs[blockIdx.x * 2 + 1] = rsqrtf(var + eps);
  }
}

// ---------- features L2 normalize ----------

__global__ void k_fn(const float* __restrict__ feat, float* __restrict__ fn) {
  int b = blockIdx.x, p = threadIdx.x;
  if (p >= NKk) return;
  const float* fb = feat + (size_t)b * VD * NKk + p;
  float s = 0.f;
  for (int c = 0; c < VD; ++c) { float v = fb[c * NKk]; s += v * v; }
  float r = rsqrtf(fmaxf(s, 1e-24f));
  float* ob = fn + (size_t)b * VD * NKk + p;
  for (int c = 0; c < VD; ++c) ob[c * NKk] = fb[c * NKk] * r;
}

// ---------- kf enc_block conv (384->128, conv + proj skip) ----------

__global__ __launch_bounds__(256) void k_kfconv(
    const float* __restrict__ fn, const float* __restrict__ KFT,
    const float* __restrict__ KFPT,
    float* __restrict__ y_kf, float* __restrict__ skip_kf) {
  __shared__ float fnL[192 * 64];
  int t = threadIdx.x, p = t & 63, cq = t >> 6;
  int b = blockIdx.x >> 2, tile = blockIdx.x & 3;
  int p0 = tile * 49;
  int c0 = cq * 32, c0u = rfl(c0);
  float accy[32], accs[32];
#pragma unroll
  for (int i = 0; i < 32; ++i) { accy[i] = 0.f; accs[i] = 0.f; }
  for (int ch = 0; ch < 2; ++ch) {
    __syncthreads();
    for (int i = t; i < 192 * 64; i += 256) {
      int kk = i >> 6, pp = i & 63;
      float v = 0.f;
      if (pp < 49) v = fn[((size_t)(b * 384) + ch * 192 + kk) * NKk + p0 + pp];
      fnL[i] = v;
    }
    __syncthreads();
#pragma unroll 2
    for (int k = 0; k < 192; ++k) {
      float x = fnL[k * 64 + p];
      const float* wy = KFT + ((size_t)(ch * 192 + k)) * 128 + c0u;
      const float* wsk = KFPT + ((size_t)(ch * 192 + k)) * 128 + c0u;
#pragma unroll
      for (int i = 0; i < 32; ++i) {
        accy[i] = fmaf(wy[i], x, accy[i]);
        accs[i] = fmaf(wsk[i], x, accs[i]);
      }
    }
  }
  if (p < 49) {
#pragma unroll
    for (int i = 0; i < 32; ++i) {
      size_t off = (size_t)(b * 128 + c0 + i) * NKk + p0 + p;
      y_kf[off] = accy[i];
      skip_kf[off] = accs[i];
    }
  }
}

// ---------- SFT ----------

__global__ __launch_bounds__(256) void k_sft(
    const float* __restrict__ y_kf, const float* __restrict__ skip_kf,
    const float* __restrict__ kf_murs, const float* __restrict__ GT,
    const float* __restrict__ BT, const float* __restrict__ k_pool,
    const float* __restrict__ kgn_murs, float* __restrict__ k_final) {
  __shared__ float kfL[128 * 64];
  __shared__ float sMu[8], sRs[8], sGmu[8], sGrs[8];
  int t = threadIdx.x, p = t & 63, cq = t >> 6;
  int b = blockIdx.x >> 2, tile = blockIdx.x & 3;
  int p0 = tile * 49;
  if (t < 8) {
    sMu[t] = kf_murs[(b * 8 + t) * 2];
    sRs[t] = kf_murs[(b * 8 + t) * 2 + 1];
    sGmu[t] = kgn_murs[(b * 8 + t) * 2];
    sGrs[t] = kgn_murs[(b * 8 + t) * 2 + 1];
  }
  __syncthreads();
  for (int i = t; i < 128 * 64; i += 256) {
    int c = i >> 6, pp = i & 63;
    float v = 0.f;
    if (pp < 49) {
      size_t off = (size_t)(b * 128 + c) * NKk + p0 + pp;
      int g = c >> 4;
      v = silu_f((y_kf[off] - sMu[g]) * sRs[g]) + skip_kf[off];
    }
    kfL[i] = v;
  }
  __syncthreads();
  int c0 = cq * 32, c0u = rfl(c0);
  float ag[32], ab[32];
#pragma unroll
  for (int i = 0; i < 32; ++i) { ag[i] = 0.f; ab[i] = 0.f; }
  gemm32(ag, kfL, GT, p, c0u);
  gemm32(ab, kfL, BT, p, c0u);
  if (p < 49) {
#pragma unroll
    for (int i = 0; i < 32; ++i) {
      int c = c0 + i, g = c >> 4;
      size_t off = (size_t)(b * 128 + c) * NKk + p0 + p;
      float kn = (k_pool[off] - sGmu[g]) * sGrs[g];
      k_final[off] = fmaf(ag[i], kn, ab[i]);
    }
  }
}

// ---------- RMSNorm + projection (k side, VALU) ----------

__global__ __launch_bounds__(256) void k_rmsproj(
    const float* __restrict__ src, const float* __restrict__ WTs,
    const float* __restrict__ bias, float* __restrict__ dst, int NP) {
  __shared__ float xL[128 * 64];
  __shared__ float msP[4][64];
  int t = threadIdx.x, p = t & 63, cq = t >> 6;
  int nt = (NP + 63) / 64;
  int b = blockIdx.x / nt, tile = blockIdx.x % nt;
  int p0 = tile * 64;
  float ss = 0.f;
#pragma unroll
  for (int i = 0; i < 32; ++i) {
    int c = cq * 32 + i;
    float v = (p0 + p < NP) ? src[(size_t)(b * 128 + c) * NP + p0 + p] : 0.f;
    xL[c * 64 + p] = v;
    ss += v * v;
  }
  msP[cq][p] = ss;
  __syncthreads();
  float ms = (msP[0][p] + msP[1][p] + msP[2][p] + msP[3][p]) * (1.f / 128.f);
  float rr = rsqrtf(ms + EPS_RMS);
  int c0u = rfl(cq * 32);
  float acc[32];
#pragma unroll
  for (int i = 0; i < 32; ++i) acc[i] = 0.f;
  gemm32(acc, xL, WTs, p, c0u);
  if (p0 + p < NP) {
#pragma unroll
    for (int i = 0; i < 32; ++i)
      dst[((size_t)b * NP + p0 + p) * 128 + c0u + i] = acc[i] * rr + bias[c0u + i];
  }
}

// ---------- 3x3 conv on GN(q_pool), MFMA ----------

__global__ __launch_bounds__(256) void k_conv3m(
    const float* __restrict__ q_pool, const float* __restrict__ murs2,
    const _Float16* __restrict__ W3B, float* __restrict__ qconv,
    float* __restrict__ msq) {
  __shared__ __align__(16) _Float16 w3L[16384];
  __shared__ float sMu[8], sRs[8];
  int t = threadIdx.x, l = t & 63, w = t >> 6;
  int b = blockIdx.x / 98, reg = blockIdx.x % 98;
  int y0 = (reg / 7) * 8, x0 = (reg % 7) * 16;
  if (t < 8) { sMu[t] = murs2[(b * 8 + t) * 2]; sRs[t] = murs2[(b * 8 + t) * 2 + 1]; }
  f32x4 z = {0.f, 0.f, 0.f, 0.f};
  f32x4 acc[2][8];
#pragma unroll
  for (int rx = 0; rx < 2; ++rx)
#pragma unroll
    for (int ct = 0; ct < 8; ++ct) acc[rx][ct] = z;
  int lm = l & 15;
  int mrow = lm >> 3, mcol = lm & 7;
  for (int tap = 0; tap < 9; ++tap) {
    int dy = tap / 3 - 1, dx = tap % 3 - 1;
    __syncthreads();
    for (int i = t; i < 4096; i += 256)
      ((h16x4*)w3L)[i] = ((const h16x4*)W3B)[tap * 4096 + i];
    __syncthreads();
    int py = y0 + 2 * w + mrow + dy;
    int pxb = x0 + mcol + dx;
    bool oky = (py >= 0) && (py < 112);
#pragma unroll
    for (int kt = 0; kt < 8; ++kt) {
      float mu = sMu[kt], rs = sRs[kt];
      h16x4 a[2];
#pragma unroll
      for (int rx = 0; rx < 2; ++rx) {
        int px = pxb + rx * 8;
        bool ok = oky && (px >= 0) && (px < 112);
        h16x4 ah = {(_Float16)0.f, (_Float16)0.f, (_Float16)0.f, (_Float16)0.f};
        if (ok) {
          f32x4 v = *(const f32x4*)(q_pool + ((size_t)(b * NQ) + py * 112 + px) * 128 +
                                    kt * 16 + 4 * (l >> 4));
#pragma unroll
          for (int j = 0; j < 4; ++j) ah[j] = (_Float16)((v[j] - mu) * rs);
        }
        a[rx] = ah;
      }
#pragma unroll
      for (int ct = 0; ct < 8; ++ct) {
        h16x4 bf = ((const h16x4*)w3L)[(kt * 8 + ct) * 64 + l];
        acc[0][ct] = mfma16(a[0], bf, acc[0][ct]);
        acc[1][ct] = mfma16(a[1], bf, acc[1][ct]);
      }
    }
  }
#pragma unroll
  for (int rx = 0; rx < 2; ++rx) {
    float sq[4] = {0.f, 0.f, 0.f, 0.f};
#pragma unroll
    for (int ct = 0; ct < 8; ++ct)
#pragma unroll
      for (int r = 0; r < 4; ++r) sq[r] += acc[rx][ct][r] * acc[rx][ct][r];
#pragma unroll
    for (int r = 0; r < 4; ++r) {
      for (int m = 1; m < 16; m <<= 1) sq[r] += __shfl_xor(sq[r], m);
      int mm = 4 * (l >> 4) + r;
      int py = y0 + 2 * w + (mm >> 3), px = x0 + rx * 8 + (mm & 7);
      size_t pb = (size_t)(b * NQ) + py * 112 + px;
      if ((l & 15) == 0) msq[pb] = sq[r];
#pragma unroll
      for (int ct = 0; ct < 8; ++ct)
        qconv[pb * 128 + ct * 16 + (l & 15)] = acc[rx][ct][r];
    }
  }
}

// ---------- RMSNorm + proj (q side, MFMA) ----------

__global__ __launch_bounds__(256) void k_rmsq(
    const float* __restrict__ qconv, const _Float16* __restrict__ QPB,
    const float* __restrict__ msq, const float* __restrict__ bias,
    float* __restrict__ qp) {
  __shared__ __align__(16) _Float16 wL[16384];
  int t = threadIdx.x, l = t & 63, w = t >> 6;
  int b = blockIdx.x / 196, tile = blockIdx.x % 196;
  for (int i = t; i < 4096; i += 256)
    ((h16x4*)wL)[i] = ((const h16x4*)QPB)[i];
  __syncthreads();
  int p0 = tile * 64 + w * 16;
  f32x4 z = {0.f, 0.f, 0.f, 0.f};
  f32x4 acc[8];
#pragma unroll
  for (int ct = 0; ct < 8; ++ct) acc[ct] = z;
#pragma unroll
  for (int kt = 0; kt < 8; ++kt) {
    f32x4 av = *(const f32x4*)(qconv + ((size_t)(b * NQ) + p0 + (l & 15)) * 128 +
                               kt * 16 + 4 * (l >> 4));
    h16x4 ah;
#pragma unroll
    for (int j = 0; j < 4; ++j) ah[j] = (_Float16)av[j];
#pragma unroll
    for (int ct = 0; ct < 8; ++ct)
      acc[ct] = mfma16(ah, ((const h16x4*)wL)[(kt * 8 + ct) * 64 + l], acc[ct]);
  }
#pragma unroll
  for (int r = 0; r < 4; ++r) {
    int pix = p0 + 4 * (l >> 4) + r;
    float rr = rsqrtf(msq[(size_t)(b * NQ) + pix] * (1.f / 128.f) + EPS_RMS);
#pragma unroll
    for (int ct = 0; ct < 8; ++ct)
      qp[((size_t)(b * NQ) + pix) * 128 + ct * 16 + (l & 15)] =
          acc[ct][r] * rr + bias[ct * 16 + (l & 15)];
  }
}

// ---------- attention: QK^T + softmax + head-mean -> packed fp16 P ----------

__global__ __launch_bounds__(256) void k_attn1m(
    const float* __restrict__ qp, const float* __restrict__ kpb,
    _Float16* __restrict__ Ph) {
  __shared__ float sP[4][16][212];
  int t = threadIdx.x, l = t & 63, h = t >> 6;
  int b = blockIdx.x / 784, qt = blockIdx.x % 784;
  int q0 = qt * 16;
  constexpr float SC = 0.17677669529663687f;  // 1/sqrt(32)
  h16x4 aq[2];
#pragma unroll
  for (int kt = 0; kt < 2; ++kt) {
    f32x4 v = *(const f32x4*)(qp + ((size_t)(b * NQ) + q0 + (l & 15)) * 128 +
                              h * 32 + kt * 16 + 4 * (l >> 4));
    h16x4 ah;
#pragma unroll
    for (int j = 0; j < 4; ++j) ah[j] = (_Float16)v[j];
    aq[kt] = ah;
  }
  f32x4 z = {0.f, 0.f, 0.f, 0.f};
  f32x4 acc[13];
#pragma unroll
  for (int nt = 0; nt < 13; ++nt) acc[nt] = z;
#pragma unroll
  for (int nt = 0; nt < 13; ++nt) {
    int key = nt * 16 + (l & 15);
    bool ok = key < 196;
#pragma unroll
    for (int kt = 0; kt < 2; ++kt) {
      h16x4 bf = {(_Float16)0.f, (_Float16)0.f, (_Float16)0.f, (_Float16)0.f};
      if (ok) {
        f32x4 v = *(const f32x4*)(kpb + ((size_t)(b * 196) + key) * 128 +
                                  h * 32 + kt * 16 + 4 * (l >> 4));
#pragma unroll
        for (int j = 0; j < 4; ++j) bf[j] = (_Float16)v[j];
      }
      acc[nt] = mfma16(aq[kt], bf, acc[nt]);
    }
  }
#pragma unroll
  for (int r = 0; r < 4; ++r) {
    float mx = -3e38f;
#pragma unroll
    for (int nt = 0; nt < 13; ++nt) {
      bool ok = nt * 16 + (l & 15) < 196;
      float v = ok ? acc[nt][r] * SC : -3e38f;
      acc[nt][r] = v;
      mx = fmaxf(mx, v);
    }
    for (int m = 1; m < 16; m <<= 1) mx = fmaxf(mx, __shfl_xor(mx, m));
    float sum = 0.f;
#pragma unroll
    for (int nt = 0; nt < 13; ++nt) {
      bool ok = nt * 16 + (l & 15) < 196;
      float e = ok ? __expf(acc[nt][r] - mx) : 0.f;
      acc[nt][r] = e;
      sum += e;
    }
    for (int m = 1; m < 16; m <<= 1) sum += __shfl_xor(sum, m);
    float inv = 1.f / sum;
#pragma unroll
    for (int nt = 0; nt < 13; ++nt)
      sP[h][4 * (l >> 4) + r][nt * 16 + (l & 15)] = acc[nt][r] * inv;
  }
  __syncthreads();
  // head-mean + pack into MFMA B-frag order
  _Float16* pb = Ph + (size_t)(b * 784 + qt) * 13 * 256;
  for (int i = t; i < 832; i += 256) {
    int kt = i >> 6, ll = i & 63;
    int q = ll & 15, kb = kt * 16 + 4 * (ll >> 4);
    h16x4 v;
#pragma unroll
    for (int j = 0; j < 4; ++j) {
      int k = kb + j;
      float s = 0.25f * (sP[0][q][k] + sP[1][q][k] + sP[2][q][k] + sP[3][q][k]);
      v[j] = (_Float16)s;
    }
    *(h16x4*)(pb + (size_t)i * 4) = v;
  }
}

// ---------- attention PV: pure fragment streaming, no LDS ----------

__global__ __launch_bounds__(256) void k_attn2m(
    const _Float16* __restrict__ Ph, const _Float16* __restrict__ featB,
    float* __restrict__ out) {
  int t = threadIdx.x, l = t & 63, w = t >> 6;
  int b = blockIdx.x / 196, qt = blockIdx.x % 196;
  int q16 = qt * 4 + w;             // this wave's 16-query tile
  f32x4 z = {0.f, 0.f, 0.f, 0.f};
  f32x4 acc[24];
#pragma unroll
  for (int dt = 0; dt < 24; ++dt) acc[dt] = z;
  const h16x4* PB = (const h16x4*)Ph + ((size_t)(b * 784 + q16) * 13) * 64 + l;
  const h16x4* FB = (const h16x4*)featB + (size_t)b * 13 * 24 * 64 + l;
  for (int kt = 0; kt < 13; ++kt) {
    h16x4 bp = PB[kt * 64];
    const h16x4* fb = FB + kt * 24 * 64;
#pragma unroll
    for (int dt = 0; dt < 24; ++dt)
      acc[dt] = mfma16(fb[(size_t)dt * 64], bp, acc[dt]);
  }
  int qg = q16 * 16 + (l & 15);
#pragma unroll
  for (int dt = 0; dt < 24; ++dt)
#pragma unroll
    for (int r = 0; r < 4; ++r) {
      int d = dt * 16 + 4 * (l >> 4) + r;
      out[((size_t)(b * 384) + d) * NQ + qg] = acc[dt][r];
    }
}

}  // namespace

extern "C" void kernel_launch(void* const* d_in, const int* in_sizes, int n_in,
                              void* d_out, int out_size, void* d_ws,
                              size_t ws_size, hipStream_t stream) {
  (void)in_sizes; (void)n_in; (void)out_size; (void)ws_size;
  const float* image        = (const float*)d_in[0];
  const float* features     = (const float*)d_in[1];
  const float* rope_f       = (const float*)d_in[2];
  const float* img_conv_w   = (const float*)d_in[3];
  const float* img_proj_w   = (const float*)d_in[4];
  const float* qenc_w       = (const float*)d_in[5];
  const float* kenc_w       = (const float*)d_in[6];
  const float* kfeat_conv_w = (const float*)d_in[7];
  const float* kfeat_proj_w = (const float*)d_in[8];
  const float* sft_gamma_w  = (const float*)d_in[9];
  const float* sft_beta_w   = (const float*)d_in[10];
  const float* block_conv_w = (const float*)d_in[11];
  const float* rms_q_w      = (const float*)d_in[12];
  const float* rms_k_w      = (const float*)d_in[13];
  const float* q_proj_w     = (const float*)d_in[14];
  const float* q_proj_b     = (const float*)d_in[15];
  const float* k_proj_w     = (const float*)d_in[16];
  const float* k_proj_b     = (const float*)d_in[17];
  float* out = (float*)d_out;
  float* ws = (float*)d_ws;

  size_t off = 0;
  auto alloc = [&](size_t n) {
    size_t r = off;
    off += (n + 63) & ~(size_t)63;
    return r;
  };
  _Float16* WqB  = (_Float16*)(ws + alloc(8192));
  _Float16* WkB  = (_Float16*)(ws + alloc(8192));
  _Float16* QPB  = (_Float16*)(ws + alloc(8192));
  _Float16* W3B  = (_Float16*)(ws + alloc(73728));
  float* KFT      = ws + alloc(49152);
  float* KFPT     = ws + alloc(49152);
  float* GT       = ws + alloc(16384);
  float* BT       = ws + alloc(16384);
  float* KPT      = ws + alloc(16384);
  float* cosT     = ws + alloc(14336);
  float* sinT     = ws + alloc(14336);
  _Float16* featB = (_Float16*)(ws + alloc(159744));  // 319488 fp16
  float* imgpart  = ws + alloc(2304);
  float* img_murs = ws + alloc(64);
  float* qk_murs  = ws + alloc(128);
  float* murs2    = ws + alloc(64);
  float* kgn_murs = ws + alloc(64);
  float* kf_murs  = ws + alloc(64);
  float* G        = ws + alloc(65536);
  float* mvec     = ws + alloc(512);
  float* mpart    = ws + alloc(392 * 128);
  float* Qpart    = ws + alloc((size_t)BB * 784 * 16);
  float* kpp      = ws + alloc((size_t)BB * 784 * 128);
  float* y_kf     = ws + alloc(100352);
  float* skip_kf  = ws + alloc(100352);
  float* k_final  = ws + alloc(100352);
  float* k_pool   = ws + alloc(100352);
  float* kpb      = ws + alloc(100352);
  float* msq      = ws + alloc(50176);
  // RA (25.7MB): fnb -> Gpart -> q_pool -> qp   (all stream-ordered disjoint in time)
  float* RA = ws + alloc((size_t)BB * NQ * 128);
  // ENC (51.4MB): encF -> (qconv, Ph)
  float* ENCp = ws + alloc((size_t)BB * 784 * 8192 / 2);  // 12845056 floats
  float* fnb    = RA;
  float* Gpart  = RA;           // 392*16384 = 6422528 floats == |RA|
  float* q_pool = RA;
  float* qp     = RA;
  _Float16* encF = (_Float16*)ENCp;
  float* qconv   = ENCp;
  _Float16* Ph   = (_Float16*)(ENCp + (size_t)BB * NQ * 128);  // after qconv

  // fused weight/table/feature prep
  k_prep<<<2648, 256, 0, stream>>>(qenc_w, kenc_w, q_proj_w, rms_q_w,
                                   block_conv_w, kfeat_conv_w, kfeat_proj_w,
                                   sft_gamma_w, sft_beta_w, k_proj_w, rms_k_w,
                                   rope_f, features,
                                   WqB, WkB, QPB, W3B, KFT, KFPT, GT, BT, KPT,
                                   cosT, sinT, featB);

  // image GN stats (Gram trick over 3 channels)
  k_imgstat1<<<BB * 64, 256, 0, stream>>>(image, imgpart);
  k_imgstat2<<<BB, 128, 0, stream>>>(imgpart, img_conv_w, img_murs);

  // kf branch early (fnb in RA, dead before Gpart is written)
  k_fn<<<BB, 256, 0, stream>>>(features, fnb);
  k_kfconv<<<BB * 4, 256, 0, stream>>>(fnb, KFT, KFPT, y_kf, skip_kf);
  k_gnstats<<<32, 256, 0, stream>>>(y_kf, kf_murs, NKk, EPS_GN);

  // enc producer: materialize encF + Gram partials
  k_gram<<<BB * 98, 256, 0, stream>>>(image, cosT, sinT, img_conv_w,
                                      img_proj_w, img_murs, encF, Gpart, mpart);
  k_gred<<<BB * 64, 256, 0, stream>>>(Gpart, mpart, G, mvec);
  k_gstats<<<64, 256, 0, stream>>>(G, mvec, qenc_w, kenc_w, qk_murs);

  // q/k enc_blocks + pooling from encF (LDS-free, 3136 blocks)
  k_passA2<<<BB * 784, 256, 0, stream>>>(encF, qk_murs, WqB, WkB,
                                         q_pool, kpp, Qpart);
  k_qstatfin<<<32, 256, 0, stream>>>(Qpart, murs2);
  k_kpred<<<392, 256, 0, stream>>>(kpp, k_pool);
  k_gnstats<<<32, 256, 0, stream>>>(k_pool, kgn_murs, NKk, EPS_GN);

  // k side (tiny, VALU)
  k_sft<<<BB * 4, 256, 0, stream>>>(y_kf, skip_kf, kf_murs, GT, BT, k_pool,
                                    kgn_murs, k_final);
  k_rmsproj<<<BB * 4, 256, 0, stream>>>(k_final, KPT, k_proj_b, kpb, NKk);

  // q side (MFMA)
  k_conv3m<<<BB * 98, 256, 0, stream>>>(q_pool, murs2, W3B, qconv, msq);
  k_rmsq<<<BB * 196, 256, 0, stream>>>(qconv, QPB, msq, q_proj_b, qp);

  // attention
  k_attn1m<<<BB * 784, 256, 0, stream>>>(qp, kpb, Ph);
  k_attn2m<<<BB * 196, 256, 0, stream>>>(Ph, featB, out);
}

// Round 7
// 469.322 us; speedup vs baseline: 4.3292x; 1.3933x over previous
//
#include <hip/hip_runtime.h>
#include <cstdint>
#include <cstddef>

#define DEV __device__ __forceinline__

namespace {

constexpr int BB   = 4;
constexpr int HWP  = 50176;   // 224*224
constexpr int NQ   = 12544;   // 112*112
constexpr int NKk  = 196;     // 14*14
constexpr int VD   = 384;
constexpr float EPS_GN  = 1e-5f;
constexpr float EPS_RMS = 1.1920929e-7f;

typedef __attribute__((ext_vector_type(4))) float f32x4;
typedef __attribute__((ext_vector_type(4))) _Float16 h16x4;

DEV float silu_f(float z) { return z / (1.f + __expf(-z)); }
DEV int rfl(int v) { return __builtin_amdgcn_readfirstlane(v); }

DEV f32x4 mfma16(h16x4 a, h16x4 b, f32x4 c) {
  return __builtin_amdgcn_mfma_f32_16x16x16f16(a, b, c, 0, 0, 0);
}

// ---------- fused weight prep (one launch) ----------
DEV void pack16_one(int id, const float* W, const float* rowscale,
                    _Float16* dst) {
  int j = id & 3, l = (id >> 2) & 63, tile = id >> 8;
  int ct = tile & 7, kt = tile >> 3;
  int ci = kt * 16 + 4 * (l >> 4) + j;
  int co = ct * 16 + (l & 15);
  float v = W[(size_t)co * 128 + ci];
  if (rowscale) v *= rowscale[ci];
  dst[id] = (_Float16)v;
}
// pack 128x384 weight into frag order, K=384 (24 kt)
DEV void pack384_one(int id, const float* W, _Float16* dst) {
  int j = id & 3, l = (id >> 2) & 63, rest = id >> 8;
  int ct = rest & 7, kt = rest >> 3;          // kt 0..23
  int ci = kt * 16 + 4 * (l >> 4) + j;
  int co = ct * 16 + (l & 15);
  dst[id] = (_Float16)W[(size_t)co * 384 + ci];
}

__global__ __launch_bounds__(256) void k_prep(
    const float* __restrict__ qenc_w, const float* __restrict__ kenc_w,
    const float* __restrict__ q_proj_w, const float* __restrict__ rms_q_w,
    const float* __restrict__ block_conv_w,
    const float* __restrict__ kfeat_conv_w, const float* __restrict__ kfeat_proj_w,
    const float* __restrict__ sft_gamma_w, const float* __restrict__ sft_beta_w,
    const float* __restrict__ k_proj_w, const float* __restrict__ rms_k_w,
    const float* __restrict__ ropef, const float* __restrict__ feat,
    _Float16* __restrict__ WqB, _Float16* __restrict__ WkB,
    _Float16* __restrict__ QPB, _Float16* __restrict__ W3B,
    _Float16* __restrict__ KFB, _Float16* __restrict__ KFPB,
    _Float16* __restrict__ GB, _Float16* __restrict__ BBf,
    _Float16* __restrict__ KPB,
    float* __restrict__ cosT, float* __restrict__ sinT,
    _Float16* __restrict__ featB) {
  int idx = blockIdx.x * 256 + threadIdx.x;
  if (idx < 16384) {
    pack16_one(idx, qenc_w, nullptr, WqB);
  } else if (idx < 32768) {
    pack16_one(idx - 16384, kenc_w, nullptr, WkB);
  } else if (idx < 49152) {
    pack16_one(idx - 32768, q_proj_w, rms_q_w, QPB);
  } else if (idx < 196608) {
    int id = idx - 49152;
    int j = id & 3, l = (id >> 2) & 63, tile = (id >> 8) & 63, tap = id >> 14;
    int ct = tile & 7, kt = tile >> 3;
    int ci = kt * 16 + 4 * (l >> 4) + j;
    int co = ct * 16 + (l & 15);
    W3B[id] = (_Float16)block_conv_w[((size_t)co * 128 + ci) * 9 + tap];
  } else if (idx < 245760) {
    pack384_one(idx - 196608, kfeat_conv_w, KFB);
  } else if (idx < 294912) {
    pack384_one(idx - 245760, kfeat_proj_w, KFPB);
  } else if (idx < 311296) {
    pack16_one(idx - 294912, sft_gamma_w, nullptr, GB);
  } else if (idx < 327680) {
    pack16_one(idx - 311296, sft_beta_w, nullptr, BBf);
  } else if (idx < 344064) {
    pack16_one(idx - 327680, k_proj_w, rms_k_w, KPB);
  } else if (idx < 358400) {
    int id = idx - 344064;            // pos*64 + d
    int pos = id >> 6, d = id & 63;
    float a = (pos + 0.5f) * (1.f / 224.f) * ropef[d];
    float s, c;
    __sincosf(a, &s, &c);
    cosT[id] = c;
    sinT[id] = s;
  } else if (idx < 677888) {
    int id = idx - 358400;            // (((b*13+kt)*24+dt)*64+l)*4+j
    int j = id & 3, l = (id >> 2) & 63;
    int rest = id >> 8;
    int dt = rest % 24;
    int kt = (rest / 24) % 13;
    int b = rest / (24 * 13);
    int key = kt * 16 + 4 * (l >> 4) + j;
    int d = dt * 16 + (l & 15);
    float v = (key < 196) ? feat[((size_t)(b * 384) + d) * 196 + key] : 0.f;
    featB[id] = (_Float16)v;
  }
}

// ---------- image GN stats via 3x3 Gram ----------

__global__ __launch_bounds__(256) void k_imgstat1(
    const float* __restrict__ img, float* __restrict__ part) {
  __shared__ float lds[4][9];
  int b = blockIdx.x >> 6, blk = blockIdx.x & 63;
  int t = threadIdx.x;
  float a[9];
#pragma unroll
  for (int j = 0; j < 9; ++j) a[j] = 0.f;
  const float* ib = img + (size_t)b * 3 * HWP;
  for (int pix = blk * 784 + t; pix < blk * 784 + 784; pix += 256) {
    float x0 = ib[pix], x1 = ib[HWP + pix], x2 = ib[2 * HWP + pix];
    a[0] += x0; a[1] += x1; a[2] += x2;
    a[3] += x0 * x0; a[4] += x0 * x1; a[5] += x0 * x2;
    a[6] += x1 * x1; a[7] += x1 * x2; a[8] += x2 * x2;
  }
#pragma unroll
  for (int j = 0; j < 9; ++j)
    for (int m = 1; m < 64; m <<= 1) a[j] += __shfl_xor(a[j], m);
  if ((t & 63) == 0)
    for (int j = 0; j < 9; ++j) lds[t >> 6][j] = a[j];
  __syncthreads();
  if (t < 9)
    part[(size_t)blockIdx.x * 9 + t] =
        lds[0][t] + lds[1][t] + lds[2][t] + lds[3][t];
}

__global__ __launch_bounds__(128) void k_imgstat2(
    const float* __restrict__ part, const float* __restrict__ wimg,
    float* __restrict__ img_murs) {
  __shared__ float MG[9];
  int b = blockIdx.x, t = threadIdx.x;
  if (t < 9) {
    float s = 0.f;
    for (int i = 0; i < 64; ++i) s += part[(size_t)(b * 64 + i) * 9 + t];
    MG[t] = s;
  }
  __syncthreads();
  int c = t;
  float w0 = wimg[c * 3], w1 = wimg[c * 3 + 1], w2 = wimg[c * 3 + 2];
  float s1 = w0 * MG[0] + w1 * MG[1] + w2 * MG[2];
  float s2 = w0 * w0 * MG[3] + w1 * w1 * MG[6] + w2 * w2 * MG[8] +
             2.f * (w0 * w1 * MG[4] + w0 * w2 * MG[5] + w1 * w2 * MG[7]);
  for (int m = 1; m < 16; m <<= 1) {
    s1 += __shfl_xor(s1, m);
    s2 += __shfl_xor(s2, m);
  }
  if ((c & 15) == 0) {
    int g = c >> 4;
    float invN = 1.f / (16.f * HWP);
    float mu = s1 * invN;
    float var = s2 * invN - mu * mu;
    img_murs[b * 16 + g] = mu;
    img_murs[b * 16 + 8 + g] = rsqrtf(var + EPS_GN);
  }
}

// ---------- enc producer + Gram + enc_frag materialization ----------

__global__ __launch_bounds__(256) void k_gram(
    const float* __restrict__ img, const float* __restrict__ cosT,
    const float* __restrict__ sinT,
    const float* __restrict__ wimg, const float* __restrict__ wimgp,
    const float* __restrict__ img_murs,
    _Float16* __restrict__ encF,
    float* __restrict__ Gpart, float* __restrict__ mpart) {
  __shared__ __align__(16) _Float16 fragP[2080 * 4];   // [kt*4+mt][lane(65 pad)][j]
  __shared__ __align__(16) _Float16 fragC[8192];       // [pk][ct][lane][j]
  __shared__ float sWc[384], sWp[384], sMu[8], sRs[8];
  int t = threadIdx.x, l = t & 63, w = t >> 6;
  int b = blockIdx.x / 98, blk = blockIdx.x % 98;
  for (int i = t; i < 384; i += 256) { sWc[i] = wimg[i]; sWp[i] = wimgp[i]; }
  if (t < 8) { sMu[t] = img_murs[b * 16 + t]; sRs[t] = img_murs[b * 16 + 8 + t]; }
  f32x4 acc[2][8];
  f32x4 macc[2];
  f32x4 z = {0.f, 0.f, 0.f, 0.f};
#pragma unroll
  for (int e = 0; e < 2; ++e) {
    macc[e] = z;
#pragma unroll
    for (int nt = 0; nt < 8; ++nt) acc[e][nt] = z;
  }
  h16x4 hone = {(_Float16)1.f, (_Float16)1.f, (_Float16)1.f, (_Float16)1.f};
  int mt = l >> 4;
  int laneCbase = 16 * ((l & 15) >> 2);
  int jC = (l & 15) & 3;
  for (int s = 0; s < 8; ++s) {
    int sub = blk * 8 + s;
    int tile = sub >> 2, st = sub & 3;
    int py = (tile / 14) * 16 + ((st >> 1) << 3) + (l >> 3);
    int px = (tile % 14) * 16 + ((st & 1) << 3) + (l & 7);
    __syncthreads();
    {
      const float* ip = img + (size_t)b * 3 * HWP + py * 224 + px;
      float x0 = ip[0], x1 = ip[HWP], x2 = ip[2 * HWP];
      const float* cy = cosT + py * 64 + w * 16;
      const float* sy = sinT + py * 64 + w * 16;
      const float* cx = cosT + px * 64 + w * 16;
      const float* sx = sinT + px * 64 + w * 16;
#pragma unroll
      for (int jj = 0; jj < 4; ++jj) {
        f32x4 cyv = *(const f32x4*)(cy + jj * 4);
        f32x4 syv = *(const f32x4*)(sy + jj * 4);
        f32x4 cxv = *(const f32x4*)(cx + jj * 4);
        f32x4 sxv = *(const f32x4*)(sx + jj * 4);
        h16x4 lo4, hi4;
#pragma unroll
        for (int u = 0; u < 4; ++u) {
          int d = w * 16 + jj * 4 + u;
          int c2 = d + 64;
          float y1 = sWc[d * 3] * x0 + sWc[d * 3 + 1] * x1 + sWc[d * 3 + 2] * x2;
          float s1 = sWp[d * 3] * x0 + sWp[d * 3 + 1] * x1 + sWp[d * 3 + 2] * x2;
          float y2 = sWc[c2 * 3] * x0 + sWc[c2 * 3 + 1] * x1 + sWc[c2 * 3 + 2] * x2;
          float s2 = sWp[c2 * 3] * x0 + sWp[c2 * 3 + 1] * x1 + sWp[c2 * 3 + 2] * x2;
          int g1 = d >> 4, g2 = g1 + 4;
          float t1 = silu_f((y1 - sMu[g1]) * sRs[g1]) + s1;
          float t2 = silu_f((y2 - sMu[g2]) * sRs[g2]) + s2;
          lo4[u] = (_Float16)(t1 * cyv[u] - t2 * syv[u]);
          hi4[u] = (_Float16)(t2 * cxv[u] + t1 * sxv[u]);
        }
        int lane = (l & 15) + 16 * jj;
        *(h16x4*)&fragP[((w * 4 + mt) * 65 + lane) * 4]       = lo4;
        *(h16x4*)&fragP[(((w + 4) * 4 + mt) * 65 + lane) * 4] = hi4;
#pragma unroll
        for (int u = 0; u < 4; ++u) {
          int laneC = jj * 4 + u + laneCbase;
          fragC[((mt * 8 + w) * 64 + laneC) * 4 + jC]     = lo4[u];
          fragC[((mt * 8 + w + 4) * 64 + laneC) * 4 + jC] = hi4[u];
        }
      }
    }
    __syncthreads();
    _Float16* ef = encF + ((size_t)(b * 784) + sub) * 8192;
    for (int i = t; i < 2048; i += 256) {
      int kt = i >> 8, m2 = (i >> 6) & 3, ln = i & 63;
      *(h16x4*)(ef + (size_t)i * 4) =
          *(const h16x4*)&fragP[((kt * 4 + m2) * 65 + ln) * 4];
    }
#pragma unroll
    for (int pk = 0; pk < 4; ++pk) {
      h16x4 a0 = *(const h16x4*)&fragC[((pk * 8 + 2 * w) * 64 + l) * 4];
      h16x4 a1 = *(const h16x4*)&fragC[((pk * 8 + 2 * w + 1) * 64 + l) * 4];
      macc[0] = mfma16(a0, hone, macc[0]);
      macc[1] = mfma16(a1, hone, macc[1]);
#pragma unroll
      for (int nt = 0; nt < 8; ++nt) {
        h16x4 bv = *(const h16x4*)&fragC[((pk * 8 + nt) * 64 + l) * 4];
        acc[0][nt] = mfma16(a0, bv, acc[0][nt]);
        acc[1][nt] = mfma16(a1, bv, acc[1][nt]);
      }
    }
  }
  float* gp = Gpart + (size_t)(b * 98 + blk) * 16384;
#pragma unroll
  for (int e = 0; e < 2; ++e)
#pragma unroll
    for (int nt = 0; nt < 8; ++nt)
#pragma unroll
      for (int r = 0; r < 4; ++r) {
        int row = (2 * w + e) * 16 + 4 * (l >> 4) + r;
        int col = nt * 16 + (l & 15);
        gp[row * 128 + col] = acc[e][nt][r];
      }
  if ((l & 15) == 0) {
    float* mp = mpart + (size_t)(b * 98 + blk) * 128;
#pragma unroll
    for (int e = 0; e < 2; ++e)
#pragma unroll
      for (int r = 0; r < 4; ++r)
        mp[(2 * w + e) * 16 + 4 * (l >> 4) + r] = macc[e][r];
  }
}

__global__ void k_gred(const float* __restrict__ Gpart,
                       const float* __restrict__ mpart,
                       float* __restrict__ G, float* __restrict__ mvec) {
  int b = blockIdx.x >> 6, chunk = blockIdx.x & 63;
  int idx = chunk * 256 + threadIdx.x;
  float s = 0.f;
  for (int i = 0; i < 98; ++i) s += Gpart[(size_t)(b * 98 + i) * 16384 + idx];
  G[(size_t)b * 16384 + idx] = s;
  if (idx < 128) {
    float sm = 0.f;
    for (int i = 0; i < 98; ++i) sm += mpart[(size_t)(b * 98 + i) * 128 + idx];
    mvec[b * 128 + idx] = sm;
  }
}

__global__ __launch_bounds__(256) void k_gstats(
    const float* __restrict__ G, const float* __restrict__ mvec,
    const float* __restrict__ qw, const float* __restrict__ kw,
    float* __restrict__ qk_murs) {
  __shared__ float red1[4], red2[4];
  int bi = blockIdx.x;               // conv*32 + b*8 + g
  int conv = bi >> 5, b = (bi >> 3) & 3, g = bi & 7;
  const float* W = conv ? kw : qw;
  int t = threadIdx.x;
  int c = g * 16 + (t >> 4);
  int i0 = (t & 15) * 8;
  const float* wc = W + (size_t)c * 128;
  const float* Gb = G + (size_t)b * 16384;
  const float* mb = mvec + b * 128;
  float s1 = 0.f, s2 = 0.f;
  for (int i = i0; i < i0 + 8; ++i) {
    float gi = 0.f;
    for (int j = 0; j < 128; ++j) gi += Gb[i * 128 + j] * wc[j];
    s2 += wc[i] * gi;
    s1 += wc[i] * mb[i];
  }
  for (int m = 1; m < 64; m <<= 1) { s1 += __shfl_xor(s1, m); s2 += __shfl_xor(s2, m); }
  if ((t & 63) == 0) { red1[t >> 6] = s1; red2[t >> 6] = s2; }
  __syncthreads();
  if (t == 0) {
    float S1 = red1[0] + red1[1] + red1[2] + red1[3];
    float S2 = red2[0] + red2[1] + red2[2] + red2[3];
    float invN = 1.f / 802816.f;
    float mu = S1 * invN;
    float var = S2 * invN - mu * mu;
    qk_murs[bi * 2] = mu;
    qk_murs[bi * 2 + 1] = rsqrtf(var + EPS_GN);
  }
}

// ---------- pass A: q/k enc_blocks from encF (no LDS, no barriers) ----------

__global__ __launch_bounds__(256) void k_passA2(
    const _Float16* __restrict__ encF, const float* __restrict__ qk_murs,
    const _Float16* __restrict__ WqB, const _Float16* __restrict__ WkB,
    float* __restrict__ q_pool, float* __restrict__ kpp,
    float* __restrict__ Qpart) {
  int t = threadIdx.x, l = t & 63;
  int wu = rfl(t >> 6);
  int bi = blockIdx.x;
  int b = bi / 784, sub = bi % 784;
  int tile = sub >> 2, st = sub & 3;
  int by = (tile / 14) * 16, bx = (tile % 14) * 16;
  float qmu[2], qrs[2], kmu[2], krs[2];
#pragma unroll
  for (int cc = 0; cc < 2; ++cc) {
    int g = 2 * wu + cc;
    qmu[cc] = qk_murs[(b * 8 + g) * 2];
    qrs[cc] = qk_murs[(b * 8 + g) * 2 + 1];
    kmu[cc] = qk_murs[(32 + b * 8 + g) * 2];
    krs[cc] = qk_murs[(32 + b * 8 + g) * 2 + 1];
  }
  const h16x4* EF = (const h16x4*)encF + ((size_t)(b * 784) + sub) * 2048;
  f32x4 z = {0.f, 0.f, 0.f, 0.f};
  f32x4 accQ[4][2], accK[4][2];
#pragma unroll
  for (int mt = 0; mt < 4; ++mt)
#pragma unroll
    for (int cc = 0; cc < 2; ++cc) { accQ[mt][cc] = z; accK[mt][cc] = z; }
  for (int kt = 0; kt < 8; ++kt) {
    h16x4 a[4];
#pragma unroll
    for (int mt = 0; mt < 4; ++mt) a[mt] = EF[(kt * 4 + mt) * 64 + l];
    int fi = (kt * 8 + 2 * wu) * 64 + l;
    h16x4 bq0 = *(const h16x4*)(WqB + (size_t)fi * 4);
    h16x4 bq1 = *(const h16x4*)(WqB + (size_t)(fi + 64) * 4);
    h16x4 bk0 = *(const h16x4*)(WkB + (size_t)fi * 4);
    h16x4 bk1 = *(const h16x4*)(WkB + (size_t)(fi + 64) * 4);
#pragma unroll
    for (int mt = 0; mt < 4; ++mt) {
      accQ[mt][0] = mfma16(a[mt], bq0, accQ[mt][0]);
      accQ[mt][1] = mfma16(a[mt], bq1, accQ[mt][1]);
      accK[mt][0] = mfma16(a[mt], bk0, accK[mt][0]);
      accK[mt][1] = mfma16(a[mt], bk1, accK[mt][1]);
    }
  }
  const _Float16* EH = encF + ((size_t)(b * 784) + sub) * 8192;
  int cl = l & 15;
  int clo = 16 * (cl >> 2), cj = cl & 3;
  float kacc0 = 0.f, kacc1 = 0.f;
  float qs1[2] = {0.f, 0.f}, qs2[2] = {0.f, 0.f};
#pragma unroll
  for (int cc = 0; cc < 2; ++cc) {
    int g = 2 * wu + cc;
    int cout = g * 16 + cl;
    float kav = 0.f;
#pragma unroll
    for (int mt = 0; mt < 4; ++mt) {
      float qv[4];
#pragma unroll
      for (int r = 0; r < 4; ++r) {
        int m = 4 * (l >> 4) + r;
        float skip = (float)EH[((g * 4 + mt) * 64 + m + clo) * 4 + cj];
        qv[r] = silu_f((accQ[mt][cc][r] - qmu[cc]) * qrs[cc]) + skip;
        kav += silu_f((accK[mt][cc][r] - kmu[cc]) * krs[cc]) + skip;
      }
      float s01 = qv[0] + qv[1], s23 = qv[2] + qv[3];
      s01 += __shfl_xor(s01, 32);
      s23 += __shfl_xor(s23, 32);
      if ((l >> 4) < 2) {
        int py2 = (by + (st >> 1) * 8 + 2 * mt) >> 1;
        int px2 = (bx + (st & 1) * 8 + (l >> 4) * 4) >> 1;
        size_t base = ((size_t)(b * NQ) + py2 * 112 + px2) * 128 + cout;
        float pv0 = s01 * 0.25f, pv1 = s23 * 0.25f;
        q_pool[base] = pv0;
        q_pool[base + 128] = pv1;
        qs1[cc] += pv0 + pv1;
        qs2[cc] += pv0 * pv0 + pv1 * pv1;
      }
    }
    if (cc == 0) kacc0 = kav; else kacc1 = kav;
  }
  kacc0 += __shfl_xor(kacc0, 16); kacc0 += __shfl_xor(kacc0, 32);
  kacc1 += __shfl_xor(kacc1, 16); kacc1 += __shfl_xor(kacc1, 32);
  if (l < 16) {
    kpp[(size_t)bi * 128 + (2 * wu) * 16 + l]       = kacc0;
    kpp[(size_t)bi * 128 + (2 * wu + 1) * 16 + l]   = kacc1;
  }
#pragma unroll
  for (int cc = 0; cc < 2; ++cc) {
    float a1 = qs1[cc], a2 = qs2[cc];
    for (int m = 1; m < 64; m <<= 1) {
      a1 += __shfl_xor(a1, m);
      a2 += __shfl_xor(a2, m);
    }
    if (l == 0) {
      Qpart[(size_t)bi * 16 + (2 * wu + cc) * 2] = a1;
      Qpart[(size_t)bi * 16 + (2 * wu + cc) * 2 + 1] = a2;
    }
  }
}

__global__ __launch_bounds__(256) void k_kpred(
    const float* __restrict__ kpp, float* __restrict__ k_pool) {
  int idx = blockIdx.x * 256 + threadIdx.x;
  if (idx >= BB * 128 * NKk) return;
  int b = idx / (128 * NKk);
  int rem = idx % (128 * NKk);
  int c = rem / NKk, tile = rem % NKk;
  const float* base = kpp + ((size_t)(b * 196 + tile) * 4) * 128 + c;
  float s = base[0] + base[128] + base[256] + base[384];
  k_pool[idx] = s * (1.f / 256.f);
}

__global__ __launch_bounds__(256) void k_qstatfin(
    const float* __restrict__ Qpart, float* __restrict__ murs2) {
  __shared__ float l1[4], l2[4];
  int b = blockIdx.x >> 3, g = blockIdx.x & 7, t = threadIdx.x;
  float s1 = 0.f, s2 = 0.f;
  for (int i = t; i < 784; i += 256) {
    s1 += Qpart[((size_t)(b * 784) + i) * 16 + g * 2];
    s2 += Qpart[((size_t)(b * 784) + i) * 16 + g * 2 + 1];
  }
  for (int m = 1; m < 64; m <<= 1) { s1 += __shfl_xor(s1, m); s2 += __shfl_xor(s2, m); }
  if ((t & 63) == 0) { l1[t >> 6] = s1; l2[t >> 6] = s2; }
  __syncthreads();
  if (t == 0) {
    float a = l1[0] + l1[1] + l1[2] + l1[3];
    float bq = l2[0] + l2[1] + l2[2] + l2[3];
    float invN = 1.f / (16.f * (float)NQ);
    float mu = a * invN;
    float var = bq * invN - mu * mu;
    murs2[blockIdx.x * 2] = mu;
    murs2[blockIdx.x * 2 + 1] = rsqrtf(var + EPS_GN);
  }
}

// ---------- GN stats (channel-major src[b][c][P]) ----------

__global__ __launch_bounds__(256) void k_gnstats(
    const float* __restrict__ src, float* __restrict__ murs, int P, float eps) {
  __shared__ float l1[4], l2[4];
  int b = blockIdx.x >> 3, g = blockIdx.x & 7, t = threadIdx.x;
  const float* base = src + ((size_t)(b * 128) + g * 16) * P;
  float s1 = 0.f, s2 = 0.f;
  for (int i = t; i < 16 * P; i += 256) {
    float v = base[i];
    s1 += v; s2 += v * v;
  }
  for (int m = 1; m < 64; m <<= 1) { s1 += __shfl_xor(s1, m); s2 += __shfl_xor(s2, m); }
  if ((t & 63) == 0) { l1[t >> 6] = s1; l2[t >> 6] = s2; }
  __syncthreads();
  if (t == 0) {
    float invN = 1.f / (16.f * (float)P);
    float a = l1[0] + l1[1] + l1[2] + l1[3];
    float bq = l2[0] + l2[1] + l2[2] + l2[3];
    float mu = a * invN;
    float var = bq * invN - mu * mu;
    murs[blockIdx.x * 2] = mu;
    murs[blockIdx.x * 2 + 1] = rsqrtf(var + eps);
  }
}

// ---------- kf branch: fused L2-norm + 384->128 conv+proj (MFMA) ----------
// grid = BB*4, block 256. Tile = 49 px (padded to 64).
__global__ __launch_bounds__(256) void k_kf(
    const float* __restrict__ feat,
    const _Float16* __restrict__ KFB, const _Float16* __restrict__ KFPB,
    float* __restrict__ y_kf, float* __restrict__ skip_kf) {
  __shared__ __align__(16) _Float16 fnF[24 * 4 * 64 * 4];  // 48KB, A-frags
  __shared__ float ssqL[4][64];
  __shared__ float rsqL[64];
  int t = threadIdx.x, l = t & 63, w = t >> 6;
  int b = blockIdx.x >> 2, tile = blockIdx.x & 3;
  int p0 = tile * 49;
  const float* fb = feat + (size_t)b * VD * NKk;
  {  // pass 1: per-pixel sum of squares (thread: pixel=l, k = w+4n)
    float s = 0.f;
    if (l < 49) {
#pragma unroll 4
      for (int k = w; k < VD; k += 4) {
        float v = fb[(size_t)k * NKk + p0 + l];
        s += v * v;
      }
    }
    ssqL[w][l] = s;
  }
  __syncthreads();
  if (t < 64) {
    float s = ssqL[0][t] + ssqL[1][t] + ssqL[2][t] + ssqL[3][t];
    rsqL[t] = rsqrtf(fmaxf(s, 1e-24f));
  }
  __syncthreads();
  // pass 2: stage normalized fp16 A-frags
  for (int i = t; i < VD * 64; i += 256) {
    int k = i >> 6, p = i & 63;
    float v = 0.f;
    if (p < 49) v = fb[(size_t)k * NKk + p0 + p] * rsqL[p];
    int kt = k >> 4, kr = k & 15, u = kr >> 2, j = kr & 3, mt = p >> 4;
    fnF[(((kt * 4 + mt) * 64) + (p & 15) + 16 * u) * 4 + j] = (_Float16)v;
  }
  __syncthreads();
  f32x4 z = {0.f, 0.f, 0.f, 0.f};
  f32x4 accY[4][2], accS[4][2];
#pragma unroll
  for (int mt = 0; mt < 4; ++mt)
#pragma unroll
    for (int cc = 0; cc < 2; ++cc) { accY[mt][cc] = z; accS[mt][cc] = z; }
  for (int kt = 0; kt < 24; ++kt) {
    h16x4 a[4];
#pragma unroll
    for (int mt = 0; mt < 4; ++mt)
      a[mt] = *(const h16x4*)&fnF[((kt * 4 + mt) * 64 + l) * 4];
    int fi = (kt * 8 + 2 * w) * 64 + l;
    h16x4 by0 = *(const h16x4*)(KFB + (size_t)fi * 4);
    h16x4 by1 = *(const h16x4*)(KFB + (size_t)(fi + 64) * 4);
    h16x4 bs0 = *(const h16x4*)(KFPB + (size_t)fi * 4);
    h16x4 bs1 = *(const h16x4*)(KFPB + (size_t)(fi + 64) * 4);
#pragma unroll
    for (int mt = 0; mt < 4; ++mt) {
      accY[mt][0] = mfma16(a[mt], by0, accY[mt][0]);
      accY[mt][1] = mfma16(a[mt], by1, accY[mt][1]);
      accS[mt][0] = mfma16(a[mt], bs0, accS[mt][0]);
      accS[mt][1] = mfma16(a[mt], bs1, accS[mt][1]);
    }
  }
#pragma unroll
  for (int cc = 0; cc < 2; ++cc) {
    int co = (2 * w + cc) * 16 + (l & 15);
#pragma unroll
    for (int mt = 0; mt < 4; ++mt)
#pragma unroll
      for (int r = 0; r < 4; ++r) {
        int pix = mt * 16 + 4 * (l >> 4) + r;
        if (pix < 49) {
          size_t off = ((size_t)(b * 128) + co) * NKk + p0 + pix;
          y_kf[off] = accY[mt][cc][r];
          skip_kf[off] = accS[mt][cc][r];
        }
      }
  }
}

// ---------- merged SFT + RMSNorm + k-proj (MFMA) ----------
// grid = BB*4, block 256. Tile = 49 px.
__global__ __launch_bounds__(256) void k_ksft(
    const float* __restrict__ y_kf, const float* __restrict__ skip_kf,
    const float* __restrict__ kf_murs, const float* __restrict__ kgn_murs,
    const _Float16* __restrict__ GB, const _Float16* __restrict__ BBf,
    const _Float16* __restrict__ KPB,
    const float* __restrict__ k_pool, const float* __restrict__ k_proj_b,
    float* __restrict__ kpb) {
  __shared__ __align__(16) _Float16 kfF[8 * 4 * 64 * 4];  // 16KB A-frags
  __shared__ float msL[4][64];
  __shared__ float sMu[8], sRs[8], sGmu[8], sGrs[8];
  int t = threadIdx.x, l = t & 63, w = t >> 6;
  int b = blockIdx.x >> 2, tile = blockIdx.x & 3;
  int p0 = tile * 49;
  if (t < 8) {
    sMu[t] = kf_murs[(b * 8 + t) * 2];
    sRs[t] = kf_murs[(b * 8 + t) * 2 + 1];
    sGmu[t] = kgn_murs[(b * 8 + t) * 2];
    sGrs[t] = kgn_murs[(b * 8 + t) * 2 + 1];
  }
  __syncthreads();
  // stage kf = silu(GN(y)) + skip as fp16 A-frags
  for (int i = t; i < 128 * 64; i += 256) {
    int c = i >> 6, p = i & 63;
    float v = 0.f;
    if (p < 49) {
      size_t off = ((size_t)(b * 128) + c) * NKk + p0 + p;
      int g = c >> 4;
      v = silu_f((y_kf[off] - sMu[g]) * sRs[g]) + skip_kf[off];
    }
    int kt = c >> 4, kr = c & 15, u = kr >> 2, j = kr & 3, mt = p >> 4;
    kfF[(((kt * 4 + mt) * 64) + (p & 15) + 16 * u) * 4 + j] = (_Float16)v;
  }
  __syncthreads();
  f32x4 z = {0.f, 0.f, 0.f, 0.f};
  f32x4 accG[4][2], accB[4][2];
#pragma unroll
  for (int mt = 0; mt < 4; ++mt)
#pragma unroll
    for (int cc = 0; cc < 2; ++cc) { accG[mt][cc] = z; accB[mt][cc] = z; }
  for (int kt = 0; kt < 8; ++kt) {
    h16x4 a[4];
#pragma unroll
    for (int mt = 0; mt < 4; ++mt)
      a[mt] = *(const h16x4*)&kfF[((kt * 4 + mt) * 64 + l) * 4];
    int fi = (kt * 8 + 2 * w) * 64 + l;
    h16x4 bg0 = *(const h16x4*)(GB + (size_t)fi * 4);
    h16x4 bg1 = *(const h16x4*)(GB + (size_t)(fi + 64) * 4);
    h16x4 bb0 = *(const h16x4*)(BBf + (size_t)fi * 4);
    h16x4 bb1 = *(const h16x4*)(BBf + (size_t)(fi + 64) * 4);
#pragma unroll
    for (int mt = 0; mt < 4; ++mt) {
      accG[mt][0] = mfma16(a[mt], bg0, accG[mt][0]);
      accG[mt][1] = mfma16(a[mt], bg1, accG[mt][1]);
      accB[mt][0] = mfma16(a[mt], bb0, accB[mt][0]);
      accB[mt][1] = mfma16(a[mt], bb1, accB[mt][1]);
    }
  }
  // k_final = gamma * GN(k_pool) + beta; per-pixel sumsq partials
  float kfin[4][2][4];
#pragma unroll
  for (int cc = 0; cc < 2; ++cc) {
    int g = 2 * w + cc;
    int co = g * 16 + (l & 15);
    float gmu = sGmu[g], grs = sGrs[g];
#pragma unroll
    for (int mt = 0; mt < 4; ++mt)
#pragma unroll
      for (int r = 0; r < 4; ++r) {
        int pix = mt * 16 + 4 * (l >> 4) + r;
        float v = 0.f;
        if (pix < 49) {
          float kn = (k_pool[((size_t)(b * 128) + co) * NKk + p0 + pix] - gmu) * grs;
          v = fmaf(accG[mt][cc][r], kn, accB[mt][cc][r]);
        }
        kfin[mt][cc][r] = v;
      }
  }
#pragma unroll
  for (int mt = 0; mt < 4; ++mt)
#pragma unroll
    for (int r = 0; r < 4; ++r) {
      float s2 = kfin[mt][0][r] * kfin[mt][0][r] + kfin[mt][1][r] * kfin[mt][1][r];
      for (int m = 1; m < 16; m <<= 1) s2 += __shfl_xor(s2, m);
      if ((l & 15) == 0) msL[w][mt * 16 + 4 * (l >> 4) + r] = s2;
    }
  __syncthreads();   // msL ready; all kfF reads done -> safe to overwrite
  // stage k_final as fp16 A-frags (K dim = channel)
#pragma unroll
  for (int cc = 0; cc < 2; ++cc) {
    int ktn = 2 * w + cc;
    int u = (l & 15) >> 2, j = (l & 15) & 3;
#pragma unroll
    for (int mt = 0; mt < 4; ++mt)
#pragma unroll
      for (int r = 0; r < 4; ++r) {
        int lane = (4 * (l >> 4) + r) + 16 * u;
        kfF[((ktn * 4 + mt) * 64 + lane) * 4 + j] = (_Float16)kfin[mt][cc][r];
      }
  }
  __syncthreads();
  f32x4 accP[4][2];
#pragma unroll
  for (int mt = 0; mt < 4; ++mt)
#pragma unroll
    for (int cc = 0; cc < 2; ++cc) accP[mt][cc] = z;
  for (int kt = 0; kt < 8; ++kt) {
    h16x4 a[4];
#pragma unroll
    for (int mt = 0; mt < 4; ++mt)
      a[mt] = *(const h16x4*)&kfF[((kt * 4 + mt) * 64 + l) * 4];
    int fi = (kt * 8 + 2 * w) * 64 + l;
    h16x4 b0 = *(const h16x4*)(KPB + (size_t)fi * 4);
    h16x4 b1 = *(const h16x4*)(KPB + (size_t)(fi + 64) * 4);
#pragma unroll
    for (int mt = 0; mt < 4; ++mt) {
      accP[mt][0] = mfma16(a[mt], b0, accP[mt][0]);
      accP[mt][1] = mfma16(a[mt], b1, accP[mt][1]);
    }
  }
#pragma unroll
  for (int mt = 0; mt < 4; ++mt)
#pragma unroll
    for (int r = 0; r < 4; ++r) {
      int pix = mt * 16 + 4 * (l >> 4) + r;
      if (pix >= 49) continue;
      float ms = msL[0][pix] + msL[1][pix] + msL[2][pix] + msL[3][pix];
      float rr = rsqrtf(ms * (1.f / 128.f) + EPS_RMS);
#pragma unroll
      for (int cc = 0; cc < 2; ++cc) {
        int co = (2 * w + cc) * 16 + (l & 15);
        kpb[((size_t)(b * 196) + p0 + pix) * 128 + co] =
            accP[mt][cc][r] * rr + k_proj_b[co];
      }
    }
}

// ---------- 3x3 conv on GN(q_pool), MFMA ----------

__global__ __launch_bounds__(256) void k_conv3m(
    const float* __restrict__ q_pool, const float* __restrict__ murs2,
    const _Float16* __restrict__ W3B, float* __restrict__ qconv,
    float* __restrict__ msq) {
  __shared__ __align__(16) _Float16 w3L[16384];
  __shared__ float sMu[8], sRs[8];
  int t = threadIdx.x, l = t & 63, w = t >> 6;
  int b = blockIdx.x / 98, reg = blockIdx.x % 98;
  int y0 = (reg / 7) * 8, x0 = (reg % 7) * 16;
  if (t < 8) { sMu[t] = murs2[(b * 8 + t) * 2]; sRs[t] = murs2[(b * 8 + t) * 2 + 1]; }
  f32x4 z = {0.f, 0.f, 0.f, 0.f};
  f32x4 acc[2][8];
#pragma unroll
  for (int rx = 0; rx < 2; ++rx)
#pragma unroll
    for (int ct = 0; ct < 8; ++ct) acc[rx][ct] = z;
  int lm = l & 15;
  int mrow = lm >> 3, mcol = lm & 7;
  for (int tap = 0; tap < 9; ++tap) {
    int dy = tap / 3 - 1, dx = tap % 3 - 1;
    __syncthreads();
    for (int i = t; i < 4096; i += 256)
      ((h16x4*)w3L)[i] = ((const h16x4*)W3B)[tap * 4096 + i];
    __syncthreads();
    int py = y0 + 2 * w + mrow + dy;
    int pxb = x0 + mcol + dx;
    bool oky = (py >= 0) && (py < 112);
#pragma unroll
    for (int kt = 0; kt < 8; ++kt) {
      float mu = sMu[kt], rs = sRs[kt];
      h16x4 a[2];
#pragma unroll
      for (int rx = 0; rx < 2; ++rx) {
        int px = pxb + rx * 8;
        bool ok = oky && (px >= 0) && (px < 112);
        h16x4 ah = {(_Float16)0.f, (_Float16)0.f, (_Float16)0.f, (_Float16)0.f};
        if (ok) {
          f32x4 v = *(const f32x4*)(q_pool + ((size_t)(b * NQ) + py * 112 + px) * 128 +
                                    kt * 16 + 4 * (l >> 4));
#pragma unroll
          for (int j = 0; j < 4; ++j) ah[j] = (_Float16)((v[j] - mu) * rs);
        }
        a[rx] = ah;
      }
#pragma unroll
      for (int ct = 0; ct < 8; ++ct) {
        h16x4 bf = ((const h16x4*)w3L)[(kt * 8 + ct) * 64 + l];
        acc[0][ct] = mfma16(a[0], bf, acc[0][ct]);
        acc[1][ct] = mfma16(a[1], bf, acc[1][ct]);
      }
    }
  }
#pragma unroll
  for (int rx = 0; rx < 2; ++rx) {
    float sq[4] = {0.f, 0.f, 0.f, 0.f};
#pragma unroll
    for (int ct = 0; ct < 8; ++ct)
#pragma unroll
      for (int r = 0; r < 4; ++r) sq[r] += acc[rx][ct][r] * acc[rx][ct][r];
#pragma unroll
    for (int r = 0; r < 4; ++r) {
      for (int m = 1; m < 16; m <<= 1) sq[r] += __shfl_xor(sq[r], m);
      int mm = 4 * (l >> 4) + r;
      int py = y0 + 2 * w + (mm >> 3), px = x0 + rx * 8 + (mm & 7);
      size_t pb = (size_t)(b * NQ) + py * 112 + px;
      if ((l & 15) == 0) msq[pb] = sq[r];
#pragma unroll
      for (int ct = 0; ct < 8; ++ct)
        qconv[pb * 128 + ct * 16 + (l & 15)] = acc[rx][ct][r];
    }
  }
}

// ---------- RMSNorm + proj (q side, MFMA) ----------

__global__ __launch_bounds__(256) void k_rmsq(
    const float* __restrict__ qconv, const _Float16* __restrict__ QPB,
    const float* __restrict__ msq, const float* __restrict__ bias,
    float* __restrict__ qp) {
  __shared__ __align__(16) _Float16 wL[16384];
  int t = threadIdx.x, l = t & 63, w = t >> 6;
  int b = blockIdx.x / 196, tile = blockIdx.x % 196;
  for (int i = t; i < 4096; i += 256)
    ((h16x4*)wL)[i] = ((const h16x4*)QPB)[i];
  __syncthreads();
  int p0 = tile * 64 + w * 16;
  f32x4 z = {0.f, 0.f, 0.f, 0.f};
  f32x4 acc[8];
#pragma unroll
  for (int ct = 0; ct < 8; ++ct) acc[ct] = z;
#pragma unroll
  for (int kt = 0; kt < 8; ++kt) {
    f32x4 av = *(const f32x4*)(qconv + ((size_t)(b * NQ) + p0 + (l & 15)) * 128 +
                               kt * 16 + 4 * (l >> 4));
    h16x4 ah;
#pragma unroll
    for (int j = 0; j < 4; ++j) ah[j] = (_Float16)av[j];
#pragma unroll
    for (int ct = 0; ct < 8; ++ct)
      acc[ct] = mfma16(ah, ((const h16x4*)wL)[(kt * 8 + ct) * 64 + l], acc[ct]);
  }
#pragma unroll
  for (int r = 0; r < 4; ++r) {
    int pix = p0 + 4 * (l >> 4) + r;
    float rr = rsqrtf(msq[(size_t)(b * NQ) + pix] * (1.f / 128.f) + EPS_RMS);
#pragma unroll
    for (int ct = 0; ct < 8; ++ct)
      qp[((size_t)(b * NQ) + pix) * 128 + ct * 16 + (l & 15)] =
          acc[ct][r] * rr + bias[ct * 16 + (l & 15)];
  }
}

// ---------- attention: QK^T + softmax + head-mean -> packed fp16 P ----------

__global__ __launch_bounds__(256) void k_attn1m(
    const float* __restrict__ qp, const float* __restrict__ kpb,
    _Float16* __restrict__ Ph) {
  __shared__ float sP[4][16][212];
  int t = threadIdx.x, l = t & 63, h = t >> 6;
  int b = blockIdx.x / 784, qt = blockIdx.x % 784;
  int q0 = qt * 16;
  constexpr float SC = 0.17677669529663687f;  // 1/sqrt(32)
  h16x4 aq[2];
#pragma unroll
  for (int kt = 0; kt < 2; ++kt) {
    f32x4 v = *(const f32x4*)(qp + ((size_t)(b * NQ) + q0 + (l & 15)) * 128 +
                              h * 32 + kt * 16 + 4 * (l >> 4));
    h16x4 ah;
#pragma unroll
    for (int j = 0; j < 4; ++j) ah[j] = (_Float16)v[j];
    aq[kt] = ah;
  }
  f32x4 z = {0.f, 0.f, 0.f, 0.f};
  f32x4 acc[13];
#pragma unroll
  for (int nt = 0; nt < 13; ++nt) acc[nt] = z;
#pragma unroll
  for (int nt = 0; nt < 13; ++nt) {
    int key = nt * 16 + (l & 15);
    bool ok = key < 196;
#pragma unroll
    for (int kt = 0; kt < 2; ++kt) {
      h16x4 bf = {(_Float16)0.f, (_Float16)0.f, (_Float16)0.f, (_Float16)0.f};
      if (ok) {
        f32x4 v = *(const f32x4*)(kpb + ((size_t)(b * 196) + key) * 128 +
                                  h * 32 + kt * 16 + 4 * (l >> 4));
#pragma unroll
        for (int j = 0; j < 4; ++j) bf[j] = (_Float16)v[j];
      }
      acc[nt] = mfma16(aq[kt], bf, acc[nt]);
    }
  }
#pragma unroll
  for (int r = 0; r < 4; ++r) {
    float mx = -3e38f;
#pragma unroll
    for (int nt = 0; nt < 13; ++nt) {
      bool ok = nt * 16 + (l & 15) < 196;
      float v = ok ? acc[nt][r] * SC : -3e38f;
      acc[nt][r] = v;
      mx = fmaxf(mx, v);
    }
    for (int m = 1; m < 16; m <<= 1) mx = fmaxf(mx, __shfl_xor(mx, m));
    float sum = 0.f;
#pragma unroll
    for (int nt = 0; nt < 13; ++nt) {
      bool ok = nt * 16 + (l & 15) < 196;
      float e = ok ? __expf(acc[nt][r] - mx) : 0.f;
      acc[nt][r] = e;
      sum += e;
    }
    for (int m = 1; m < 16; m <<= 1) sum += __shfl_xor(sum, m);
    float inv = 1.f / sum;
#pragma unroll
    for (int nt = 0; nt < 13; ++nt)
      sP[h][4 * (l >> 4) + r][nt * 16 + (l & 15)] = acc[nt][r] * inv;
  }
  __syncthreads();
  _Float16* pb = Ph + (size_t)(b * 784 + qt) * 13 * 256;
  for (int i = t; i < 832; i += 256) {
    int kt = i >> 6, ll = i & 63;
    int q = ll & 15, kb = kt * 16 + 4 * (ll >> 4);
    h16x4 v;
#pragma unroll
    for (int j = 0; j < 4; ++j) {
      int k = kb + j;
      float s = 0.25f * (sP[0][q][k] + sP[1][q][k] + sP[2][q][k] + sP[3][q][k]);
      v[j] = (_Float16)s;
    }
    *(h16x4*)(pb + (size_t)i * 4) = v;
  }
}

// ---------- attention PV: pure fragment streaming, no LDS ----------

__global__ __launch_bounds__(256) void k_attn2m(
    const _Float16* __restrict__ Ph, const _Float16* __restrict__ featB,
    float* __restrict__ out) {
  int t = threadIdx.x, l = t & 63, w = t >> 6;
  int b = blockIdx.x / 196, qt = blockIdx.x % 196;
  int q16 = qt * 4 + w;
  f32x4 z = {0.f, 0.f, 0.f, 0.f};
  f32x4 acc[24];
#pragma unroll
  for (int dt = 0; dt < 24; ++dt) acc[dt] = z;
  const h16x4* PB = (const h16x4*)Ph + ((size_t)(b * 784 + q16) * 13) * 64 + l;
  const h16x4* FB = (const h16x4*)featB + (size_t)b * 13 * 24 * 64 + l;
  for (int kt = 0; kt < 13; ++kt) {
    h16x4 bp = PB[kt * 64];
    const h16x4* fb = FB + kt * 24 * 64;
#pragma unroll
    for (int dt = 0; dt < 24; ++dt)
      acc[dt] = mfma16(fb[(size_t)dt * 64], bp, acc[dt]);
  }
  int qg = q16 * 16 + (l & 15);
#pragma unroll
  for (int dt = 0; dt < 24; ++dt)
#pragma unroll
    for (int r = 0; r < 4; ++r) {
      int d = dt * 16 + 4 * (l >> 4) + r;
      out[((size_t)(b * 384) + d) * NQ + qg] = acc[dt][r];
    }
}

}  // namespace

extern "C" void kernel_launch(void* const* d_in, const int* in_sizes, int n_in,
                              void* d_out, int out_size, void* d_ws,
                              size_t ws_size, hipStream_t stream) {
  (void)in_sizes; (void)n_in; (void)out_size; (void)ws_size;
  const float* image        = (const float*)d_in[0];
  const float* features     = (const float*)d_in[1];
  const float* rope_f       = (const float*)d_in[2];
  const float* img_conv_w   = (const float*)d_in[3];
  const float* img_proj_w   = (const float*)d_in[4];
  const float* qenc_w       = (const float*)d_in[5];
  const float* kenc_w       = (const float*)d_in[6];
  const float* kfeat_conv_w = (const float*)d_in[7];
  const float* kfeat_proj_w = (const float*)d_in[8];
  const float* sft_gamma_w  = (const float*)d_in[9];
  const float* sft_beta_w   = (const float*)d_in[10];
  const float* block_conv_w = (const float*)d_in[11];
  const float* rms_q_w      = (const float*)d_in[12];
  const float* rms_k_w      = (const float*)d_in[13];
  const float* q_proj_w     = (const float*)d_in[14];
  const float* q_proj_b     = (const float*)d_in[15];
  const float* k_proj_w     = (const float*)d_in[16];
  const float* k_proj_b     = (const float*)d_in[17];
  float* out = (float*)d_out;
  float* ws = (float*)d_ws;

  size_t off = 0;
  auto alloc = [&](size_t n) {
    size_t r = off;
    off += (n + 63) & ~(size_t)63;
    return r;
  };
  _Float16* WqB  = (_Float16*)(ws + alloc(8192));
  _Float16* WkB  = (_Float16*)(ws + alloc(8192));
  _Float16* QPB  = (_Float16*)(ws + alloc(8192));
  _Float16* W3B  = (_Float16*)(ws + alloc(73728));
  _Float16* KFB  = (_Float16*)(ws + alloc(24576));   // 49152 fp16
  _Float16* KFPB = (_Float16*)(ws + alloc(24576));
  _Float16* GB   = (_Float16*)(ws + alloc(8192));
  _Float16* BBf  = (_Float16*)(ws + alloc(8192));
  _Float16* KPB  = (_Float16*)(ws + alloc(8192));
  float* cosT     = ws + alloc(14336);
  float* sinT     = ws + alloc(14336);
  _Float16* featB = (_Float16*)(ws + alloc(159744));  // 319488 fp16
  float* imgpart  = ws + alloc(2304);
  float* img_murs = ws + alloc(64);
  float* qk_murs  = ws + alloc(128);
  float* murs2    = ws + alloc(64);
  float* kgn_murs = ws + alloc(64);
  float* kf_murs  = ws + alloc(64);
  float* G        = ws + alloc(65536);
  float* mvec     = ws + alloc(512);
  float* mpart    = ws + alloc(392 * 128);
  float* Qpart    = ws + alloc((size_t)BB * 784 * 16);
  float* kpp      = ws + alloc((size_t)BB * 784 * 128);
  float* y_kf     = ws + alloc(100352);
  float* skip_kf  = ws + alloc(100352);
  float* k_pool   = ws + alloc(100352);
  float* kpb      = ws + alloc(100352);
  float* msq      = ws + alloc(50176);
  // RA (25.7MB): Gpart -> q_pool -> qp
  float* RA = ws + alloc((size_t)BB * NQ * 128);
  // ENC (51.4MB): encF -> (qconv, Ph)
  float* ENCp = ws + alloc((size_t)BB * 784 * 8192 / 2);
  float* Gpart  = RA;
  float* q_pool = RA;
  float* qp     = RA;
  _Float16* encF = (_Float16*)ENCp;
  float* qconv   = ENCp;
  _Float16* Ph   = (_Float16*)(ENCp + (size_t)BB * NQ * 128);

  // fused weight/table/feature prep
  k_prep<<<2648, 256, 0, stream>>>(qenc_w, kenc_w, q_proj_w, rms_q_w,
                                   block_conv_w, kfeat_conv_w, kfeat_proj_w,
                                   sft_gamma_w, sft_beta_w, k_proj_w, rms_k_w,
                                   rope_f, features,
                                   WqB, WkB, QPB, W3B, KFB, KFPB, GB, BBf, KPB,
                                   cosT, sinT, featB);

  // image GN stats (Gram trick over 3 channels)
  k_imgstat1<<<BB * 64, 256, 0, stream>>>(image, imgpart);
  k_imgstat2<<<BB, 128, 0, stream>>>(imgpart, img_conv_w, img_murs);

  // kf branch: fused L2-norm + conv (MFMA) + GN stats
  k_kf<<<BB * 4, 256, 0, stream>>>(features, KFB, KFPB, y_kf, skip_kf);
  k_gnstats<<<32, 256, 0, stream>>>(y_kf, kf_murs, NKk, EPS_GN);

  // enc producer: materialize encF + Gram partials
  k_gram<<<BB * 98, 256, 0, stream>>>(image, cosT, sinT, img_conv_w,
                                      img_proj_w, img_murs, encF, Gpart, mpart);
  k_gred<<<BB * 64, 256, 0, stream>>>(Gpart, mpart, G, mvec);
  k_gstats<<<64, 256, 0, stream>>>(G, mvec, qenc_w, kenc_w, qk_murs);

  // q/k enc_blocks + pooling from encF
  k_passA2<<<BB * 784, 256, 0, stream>>>(encF, qk_murs, WqB, WkB,
                                         q_pool, kpp, Qpart);
  k_qstatfin<<<32, 256, 0, stream>>>(Qpart, murs2);
  k_kpred<<<392, 256, 0, stream>>>(kpp, k_pool);
  k_gnstats<<<32, 256, 0, stream>>>(k_pool, kgn_murs, NKk, EPS_GN);

  // merged SFT + RMS + k-proj (MFMA)
  k_ksft<<<BB * 4, 256, 0, stream>>>(y_kf, skip_kf, kf_murs, kgn_murs,
                                     GB, BBf, KPB, k_pool, k_proj_b, kpb);

  // q side (MFMA)
  k_conv3m<<<BB * 98, 256, 0, stream>>>(q_pool, murs2, W3B, qconv, msq);
  k_rmsq<<<BB * 196, 256, 0, stream>>>(qconv, QPB, msq, q_proj_b, qp);

  // attention
  k_attn1m<<<BB * 784, 256, 0, stream>>>(qp, kpb, Ph);
  k_attn2m<<<BB * 196, 256, 0, stream>>>(Ph, featB, out);
}

// Round 8
// 465.831 us; speedup vs baseline: 4.3616x; 1.0075x over previous
//
#include <hip/hip_runtime.h>
#include <cstdint>
#include <cstddef>

#define DEV __device__ __forceinline__

namespace {

constexpr int BB   = 4;
constexpr int HWP  = 50176;   // 224*224
constexpr int NQ   = 12544;   // 112*112
constexpr int NKk  = 196;     // 14*14
constexpr int VD   = 384;
constexpr float EPS_GN  = 1e-5f;
constexpr float EPS_RMS = 1.1920929e-7f;

typedef __attribute__((ext_vector_type(4))) float f32x4;
typedef __attribute__((ext_vector_type(4))) _Float16 h16x4;

DEV float silu_f(float z) { return z / (1.f + __expf(-z)); }
DEV int rfl(int v) { return __builtin_amdgcn_readfirstlane(v); }

DEV f32x4 mfma16(h16x4 a, h16x4 b, f32x4 c) {
  return __builtin_amdgcn_mfma_f32_16x16x16f16(a, b, c, 0, 0, 0);
}

// ---------- fused weight prep (one launch) ----------
DEV void pack16_one(int id, const float* W, const float* rowscale,
                    _Float16* dst) {
  int j = id & 3, l = (id >> 2) & 63, tile = id >> 8;
  int ct = tile & 7, kt = tile >> 3;
  int ci = kt * 16 + 4 * (l >> 4) + j;
  int co = ct * 16 + (l & 15);
  float v = W[(size_t)co * 128 + ci];
  if (rowscale) v *= rowscale[ci];
  dst[id] = (_Float16)v;
}
// pack 128x384 weight into frag order, K=384 (24 kt)
DEV void pack384_one(int id, const float* W, _Float16* dst) {
  int j = id & 3, l = (id >> 2) & 63, rest = id >> 8;
  int ct = rest & 7, kt = rest >> 3;          // kt 0..23
  int ci = kt * 16 + 4 * (l >> 4) + j;
  int co = ct * 16 + (l & 15);
  dst[id] = (_Float16)W[(size_t)co * 384 + ci];
}

__global__ __launch_bounds__(256) void k_prep(
    const float* __restrict__ qenc_w, const float* __restrict__ kenc_w,
    const float* __restrict__ q_proj_w, const float* __restrict__ rms_q_w,
    const float* __restrict__ block_conv_w,
    const float* __restrict__ kfeat_conv_w, const float* __restrict__ kfeat_proj_w,
    const float* __restrict__ sft_gamma_w, const float* __restrict__ sft_beta_w,
    const float* __restrict__ k_proj_w, const float* __restrict__ rms_k_w,
    const float* __restrict__ ropef, const float* __restrict__ feat,
    _Float16* __restrict__ WqB, _Float16* __restrict__ WkB,
    _Float16* __restrict__ QPB, _Float16* __restrict__ W3B,
    _Float16* __restrict__ KFB, _Float16* __restrict__ KFPB,
    _Float16* __restrict__ GB, _Float16* __restrict__ BBf,
    _Float16* __restrict__ KPB,
    float* __restrict__ cosT, float* __restrict__ sinT,
    _Float16* __restrict__ featB) {
  int idx = blockIdx.x * 256 + threadIdx.x;
  if (idx < 16384) {
    pack16_one(idx, qenc_w, nullptr, WqB);
  } else if (idx < 32768) {
    pack16_one(idx - 16384, kenc_w, nullptr, WkB);
  } else if (idx < 49152) {
    pack16_one(idx - 32768, q_proj_w, rms_q_w, QPB);
  } else if (idx < 196608) {
    int id = idx - 49152;
    int j = id & 3, l = (id >> 2) & 63, tile = (id >> 8) & 63, tap = id >> 14;
    int ct = tile & 7, kt = tile >> 3;
    int ci = kt * 16 + 4 * (l >> 4) + j;
    int co = ct * 16 + (l & 15);
    W3B[id] = (_Float16)block_conv_w[((size_t)co * 128 + ci) * 9 + tap];
  } else if (idx < 245760) {
    pack384_one(idx - 196608, kfeat_conv_w, KFB);
  } else if (idx < 294912) {
    pack384_one(idx - 245760, kfeat_proj_w, KFPB);
  } else if (idx < 311296) {
    pack16_one(idx - 294912, sft_gamma_w, nullptr, GB);
  } else if (idx < 327680) {
    pack16_one(idx - 311296, sft_beta_w, nullptr, BBf);
  } else if (idx < 344064) {
    pack16_one(idx - 327680, k_proj_w, rms_k_w, KPB);
  } else if (idx < 358400) {
    int id = idx - 344064;            // pos*64 + d
    int pos = id >> 6, d = id & 63;
    float a = (pos + 0.5f) * (1.f / 224.f) * ropef[d];
    float s, c;
    __sincosf(a, &s, &c);
    cosT[id] = c;
    sinT[id] = s;
  } else if (idx < 677888) {
    int id = idx - 358400;            // (((b*13+kt)*24+dt)*64+l)*4+j
    int j = id & 3, l = (id >> 2) & 63;
    int rest = id >> 8;
    int dt = rest % 24;
    int kt = (rest / 24) % 13;
    int b = rest / (24 * 13);
    int key = kt * 16 + 4 * (l >> 4) + j;
    int d = dt * 16 + (l & 15);
    float v = (key < 196) ? feat[((size_t)(b * 384) + d) * 196 + key] : 0.f;
    featB[id] = (_Float16)v;
  }
}

// ---------- image GN stats via 3x3 Gram ----------

__global__ __launch_bounds__(256) void k_imgstat1(
    const float* __restrict__ img, float* __restrict__ part) {
  __shared__ float lds[4][9];
  int b = blockIdx.x >> 6, blk = blockIdx.x & 63;
  int t = threadIdx.x;
  float a[9];
#pragma unroll
  for (int j = 0; j < 9; ++j) a[j] = 0.f;
  const float* ib = img + (size_t)b * 3 * HWP;
  for (int pix = blk * 784 + t; pix < blk * 784 + 784; pix += 256) {
    float x0 = ib[pix], x1 = ib[HWP + pix], x2 = ib[2 * HWP + pix];
    a[0] += x0; a[1] += x1; a[2] += x2;
    a[3] += x0 * x0; a[4] += x0 * x1; a[5] += x0 * x2;
    a[6] += x1 * x1; a[7] += x1 * x2; a[8] += x2 * x2;
  }
#pragma unroll
  for (int j = 0; j < 9; ++j)
    for (int m = 1; m < 64; m <<= 1) a[j] += __shfl_xor(a[j], m);
  if ((t & 63) == 0)
    for (int j = 0; j < 9; ++j) lds[t >> 6][j] = a[j];
  __syncthreads();
  if (t < 9)
    part[(size_t)blockIdx.x * 9 + t] =
        lds[0][t] + lds[1][t] + lds[2][t] + lds[3][t];
}

__global__ __launch_bounds__(128) void k_imgstat2(
    const float* __restrict__ part, const float* __restrict__ wimg,
    float* __restrict__ img_murs) {
  __shared__ float MG[9];
  int b = blockIdx.x, t = threadIdx.x;
  if (t < 9) {
    float s = 0.f;
    for (int i = 0; i < 64; ++i) s += part[(size_t)(b * 64 + i) * 9 + t];
    MG[t] = s;
  }
  __syncthreads();
  int c = t;
  float w0 = wimg[c * 3], w1 = wimg[c * 3 + 1], w2 = wimg[c * 3 + 2];
  float s1 = w0 * MG[0] + w1 * MG[1] + w2 * MG[2];
  float s2 = w0 * w0 * MG[3] + w1 * w1 * MG[6] + w2 * w2 * MG[8] +
             2.f * (w0 * w1 * MG[4] + w0 * w2 * MG[5] + w1 * w2 * MG[7]);
  for (int m = 1; m < 16; m <<= 1) {
    s1 += __shfl_xor(s1, m);
    s2 += __shfl_xor(s2, m);
  }
  if ((c & 15) == 0) {
    int g = c >> 4;
    float invN = 1.f / (16.f * HWP);
    float mu = s1 * invN;
    float var = s2 * invN - mu * mu;
    img_murs[b * 16 + g] = mu;
    img_murs[b * 16 + 8 + g] = rsqrtf(var + EPS_GN);
  }
}

// ---------- enc producer + Gram + enc_frag materialization ----------

__global__ __launch_bounds__(256) void k_gram(
    const float* __restrict__ img, const float* __restrict__ cosT,
    const float* __restrict__ sinT,
    const float* __restrict__ wimg, const float* __restrict__ wimgp,
    const float* __restrict__ img_murs,
    _Float16* __restrict__ encF,
    float* __restrict__ Gpart, float* __restrict__ mpart) {
  __shared__ __align__(16) _Float16 fragP[2080 * 4];   // [kt*4+mt][lane(65 pad)][j]
  __shared__ __align__(16) _Float16 fragC[8192];       // [pk][ct][lane][j]
  __shared__ float sWc[384], sWp[384], sMu[8], sRs[8];
  int t = threadIdx.x, l = t & 63, w = t >> 6;
  int b = blockIdx.x / 98, blk = blockIdx.x % 98;
  for (int i = t; i < 384; i += 256) { sWc[i] = wimg[i]; sWp[i] = wimgp[i]; }
  if (t < 8) { sMu[t] = img_murs[b * 16 + t]; sRs[t] = img_murs[b * 16 + 8 + t]; }
  f32x4 acc[2][8];
  f32x4 macc[2];
  f32x4 z = {0.f, 0.f, 0.f, 0.f};
#pragma unroll
  for (int e = 0; e < 2; ++e) {
    macc[e] = z;
#pragma unroll
    for (int nt = 0; nt < 8; ++nt) acc[e][nt] = z;
  }
  h16x4 hone = {(_Float16)1.f, (_Float16)1.f, (_Float16)1.f, (_Float16)1.f};
  int mt = l >> 4;
  int laneCbase = 16 * ((l & 15) >> 2);
  int jC = (l & 15) & 3;
  for (int s = 0; s < 8; ++s) {
    int sub = blk * 8 + s;
    int tile = sub >> 2, st = sub & 3;
    int py = (tile / 14) * 16 + ((st >> 1) << 3) + (l >> 3);
    int px = (tile % 14) * 16 + ((st & 1) << 3) + (l & 7);
    __syncthreads();
    {
      const float* ip = img + (size_t)b * 3 * HWP + py * 224 + px;
      float x0 = ip[0], x1 = ip[HWP], x2 = ip[2 * HWP];
      const float* cy = cosT + py * 64 + w * 16;
      const float* sy = sinT + py * 64 + w * 16;
      const float* cx = cosT + px * 64 + w * 16;
      const float* sx = sinT + px * 64 + w * 16;
#pragma unroll
      for (int jj = 0; jj < 4; ++jj) {
        f32x4 cyv = *(const f32x4*)(cy + jj * 4);
        f32x4 syv = *(const f32x4*)(sy + jj * 4);
        f32x4 cxv = *(const f32x4*)(cx + jj * 4);
        f32x4 sxv = *(const f32x4*)(sx + jj * 4);
        h16x4 lo4, hi4;
#pragma unroll
        for (int u = 0; u < 4; ++u) {
          int d = w * 16 + jj * 4 + u;
          int c2 = d + 64;
          float y1 = sWc[d * 3] * x0 + sWc[d * 3 + 1] * x1 + sWc[d * 3 + 2] * x2;
          float s1 = sWp[d * 3] * x0 + sWp[d * 3 + 1] * x1 + sWp[d * 3 + 2] * x2;
          float y2 = sWc[c2 * 3] * x0 + sWc[c2 * 3 + 1] * x1 + sWc[c2 * 3 + 2] * x2;
          float s2 = sWp[c2 * 3] * x0 + sWp[c2 * 3 + 1] * x1 + sWp[c2 * 3 + 2] * x2;
          int g1 = d >> 4, g2 = g1 + 4;
          float t1 = silu_f((y1 - sMu[g1]) * sRs[g1]) + s1;
          float t2 = silu_f((y2 - sMu[g2]) * sRs[g2]) + s2;
          lo4[u] = (_Float16)(t1 * cyv[u] - t2 * syv[u]);
          hi4[u] = (_Float16)(t2 * cxv[u] + t1 * sxv[u]);
        }
        int lane = (l & 15) + 16 * jj;
        *(h16x4*)&fragP[((w * 4 + mt) * 65 + lane) * 4]       = lo4;
        *(h16x4*)&fragP[(((w + 4) * 4 + mt) * 65 + lane) * 4] = hi4;
#pragma unroll
        for (int u = 0; u < 4; ++u) {
          int laneC = jj * 4 + u + laneCbase;
          fragC[((mt * 8 + w) * 64 + laneC) * 4 + jC]     = lo4[u];
          fragC[((mt * 8 + w + 4) * 64 + laneC) * 4 + jC] = hi4[u];
        }
      }
    }
    __syncthreads();
    _Float16* ef = encF + ((size_t)(b * 784) + sub) * 8192;
    for (int i = t; i < 2048; i += 256) {
      int kt = i >> 8, m2 = (i >> 6) & 3, ln = i & 63;
      *(h16x4*)(ef + (size_t)i * 4) =
          *(const h16x4*)&fragP[((kt * 4 + m2) * 65 + ln) * 4];
    }
#pragma unroll
    for (int pk = 0; pk < 4; ++pk) {
      h16x4 a0 = *(const h16x4*)&fragC[((pk * 8 + 2 * w) * 64 + l) * 4];
      h16x4 a1 = *(const h16x4*)&fragC[((pk * 8 + 2 * w + 1) * 64 + l) * 4];
      macc[0] = mfma16(a0, hone, macc[0]);
      macc[1] = mfma16(a1, hone, macc[1]);
#pragma unroll
      for (int nt = 0; nt < 8; ++nt) {
        h16x4 bv = *(const h16x4*)&fragC[((pk * 8 + nt) * 64 + l) * 4];
        acc[0][nt] = mfma16(a0, bv, acc[0][nt]);
        acc[1][nt] = mfma16(a1, bv, acc[1][nt]);
      }
    }
  }
  float* gp = Gpart + (size_t)(b * 98 + blk) * 16384;
#pragma unroll
  for (int e = 0; e < 2; ++e)
#pragma unroll
    for (int nt = 0; nt < 8; ++nt)
#pragma unroll
      for (int r = 0; r < 4; ++r) {
        int row = (2 * w + e) * 16 + 4 * (l >> 4) + r;
        int col = nt * 16 + (l & 15);
        gp[row * 128 + col] = acc[e][nt][r];
      }
  if ((l & 15) == 0) {
    float* mp = mpart + (size_t)(b * 98 + blk) * 128;
#pragma unroll
    for (int e = 0; e < 2; ++e)
#pragma unroll
      for (int r = 0; r < 4; ++r)
        mp[(2 * w + e) * 16 + 4 * (l >> 4) + r] = macc[e][r];
  }
}

__global__ void k_gred(const float* __restrict__ Gpart,
                       const float* __restrict__ mpart,
                       float* __restrict__ G, float* __restrict__ mvec) {
  int b = blockIdx.x >> 6, chunk = blockIdx.x & 63;
  int idx = chunk * 256 + threadIdx.x;
  float s = 0.f;
  for (int i = 0; i < 98; ++i) s += Gpart[(size_t)(b * 98 + i) * 16384 + idx];
  G[(size_t)b * 16384 + idx] = s;
  if (idx < 128) {
    float sm = 0.f;
    for (int i = 0; i < 98; ++i) sm += mpart[(size_t)(b * 98 + i) * 128 + idx];
    mvec[b * 128 + idx] = sm;
  }
}

__global__ __launch_bounds__(256) void k_gstats(
    const float* __restrict__ G, const float* __restrict__ mvec,
    const float* __restrict__ qw, const float* __restrict__ kw,
    float* __restrict__ qk_murs) {
  __shared__ float red1[4], red2[4];
  int bi = blockIdx.x;               // conv*32 + b*8 + g
  int conv = bi >> 5, b = (bi >> 3) & 3, g = bi & 7;
  const float* W = conv ? kw : qw;
  int t = threadIdx.x;
  int c = g * 16 + (t >> 4);
  int i0 = (t & 15) * 8;
  const float* wc = W + (size_t)c * 128;
  const float* Gb = G + (size_t)b * 16384;
  const float* mb = mvec + b * 128;
  float s1 = 0.f, s2 = 0.f;
  for (int i = i0; i < i0 + 8; ++i) {
    float gi = 0.f;
    for (int j = 0; j < 128; ++j) gi += Gb[i * 128 + j] * wc[j];
    s2 += wc[i] * gi;
    s1 += wc[i] * mb[i];
  }
  for (int m = 1; m < 64; m <<= 1) { s1 += __shfl_xor(s1, m); s2 += __shfl_xor(s2, m); }
  if ((t & 63) == 0) { red1[t >> 6] = s1; red2[t >> 6] = s2; }
  __syncthreads();
  if (t == 0) {
    float S1 = red1[0] + red1[1] + red1[2] + red1[3];
    float S2 = red2[0] + red2[1] + red2[2] + red2[3];
    float invN = 1.f / 802816.f;
    float mu = S1 * invN;
    float var = S2 * invN - mu * mu;
    qk_murs[bi * 2] = mu;
    qk_murs[bi * 2 + 1] = rsqrtf(var + EPS_GN);
  }
}

// ---------- pass A: q/k enc_blocks from encF, swapped operands ----------
// D[co][pixel] = mfma(A=W-frag, B=enc-frag): skip values live in the
// thread's own enc B-frags (kt == ct) -> zero extra loads for skip.
__global__ __launch_bounds__(256) void k_passA2(
    const _Float16* __restrict__ encF, const float* __restrict__ qk_murs,
    const _Float16* __restrict__ WqB, const _Float16* __restrict__ WkB,
    float* __restrict__ q_pool, float* __restrict__ kpp,
    float* __restrict__ Qpart) {
  int t = threadIdx.x, l = t & 63;
  int wu = rfl(t >> 6);
  int bi = blockIdx.x;
  int b = bi / 784, sub = bi % 784;
  int tile = sub >> 2, st = sub & 3;
  int by = (tile / 14) * 16, bx = (tile % 14) * 16;
  float qmu[2], qrs[2], kmu[2], krs[2];
#pragma unroll
  for (int cc = 0; cc < 2; ++cc) {
    int g = 2 * wu + cc;
    qmu[cc] = qk_murs[(b * 8 + g) * 2];
    qrs[cc] = qk_murs[(b * 8 + g) * 2 + 1];
    kmu[cc] = qk_murs[(32 + b * 8 + g) * 2];
    krs[cc] = qk_murs[(32 + b * 8 + g) * 2 + 1];
  }
  const h16x4* EF = (const h16x4*)encF + ((size_t)(b * 784) + sub) * 2048;
  f32x4 z = {0.f, 0.f, 0.f, 0.f};
  f32x4 accQ[4][2], accK[4][2];
  h16x4 sf[2][4];                    // enc frags for kt == 2wu, 2wu+1 (skip)
#pragma unroll
  for (int mt = 0; mt < 4; ++mt)
#pragma unroll
    for (int cc = 0; cc < 2; ++cc) { accQ[mt][cc] = z; accK[mt][cc] = z; }
  for (int kt = 0; kt < 8; ++kt) {
    h16x4 a[4];
#pragma unroll
    for (int mt = 0; mt < 4; ++mt) a[mt] = EF[(kt * 4 + mt) * 64 + l];
    if ((kt >> 1) == wu) {
#pragma unroll
      for (int mt = 0; mt < 4; ++mt) sf[kt & 1][mt] = a[mt];
    }
    int fi = (kt * 8 + 2 * wu) * 64 + l;
    h16x4 bq0 = *(const h16x4*)(WqB + (size_t)fi * 4);
    h16x4 bq1 = *(const h16x4*)(WqB + (size_t)(fi + 64) * 4);
    h16x4 bk0 = *(const h16x4*)(WkB + (size_t)fi * 4);
    h16x4 bk1 = *(const h16x4*)(WkB + (size_t)(fi + 64) * 4);
#pragma unroll
    for (int mt = 0; mt < 4; ++mt) {
      accQ[mt][0] = mfma16(bq0, a[mt], accQ[mt][0]);
      accQ[mt][1] = mfma16(bq1, a[mt], accQ[mt][1]);
      accK[mt][0] = mfma16(bk0, a[mt], accK[mt][0]);
      accK[mt][1] = mfma16(bk1, a[mt], accK[mt][1]);
    }
  }
  // epilogue: thread owns pixel p = mt*16 + (l&15), channels
  // co = (2wu+cc)*16 + 4*(l>>4) + r;  skip = sf[cc][mt][r].
  int q = l & 15;
  bool act = (q & 9) == 0;           // 2x2-quad leader
  float kacc[2][4];
  float qs1[2] = {0.f, 0.f}, qs2[2] = {0.f, 0.f};
#pragma unroll
  for (int cc = 0; cc < 2; ++cc)
#pragma unroll
    for (int r = 0; r < 4; ++r) kacc[cc][r] = 0.f;
#pragma unroll
  for (int cc = 0; cc < 2; ++cc) {
    int g = 2 * wu + cc;
#pragma unroll
    for (int mt = 0; mt < 4; ++mt) {
      f32x4 pv;
#pragma unroll
      for (int r = 0; r < 4; ++r) {
        float skip = (float)sf[cc][mt][r];
        pv[r] = silu_f((accQ[mt][cc][r] - qmu[cc]) * qrs[cc]) + skip;
        kacc[cc][r] += silu_f((accK[mt][cc][r] - kmu[cc]) * krs[cc]) + skip;
      }
#pragma unroll
      for (int r = 0; r < 4; ++r) {
        float v = pv[r] + __shfl_xor(pv[r], 1);
        v += __shfl_xor(v, 8);
        pv[r] = v * 0.25f;
      }
      if (act) {
        int p = mt * 16 + q;
        int py = by + (st >> 1) * 8 + (p >> 3);
        int px = bx + (st & 1) * 8 + (p & 7);
        size_t base = ((size_t)(b * NQ) + (py >> 1) * 112 + (px >> 1)) * 128 +
                      g * 16 + 4 * (l >> 4);
        *(f32x4*)(q_pool + base) = pv;
        qs1[cc] += pv[0] + pv[1] + pv[2] + pv[3];
        qs2[cc] += pv[0] * pv[0] + pv[1] * pv[1] + pv[2] * pv[2] + pv[3] * pv[3];
      }
    }
  }
  // k-pool: reduce over the 16 pixels in each lane group, write per channel
#pragma unroll
  for (int cc = 0; cc < 2; ++cc) {
#pragma unroll
    for (int r = 0; r < 4; ++r) {
      float v = kacc[cc][r];
      v += __shfl_xor(v, 1);
      v += __shfl_xor(v, 2);
      v += __shfl_xor(v, 4);
      v += __shfl_xor(v, 8);
      kacc[cc][r] = v;
    }
    if (q == 0) {
      f32x4 kv = {kacc[cc][0], kacc[cc][1], kacc[cc][2], kacc[cc][3]};
      *(f32x4*)(kpp + (size_t)bi * 128 + (2 * wu + cc) * 16 + 4 * (l >> 4)) = kv;
    }
  }
#pragma unroll
  for (int cc = 0; cc < 2; ++cc) {
    float a1 = qs1[cc], a2 = qs2[cc];
    for (int m = 1; m < 64; m <<= 1) {
      a1 += __shfl_xor(a1, m);
      a2 += __shfl_xor(a2, m);
    }
    if (l == 0) {
      Qpart[(size_t)bi * 16 + (2 * wu + cc) * 2] = a1;
      Qpart[(size_t)bi * 16 + (2 * wu + cc) * 2 + 1] = a2;
    }
  }
}

__global__ __launch_bounds__(256) void k_kpred(
    const float* __restrict__ kpp, float* __restrict__ k_pool) {
  int idx = blockIdx.x * 256 + threadIdx.x;
  if (idx >= BB * 128 * NKk) return;
  int b = idx / (128 * NKk);
  int rem = idx % (128 * NKk);
  int c = rem / NKk, tile = rem % NKk;
  const float* base = kpp + ((size_t)(b * 196 + tile) * 4) * 128 + c;
  float s = base[0] + base[128] + base[256] + base[384];
  k_pool[idx] = s * (1.f / 256.f);
}

__global__ __launch_bounds__(256) void k_qstatfin(
    const float* __restrict__ Qpart, float* __restrict__ murs2) {
  __shared__ float l1[4], l2[4];
  int b = blockIdx.x >> 3, g = blockIdx.x & 7, t = threadIdx.x;
  float s1 = 0.f, s2 = 0.f;
  for (int i = t; i < 784; i += 256) {
    s1 += Qpart[((size_t)(b * 784) + i) * 16 + g * 2];
    s2 += Qpart[((size_t)(b * 784) + i) * 16 + g * 2 + 1];
  }
  for (int m = 1; m < 64; m <<= 1) { s1 += __shfl_xor(s1, m); s2 += __shfl_xor(s2, m); }
  if ((t & 63) == 0) { l1[t >> 6] = s1; l2[t >> 6] = s2; }
  __syncthreads();
  if (t == 0) {
    float a = l1[0] + l1[1] + l1[2] + l1[3];
    float bq = l2[0] + l2[1] + l2[2] + l2[3];
    float invN = 1.f / (16.f * (float)NQ);
    float mu = a * invN;
    float var = bq * invN - mu * mu;
    murs2[blockIdx.x * 2] = mu;
    murs2[blockIdx.x * 2 + 1] = rsqrtf(var + EPS_GN);
  }
}

// ---------- GN stats (channel-major src[b][c][P]) ----------

__global__ __launch_bounds__(256) void k_gnstats(
    const float* __restrict__ src, float* __restrict__ murs, int P, float eps) {
  __shared__ float l1[4], l2[4];
  int b = blockIdx.x >> 3, g = blockIdx.x & 7, t = threadIdx.x;
  const float* base = src + ((size_t)(b * 128) + g * 16) * P;
  float s1 = 0.f, s2 = 0.f;
  for (int i = t; i < 16 * P; i += 256) {
    float v = base[i];
    s1 += v; s2 += v * v;
  }
  for (int m = 1; m < 64; m <<= 1) { s1 += __shfl_xor(s1, m); s2 += __shfl_xor(s2, m); }
  if ((t & 63) == 0) { l1[t >> 6] = s1; l2[t >> 6] = s2; }
  __syncthreads();
  if (t == 0) {
    float invN = 1.f / (16.f * (float)P);
    float a = l1[0] + l1[1] + l1[2] + l1[3];
    float bq = l2[0] + l2[1] + l2[2] + l2[3];
    float mu = a * invN;
    float var = bq * invN - mu * mu;
    murs[blockIdx.x * 2] = mu;
    murs[blockIdx.x * 2 + 1] = rsqrtf(var + eps);
  }
}

// ---------- kf branch: fused L2-norm + 384->128 conv+proj (MFMA) ----------

__global__ __launch_bounds__(256) void k_kf(
    const float* __restrict__ feat,
    const _Float16* __restrict__ KFB, const _Float16* __restrict__ KFPB,
    float* __restrict__ y_kf, float* __restrict__ skip_kf) {
  __shared__ __align__(16) _Float16 fnF[24 * 4 * 64 * 4];  // 48KB, A-frags
  __shared__ float ssqL[4][64];
  __shared__ float rsqL[64];
  int t = threadIdx.x, l = t & 63, w = t >> 6;
  int b = blockIdx.x >> 2, tile = blockIdx.x & 3;
  int p0 = tile * 49;
  const float* fb = feat + (size_t)b * VD * NKk;
  {
    float s = 0.f;
    if (l < 49) {
#pragma unroll 4
      for (int k = w; k < VD; k += 4) {
        float v = fb[(size_t)k * NKk + p0 + l];
        s += v * v;
      }
    }
    ssqL[w][l] = s;
  }
  __syncthreads();
  if (t < 64) {
    float s = ssqL[0][t] + ssqL[1][t] + ssqL[2][t] + ssqL[3][t];
    rsqL[t] = rsqrtf(fmaxf(s, 1e-24f));
  }
  __syncthreads();
  for (int i = t; i < VD * 64; i += 256) {
    int k = i >> 6, p = i & 63;
    float v = 0.f;
    if (p < 49) v = fb[(size_t)k * NKk + p0 + p] * rsqL[p];
    int kt = k >> 4, kr = k & 15, u = kr >> 2, j = kr & 3, mt = p >> 4;
    fnF[(((kt * 4 + mt) * 64) + (p & 15) + 16 * u) * 4 + j] = (_Float16)v;
  }
  __syncthreads();
  f32x4 z = {0.f, 0.f, 0.f, 0.f};
  f32x4 accY[4][2], accS[4][2];
#pragma unroll
  for (int mt = 0; mt < 4; ++mt)
#pragma unroll
    for (int cc = 0; cc < 2; ++cc) { accY[mt][cc] = z; accS[mt][cc] = z; }
  for (int kt = 0; kt < 24; ++kt) {
    h16x4 a[4];
#pragma unroll
    for (int mt = 0; mt < 4; ++mt)
      a[mt] = *(const h16x4*)&fnF[((kt * 4 + mt) * 64 + l) * 4];
    int fi = (kt * 8 + 2 * w) * 64 + l;
    h16x4 by0 = *(const h16x4*)(KFB + (size_t)fi * 4);
    h16x4 by1 = *(const h16x4*)(KFB + (size_t)(fi + 64) * 4);
    h16x4 bs0 = *(const h16x4*)(KFPB + (size_t)fi * 4);
    h16x4 bs1 = *(const h16x4*)(KFPB + (size_t)(fi + 64) * 4);
#pragma unroll
    for (int mt = 0; mt < 4; ++mt) {
      accY[mt][0] = mfma16(a[mt], by0, accY[mt][0]);
      accY[mt][1] = mfma16(a[mt], by1, accY[mt][1]);
      accS[mt][0] = mfma16(a[mt], bs0, accS[mt][0]);
      accS[mt][1] = mfma16(a[mt], bs1, accS[mt][1]);
    }
  }
#pragma unroll
  for (int cc = 0; cc < 2; ++cc) {
    int co = (2 * w + cc) * 16 + (l & 15);
#pragma unroll
    for (int mt = 0; mt < 4; ++mt)
#pragma unroll
      for (int r = 0; r < 4; ++r) {
        int pix = mt * 16 + 4 * (l >> 4) + r;
        if (pix < 49) {
          size_t off = ((size_t)(b * 128) + co) * NKk + p0 + pix;
          y_kf[off] = accY[mt][cc][r];
          skip_kf[off] = accS[mt][cc][r];
        }
      }
  }
}

// ---------- merged SFT + RMSNorm + k-proj (MFMA) ----------

__global__ __launch_bounds__(256) void k_ksft(
    const float* __restrict__ y_kf, const float* __restrict__ skip_kf,
    const float* __restrict__ kf_murs, const float* __restrict__ kgn_murs,
    const _Float16* __restrict__ GB, const _Float16* __restrict__ BBf,
    const _Float16* __restrict__ KPB,
    const float* __restrict__ k_pool, const float* __restrict__ k_proj_b,
    float* __restrict__ kpb) {
  __shared__ __align__(16) _Float16 kfF[8 * 4 * 64 * 4];  // 16KB A-frags
  __shared__ float msL[4][64];
  __shared__ float sMu[8], sRs[8], sGmu[8], sGrs[8];
  int t = threadIdx.x, l = t & 63, w = t >> 6;
  int b = blockIdx.x >> 2, tile = blockIdx.x & 3;
  int p0 = tile * 49;
  if (t < 8) {
    sMu[t] = kf_murs[(b * 8 + t) * 2];
    sRs[t] = kf_murs[(b * 8 + t) * 2 + 1];
    sGmu[t] = kgn_murs[(b * 8 + t) * 2];
    sGrs[t] = kgn_murs[(b * 8 + t) * 2 + 1];
  }
  __syncthreads();
  for (int i = t; i < 128 * 64; i += 256) {
    int c = i >> 6, p = i & 63;
    float v = 0.f;
    if (p < 49) {
      size_t off = ((size_t)(b * 128) + c) * NKk + p0 + p;
      int g = c >> 4;
      v = silu_f((y_kf[off] - sMu[g]) * sRs[g]) + skip_kf[off];
    }
    int kt = c >> 4, kr = c & 15, u = kr >> 2, j = kr & 3, mt = p >> 4;
    kfF[(((kt * 4 + mt) * 64) + (p & 15) + 16 * u) * 4 + j] = (_Float16)v;
  }
  __syncthreads();
  f32x4 z = {0.f, 0.f, 0.f, 0.f};
  f32x4 accG[4][2], accB[4][2];
#pragma unroll
  for (int mt = 0; mt < 4; ++mt)
#pragma unroll
    for (int cc = 0; cc < 2; ++cc) { accG[mt][cc] = z; accB[mt][cc] = z; }
  for (int kt = 0; kt < 8; ++kt) {
    h16x4 a[4];
#pragma unroll
    for (int mt = 0; mt < 4; ++mt)
      a[mt] = *(const h16x4*)&kfF[((kt * 4 + mt) * 64 + l) * 4];
    int fi = (kt * 8 + 2 * w) * 64 + l;
    h16x4 bg0 = *(const h16x4*)(GB + (size_t)fi * 4);
    h16x4 bg1 = *(const h16x4*)(GB + (size_t)(fi + 64) * 4);
    h16x4 bb0 = *(const h16x4*)(BBf + (size_t)fi * 4);
    h16x4 bb1 = *(const h16x4*)(BBf + (size_t)(fi + 64) * 4);
#pragma unroll
    for (int mt = 0; mt < 4; ++mt) {
      accG[mt][0] = mfma16(a[mt], bg0, accG[mt][0]);
      accG[mt][1] = mfma16(a[mt], bg1, accG[mt][1]);
      accB[mt][0] = mfma16(a[mt], bb0, accB[mt][0]);
      accB[mt][1] = mfma16(a[mt], bb1, accB[mt][1]);
    }
  }
  float kfin[4][2][4];
#pragma unroll
  for (int cc = 0; cc < 2; ++cc) {
    int g = 2 * w + cc;
    int co = g * 16 + (l & 15);
    float gmu = sGmu[g], grs = sGrs[g];
#pragma unroll
    for (int mt = 0; mt < 4; ++mt)
#pragma unroll
      for (int r = 0; r < 4; ++r) {
        int pix = mt * 16 + 4 * (l >> 4) + r;
        float v = 0.f;
        if (pix < 49) {
          float kn = (k_pool[((size_t)(b * 128) + co) * NKk + p0 + pix] - gmu) * grs;
          v = fmaf(accG[mt][cc][r], kn, accB[mt][cc][r]);
        }
        kfin[mt][cc][r] = v;
      }
  }
#pragma unroll
  for (int mt = 0; mt < 4; ++mt)
#pragma unroll
    for (int r = 0; r < 4; ++r) {
      float s2 = kfin[mt][0][r] * kfin[mt][0][r] + kfin[mt][1][r] * kfin[mt][1][r];
      for (int m = 1; m < 16; m <<= 1) s2 += __shfl_xor(s2, m);
      if ((l & 15) == 0) msL[w][mt * 16 + 4 * (l >> 4) + r] = s2;
    }
  __syncthreads();
#pragma unroll
  for (int cc = 0; cc < 2; ++cc) {
    int ktn = 2 * w + cc;
    int u = (l & 15) >> 2, j = (l & 15) & 3;
#pragma unroll
    for (int mt = 0; mt < 4; ++mt)
#pragma unroll
      for (int r = 0; r < 4; ++r) {
        int lane = (4 * (l >> 4) + r) + 16 * u;
        kfF[((ktn * 4 + mt) * 64 + lane) * 4 + j] = (_Float16)kfin[mt][cc][r];
      }
  }
  __syncthreads();
  f32x4 accP[4][2];
#pragma unroll
  for (int mt = 0; mt < 4; ++mt)
#pragma unroll
    for (int cc = 0; cc < 2; ++cc) accP[mt][cc] = z;
  for (int kt = 0; kt < 8; ++kt) {
    h16x4 a[4];
#pragma unroll
    for (int mt = 0; mt < 4; ++mt)
      a[mt] = *(const h16x4*)&kfF[((kt * 4 + mt) * 64 + l) * 4];
    int fi = (kt * 8 + 2 * w) * 64 + l;
    h16x4 b0 = *(const h16x4*)(KPB + (size_t)fi * 4);
    h16x4 b1 = *(const h16x4*)(KPB + (size_t)(fi + 64) * 4);
#pragma unroll
    for (int mt = 0; mt < 4; ++mt) {
      accP[mt][0] = mfma16(a[mt], b0, accP[mt][0]);
      accP[mt][1] = mfma16(a[mt], b1, accP[mt][1]);
    }
  }
#pragma unroll
  for (int mt = 0; mt < 4; ++mt)
#pragma unroll
    for (int r = 0; r < 4; ++r) {
      int pix = mt * 16 + 4 * (l >> 4) + r;
      if (pix >= 49) continue;
      float ms = msL[0][pix] + msL[1][pix] + msL[2][pix] + msL[3][pix];
      float rr = rsqrtf(ms * (1.f / 128.f) + EPS_RMS);
#pragma unroll
      for (int cc = 0; cc < 2; ++cc) {
        int co = (2 * w + cc) * 16 + (l & 15);
        kpb[((size_t)(b * 196) + p0 + pix) * 128 + co] =
            accP[mt][cc][r] * rr + k_proj_b[co];
      }
    }
}

// ---------- 3x3 conv on GN(q_pool), MFMA ----------

__global__ __launch_bounds__(256) void k_conv3m(
    const float* __restrict__ q_pool, const float* __restrict__ murs2,
    const _Float16* __restrict__ W3B, float* __restrict__ qconv,
    float* __restrict__ msq) {
  __shared__ __align__(16) _Float16 w3L[16384];
  __shared__ float sMu[8], sRs[8];
  int t = threadIdx.x, l = t & 63, w = t >> 6;
  int b = blockIdx.x / 98, reg = blockIdx.x % 98;
  int y0 = (reg / 7) * 8, x0 = (reg % 7) * 16;
  if (t < 8) { sMu[t] = murs2[(b * 8 + t) * 2]; sRs[t] = murs2[(b * 8 + t) * 2 + 1]; }
  f32x4 z = {0.f, 0.f, 0.f, 0.f};
  f32x4 acc[2][8];
#pragma unroll
  for (int rx = 0; rx < 2; ++rx)
#pragma unroll
    for (int ct = 0; ct < 8; ++ct) acc[rx][ct] = z;
  int lm = l & 15;
  int mrow = lm >> 3, mcol = lm & 7;
  for (int tap = 0; tap < 9; ++tap) {
    int dy = tap / 3 - 1, dx = tap % 3 - 1;
    __syncthreads();
    for (int i = t; i < 4096; i += 256)
      ((h16x4*)w3L)[i] = ((const h16x4*)W3B)[tap * 4096 + i];
    __syncthreads();
    int py = y0 + 2 * w + mrow + dy;
    int pxb = x0 + mcol + dx;
    bool oky = (py >= 0) && (py < 112);
#pragma unroll
    for (int kt = 0; kt < 8; ++kt) {
      float mu = sMu[kt], rs = sRs[kt];
      h16x4 a[2];
#pragma unroll
      for (int rx = 0; rx < 2; ++rx) {
        int px = pxb + rx * 8;
        bool ok = oky && (px >= 0) && (px < 112);
        h16x4 ah = {(_Float16)0.f, (_Float16)0.f, (_Float16)0.f, (_Float16)0.f};
        if (ok) {
          f32x4 v = *(const f32x4*)(q_pool + ((size_t)(b * NQ) + py * 112 + px) * 128 +
                                    kt * 16 + 4 * (l >> 4));
#pragma unroll
          for (int j = 0; j < 4; ++j) ah[j] = (_Float16)((v[j] - mu) * rs);
        }
        a[rx] = ah;
      }
#pragma unroll
      for (int ct = 0; ct < 8; ++ct) {
        h16x4 bf = ((const h16x4*)w3L)[(kt * 8 + ct) * 64 + l];
        acc[0][ct] = mfma16(a[0], bf, acc[0][ct]);
        acc[1][ct] = mfma16(a[1], bf, acc[1][ct]);
      }
    }
  }
#pragma unroll
  for (int rx = 0; rx < 2; ++rx) {
    float sq[4] = {0.f, 0.f, 0.f, 0.f};
#pragma unroll
    for (int ct = 0; ct < 8; ++ct)
#pragma unroll
      for (int r = 0; r < 4; ++r) sq[r] += acc[rx][ct][r] * acc[rx][ct][r];
#pragma unroll
    for (int r = 0; r < 4; ++r) {
      for (int m = 1; m < 16; m <<= 1) sq[r] += __shfl_xor(sq[r], m);
      int mm = 4 * (l >> 4) + r;
      int py = y0 + 2 * w + (mm >> 3), px = x0 + rx * 8 + (mm & 7);
      size_t pb = (size_t)(b * NQ) + py * 112 + px;
      if ((l & 15) == 0) msq[pb] = sq[r];
#pragma unroll
      for (int ct = 0; ct < 8; ++ct)
        qconv[pb * 128 + ct * 16 + (l & 15)] = acc[rx][ct][r];
    }
  }
}

// ---------- RMSNorm + proj (q side, MFMA) ----------

__global__ __launch_bounds__(256) void k_rmsq(
    const float* __restrict__ qconv, const _Float16* __restrict__ QPB,
    const float* __restrict__ msq, const float* __restrict__ bias,
    float* __restrict__ qp) {
  __shared__ __align__(16) _Float16 wL[16384];
  int t = threadIdx.x, l = t & 63, w = t >> 6;
  int b = blockIdx.x / 196, tile = blockIdx.x % 196;
  for (int i = t; i < 4096; i += 256)
    ((h16x4*)wL)[i] = ((const h16x4*)QPB)[i];
  __syncthreads();
  int p0 = tile * 64 + w * 16;
  f32x4 z = {0.f, 0.f, 0.f, 0.f};
  f32x4 acc[8];
#pragma unroll
  for (int ct = 0; ct < 8; ++ct) acc[ct] = z;
#pragma unroll
  for (int kt = 0; kt < 8; ++kt) {
    f32x4 av = *(const f32x4*)(qconv + ((size_t)(b * NQ) + p0 + (l & 15)) * 128 +
                               kt * 16 + 4 * (l >> 4));
    h16x4 ah;
#pragma unroll
    for (int j = 0; j < 4; ++j) ah[j] = (_Float16)av[j];
#pragma unroll
    for (int ct = 0; ct < 8; ++ct)
      acc[ct] = mfma16(ah, ((const h16x4*)wL)[(kt * 8 + ct) * 64 + l], acc[ct]);
  }
#pragma unroll
  for (int r = 0; r < 4; ++r) {
    int pix = p0 + 4 * (l >> 4) + r;
    float rr = rsqrtf(msq[(size_t)(b * NQ) + pix] * (1.f / 128.f) + EPS_RMS);
#pragma unroll
    for (int ct = 0; ct < 8; ++ct)
      qp[((size_t)(b * NQ) + pix) * 128 + ct * 16 + (l & 15)] =
          acc[ct][r] * rr + bias[ct * 16 + (l & 15)];
  }
}

// ---------- attention: QK^T + softmax + head-mean -> packed fp16 P ----------

__global__ __launch_bounds__(256) void k_attn1m(
    const float* __restrict__ qp, const float* __restrict__ kpb,
    _Float16* __restrict__ Ph) {
  __shared__ float sP[4][16][212];
  int t = threadIdx.x, l = t & 63, h = t >> 6;
  int b = blockIdx.x / 784, qt = blockIdx.x % 784;
  int q0 = qt * 16;
  constexpr float SC = 0.17677669529663687f;  // 1/sqrt(32)
  h16x4 aq[2];
#pragma unroll
  for (int kt = 0; kt < 2; ++kt) {
    f32x4 v = *(const f32x4*)(qp + ((size_t)(b * NQ) + q0 + (l & 15)) * 128 +
                              h * 32 + kt * 16 + 4 * (l >> 4));
    h16x4 ah;
#pragma unroll
    for (int j = 0; j < 4; ++j) ah[j] = (_Float16)v[j];
    aq[kt] = ah;
  }
  f32x4 z = {0.f, 0.f, 0.f, 0.f};
  f32x4 acc[13];
#pragma unroll
  for (int nt = 0; nt < 13; ++nt) acc[nt] = z;
#pragma unroll
  for (int nt = 0; nt < 13; ++nt) {
    int key = nt * 16 + (l & 15);
    bool ok = key < 196;
#pragma unroll
    for (int kt = 0; kt < 2; ++kt) {
      h16x4 bf = {(_Float16)0.f, (_Float16)0.f, (_Float16)0.f, (_Float16)0.f};
      if (ok) {
        f32x4 v = *(const f32x4*)(kpb + ((size_t)(b * 196) + key) * 128 +
                                  h * 32 + kt * 16 + 4 * (l >> 4));
#pragma unroll
        for (int j = 0; j < 4; ++j) bf[j] = (_Float16)v[j];
      }
      acc[nt] = mfma16(aq[kt], bf, acc[nt]);
    }
  }
#pragma unroll
  for (int r = 0; r < 4; ++r) {
    float mx = -3e38f;
#pragma unroll
    for (int nt = 0; nt < 13; ++nt) {
      bool ok = nt * 16 + (l & 15) < 196;
      float v = ok ? acc[nt][r] * SC : -3e38f;
      acc[nt][r] = v;
      mx = fmaxf(mx, v);
    }
    for (int m = 1; m < 16; m <<= 1) mx = fmaxf(mx, __shfl_xor(mx, m));
    float sum = 0.f;
#pragma unroll
    for (int nt = 0; nt < 13; ++nt) {
      bool ok = nt * 16 + (l & 15) < 196;
      float e = ok ? __expf(acc[nt][r] - mx) : 0.f;
      acc[nt][r] = e;
      sum += e;
    }
    for (int m = 1; m < 16; m <<= 1) sum += __shfl_xor(sum, m);
    float inv = 1.f / sum;
#pragma unroll
    for (int nt = 0; nt < 13; ++nt)
      sP[h][4 * (l >> 4) + r][nt * 16 + (l & 15)] = acc[nt][r] * inv;
  }
  __syncthreads();
  _Float16* pb = Ph + (size_t)(b * 784 + qt) * 13 * 256;
  for (int i = t; i < 832; i += 256) {
    int kt = i >> 6, ll = i & 63;
    int q = ll & 15, kb = kt * 16 + 4 * (ll >> 4);
    h16x4 v;
#pragma unroll
    for (int j = 0; j < 4; ++j) {
      int k = kb + j;
      float s = 0.25f * (sP[0][q][k] + sP[1][q][k] + sP[2][q][k] + sP[3][q][k]);
      v[j] = (_Float16)s;
    }
    *(h16x4*)(pb + (size_t)i * 4) = v;
  }
}

// ---------- attention PV: pure fragment streaming, no LDS ----------

__global__ __launch_bounds__(256) void k_attn2m(
    const _Float16* __restrict__ Ph, const _Float16* __restrict__ featB,
    float* __restrict__ out) {
  int t = threadIdx.x, l = t & 63, w = t >> 6;
  int b = blockIdx.x / 196, qt = blockIdx.x % 196;
  int q16 = qt * 4 + w;
  f32x4 z = {0.f, 0.f, 0.f, 0.f};
  f32x4 acc[24];
#pragma unroll
  for (int dt = 0; dt < 24; ++dt) acc[dt] = z;
  const h16x4* PB = (const h16x4*)Ph + ((size_t)(b * 784 + q16) * 13) * 64 + l;
  const h16x4* FB = (const h16x4*)featB + (size_t)b * 13 * 24 * 64 + l;
  for (int kt = 0; kt < 13; ++kt) {
    h16x4 bp = PB[kt * 64];
    const h16x4* fb = FB + kt * 24 * 64;
#pragma unroll
    for (int dt = 0; dt < 24; ++dt)
      acc[dt] = mfma16(fb[(size_t)dt * 64], bp, acc[dt]);
  }
  int qg = q16 * 16 + (l & 15);
#pragma unroll
  for (int dt = 0; dt < 24; ++dt)
#pragma unroll
    for (int r = 0; r < 4; ++r) {
      int d = dt * 16 + 4 * (l >> 4) + r;
      out[((size_t)(b * 384) + d) * NQ + qg] = acc[dt][r];
    }
}

}  // namespace

extern "C" void kernel_launch(void* const* d_in, const int* in_sizes, int n_in,
                              void* d_out, int out_size, void* d_ws,
                              size_t ws_size, hipStream_t stream) {
  (void)in_sizes; (void)n_in; (void)out_size; (void)ws_size;
  const float* image        = (const float*)d_in[0];
  const float* features     = (const float*)d_in[1];
  const float* rope_f       = (const float*)d_in[2];
  const float* img_conv_w   = (const float*)d_in[3];
  const float* img_proj_w   = (const float*)d_in[4];
  const float* qenc_w       = (const float*)d_in[5];
  const float* kenc_w       = (const float*)d_in[6];
  const float* kfeat_conv_w = (const float*)d_in[7];
  const float* kfeat_proj_w = (const float*)d_in[8];
  const float* sft_gamma_w  = (const float*)d_in[9];
  const float* sft_beta_w   = (const float*)d_in[10];
  const float* block_conv_w = (const float*)d_in[11];
  const float* rms_q_w      = (const float*)d_in[12];
  const float* rms_k_w      = (const float*)d_in[13];
  const float* q_proj_w     = (const float*)d_in[14];
  const float* q_proj_b     = (const float*)d_in[15];
  const float* k_proj_w     = (const float*)d_in[16];
  const float* k_proj_b     = (const float*)d_in[17];
  float* out = (float*)d_out;
  float* ws = (float*)d_ws;

  size_t off = 0;
  auto alloc = [&](size_t n) {
    size_t r = off;
    off += (n + 63) & ~(size_t)63;
    return r;
  };
  _Float16* WqB  = (_Float16*)(ws + alloc(8192));
  _Float16* WkB  = (_Float16*)(ws + alloc(8192));
  _Float16* QPB  = (_Float16*)(ws + alloc(8192));
  _Float16* W3B  = (_Float16*)(ws + alloc(73728));
  _Float16* KFB  = (_Float16*)(ws + alloc(24576));
  _Float16* KFPB = (_Float16*)(ws + alloc(24576));
  _Float16* GB   = (_Float16*)(ws + alloc(8192));
  _Float16* BBf  = (_Float16*)(ws + alloc(8192));
  _Float16* KPB  = (_Float16*)(ws + alloc(8192));
  float* cosT     = ws + alloc(14336);
  float* sinT     = ws + alloc(14336);
  _Float16* featB = (_Float16*)(ws + alloc(159744));
  float* imgpart  = ws + alloc(2304);
  float* img_murs = ws + alloc(64);
  float* qk_murs  = ws + alloc(128);
  float* murs2    = ws + alloc(64);
  float* kgn_murs = ws + alloc(64);
  float* kf_murs  = ws + alloc(64);
  float* G        = ws + alloc(65536);
  float* mvec     = ws + alloc(512);
  float* mpart    = ws + alloc(392 * 128);
  float* Qpart    = ws + alloc((size_t)BB * 784 * 16);
  float* kpp      = ws + alloc((size_t)BB * 784 * 128);
  float* y_kf     = ws + alloc(100352);
  float* skip_kf  = ws + alloc(100352);
  float* k_pool   = ws + alloc(100352);
  float* kpb      = ws + alloc(100352);
  float* msq      = ws + alloc(50176);
  float* RA = ws + alloc((size_t)BB * NQ * 128);
  float* ENCp = ws + alloc((size_t)BB * 784 * 8192 / 2);
  float* Gpart  = RA;
  float* q_pool = RA;
  float* qp     = RA;
  _Float16* encF = (_Float16*)ENCp;
  float* qconv   = ENCp;
  _Float16* Ph   = (_Float16*)(ENCp + (size_t)BB * NQ * 128);

  k_prep<<<2648, 256, 0, stream>>>(qenc_w, kenc_w, q_proj_w, rms_q_w,
                                   block_conv_w, kfeat_conv_w, kfeat_proj_w,
                                   sft_gamma_w, sft_beta_w, k_proj_w, rms_k_w,
                                   rope_f, features,
                                   WqB, WkB, QPB, W3B, KFB, KFPB, GB, BBf, KPB,
                                   cosT, sinT, featB);

  k_imgstat1<<<BB * 64, 256, 0, stream>>>(image, imgpart);
  k_imgstat2<<<BB, 128, 0, stream>>>(imgpart, img_conv_w, img_murs);

  k_kf<<<BB * 4, 256, 0, stream>>>(features, KFB, KFPB, y_kf, skip_kf);
  k_gnstats<<<32, 256, 0, stream>>>(y_kf, kf_murs, NKk, EPS_GN);

  k_gram<<<BB * 98, 256, 0, stream>>>(image, cosT, sinT, img_conv_w,
                                      img_proj_w, img_murs, encF, Gpart, mpart);
  k_gred<<<BB * 64, 256, 0, stream>>>(Gpart, mpart, G, mvec);
  k_gstats<<<64, 256, 0, stream>>>(G, mvec, qenc_w, kenc_w, qk_murs);

  k_passA2<<<BB * 784, 256, 0, stream>>>(encF, qk_murs, WqB, WkB,
                                         q_pool, kpp, Qpart);
  k_qstatfin<<<32, 256, 0, stream>>>(Qpart, murs2);
  k_kpred<<<392, 256, 0, stream>>>(kpp, k_pool);
  k_gnstats<<<32, 256, 0, stream>>>(k_pool, kgn_murs, NKk, EPS_GN);

  k_ksft<<<BB * 4, 256, 0, stream>>>(y_kf, skip_kf, kf_murs, kgn_murs,
                                     GB, BBf, KPB, k_pool, k_proj_b, kpb);

  k_conv3m<<<BB * 98, 256, 0, stream>>>(q_pool, murs2, W3B, qconv, msq);
  k_rmsq<<<BB * 196, 256, 0, stream>>>(qconv, QPB, msq, q_proj_b, qp);

  k_attn1m<<<BB * 784, 256, 0, stream>>>(qp, kpb, Ph);
  k_attn2m<<<BB * 196, 256, 0, stream>>>(Ph, featB, out);
}

// Round 9
// 446.171 us; speedup vs baseline: 4.5538x; 1.0441x over previous
//
#include <hip/hip_runtime.h>
#include <cstdint>
#include <cstddef>

#define DEV __device__ __forceinline__

namespace {

constexpr int BB   = 4;
constexpr int HWP  = 50176;   // 224*224
constexpr int NQ   = 12544;   // 112*112
constexpr int NKk  = 196;     // 14*14
constexpr int VD   = 384;
constexpr float EPS_GN  = 1e-5f;
constexpr float EPS_RMS = 1.1920929e-7f;

typedef __attribute__((ext_vector_type(4))) float f32x4;
typedef __attribute__((ext_vector_type(4))) _Float16 h16x4;

DEV float silu_f(float z) { return z / (1.f + __expf(-z)); }
DEV int rfl(int v) { return __builtin_amdgcn_readfirstlane(v); }

DEV f32x4 mfma16(h16x4 a, h16x4 b, f32x4 c) {
  return __builtin_amdgcn_mfma_f32_16x16x16f16(a, b, c, 0, 0, 0);
}

// ---------- fused weight prep (one launch) ----------
DEV void pack16_one(int id, const float* W, const float* rowscale,
                    _Float16* dst) {
  int j = id & 3, l = (id >> 2) & 63, tile = id >> 8;
  int ct = tile & 7, kt = tile >> 3;
  int ci = kt * 16 + 4 * (l >> 4) + j;
  int co = ct * 16 + (l & 15);
  float v = W[(size_t)co * 128 + ci];
  if (rowscale) v *= rowscale[ci];
  dst[id] = (_Float16)v;
}
// pack 128x384 weight into frag order, K=384 (24 kt)
DEV void pack384_one(int id, const float* W, _Float16* dst) {
  int j = id & 3, l = (id >> 2) & 63, rest = id >> 8;
  int ct = rest & 7, kt = rest >> 3;          // kt 0..23
  int ci = kt * 16 + 4 * (l >> 4) + j;
  int co = ct * 16 + (l & 15);
  dst[id] = (_Float16)W[(size_t)co * 384 + ci];
}

__global__ __launch_bounds__(256) void k_prep(
    const float* __restrict__ qenc_w, const float* __restrict__ kenc_w,
    const float* __restrict__ q_proj_w, const float* __restrict__ rms_q_w,
    const float* __restrict__ block_conv_w,
    const float* __restrict__ kfeat_conv_w, const float* __restrict__ kfeat_proj_w,
    const float* __restrict__ sft_gamma_w, const float* __restrict__ sft_beta_w,
    const float* __restrict__ k_proj_w, const float* __restrict__ rms_k_w,
    const float* __restrict__ ropef, const float* __restrict__ feat,
    _Float16* __restrict__ WqB, _Float16* __restrict__ WkB,
    _Float16* __restrict__ QPB, _Float16* __restrict__ W3B,
    _Float16* __restrict__ KFB, _Float16* __restrict__ KFPB,
    _Float16* __restrict__ GB, _Float16* __restrict__ BBf,
    _Float16* __restrict__ KPB,
    float* __restrict__ cosT, float* __restrict__ sinT,
    _Float16* __restrict__ featB) {
  int idx = blockIdx.x * 256 + threadIdx.x;
  if (idx < 16384) {
    pack16_one(idx, qenc_w, nullptr, WqB);
  } else if (idx < 32768) {
    pack16_one(idx - 16384, kenc_w, nullptr, WkB);
  } else if (idx < 49152) {
    pack16_one(idx - 32768, q_proj_w, rms_q_w, QPB);
  } else if (idx < 196608) {
    int id = idx - 49152;
    int j = id & 3, l = (id >> 2) & 63, tile = (id >> 8) & 63, tap = id >> 14;
    int ct = tile & 7, kt = tile >> 3;
    int ci = kt * 16 + 4 * (l >> 4) + j;
    int co = ct * 16 + (l & 15);
    W3B[id] = (_Float16)block_conv_w[((size_t)co * 128 + ci) * 9 + tap];
  } else if (idx < 245760) {
    pack384_one(idx - 196608, kfeat_conv_w, KFB);
  } else if (idx < 294912) {
    pack384_one(idx - 245760, kfeat_proj_w, KFPB);
  } else if (idx < 311296) {
    pack16_one(idx - 294912, sft_gamma_w, nullptr, GB);
  } else if (idx < 327680) {
    pack16_one(idx - 311296, sft_beta_w, nullptr, BBf);
  } else if (idx < 344064) {
    pack16_one(idx - 327680, k_proj_w, rms_k_w, KPB);
  } else if (idx < 358400) {
    int id = idx - 344064;            // pos*64 + d
    int pos = id >> 6, d = id & 63;
    float a = (pos + 0.5f) * (1.f / 224.f) * ropef[d];
    float s, c;
    __sincosf(a, &s, &c);
    cosT[id] = c;
    sinT[id] = s;
  } else if (idx < 677888) {
    int id = idx - 358400;            // (((b*13+kt)*24+dt)*64+l)*4+j
    int j = id & 3, l = (id >> 2) & 63;
    int rest = id >> 8;
    int dt = rest % 24;
    int kt = (rest / 24) % 13;
    int b = rest / (24 * 13);
    int key = kt * 16 + 4 * (l >> 4) + j;
    int d = dt * 16 + (l & 15);
    float v = (key < 196) ? feat[((size_t)(b * 384) + d) * 196 + key] : 0.f;
    featB[id] = (_Float16)v;
  }
}

// ---------- image GN stats via 3x3 Gram ----------

__global__ __launch_bounds__(256) void k_imgstat1(
    const float* __restrict__ img, float* __restrict__ part) {
  __shared__ float lds[4][9];
  int b = blockIdx.x >> 6, blk = blockIdx.x & 63;
  int t = threadIdx.x;
  float a[9];
#pragma unroll
  for (int j = 0; j < 9; ++j) a[j] = 0.f;
  const float* ib = img + (size_t)b * 3 * HWP;
  for (int pix = blk * 784 + t; pix < blk * 784 + 784; pix += 256) {
    float x0 = ib[pix], x1 = ib[HWP + pix], x2 = ib[2 * HWP + pix];
    a[0] += x0; a[1] += x1; a[2] += x2;
    a[3] += x0 * x0; a[4] += x0 * x1; a[5] += x0 * x2;
    a[6] += x1 * x1; a[7] += x1 * x2; a[8] += x2 * x2;
  }
#pragma unroll
  for (int j = 0; j < 9; ++j)
    for (int m = 1; m < 64; m <<= 1) a[j] += __shfl_xor(a[j], m);
  if ((t & 63) == 0)
    for (int j = 0; j < 9; ++j) lds[t >> 6][j] = a[j];
  __syncthreads();
  if (t < 9)
    part[(size_t)blockIdx.x * 9 + t] =
        lds[0][t] + lds[1][t] + lds[2][t] + lds[3][t];
}

__global__ __launch_bounds__(128) void k_imgstat2(
    const float* __restrict__ part, const float* __restrict__ wimg,
    float* __restrict__ img_murs) {
  __shared__ float MG[9];
  int b = blockIdx.x, t = threadIdx.x;
  if (t < 9) {
    float s = 0.f;
    for (int i = 0; i < 64; ++i) s += part[(size_t)(b * 64 + i) * 9 + t];
    MG[t] = s;
  }
  __syncthreads();
  int c = t;
  float w0 = wimg[c * 3], w1 = wimg[c * 3 + 1], w2 = wimg[c * 3 + 2];
  float s1 = w0 * MG[0] + w1 * MG[1] + w2 * MG[2];
  float s2 = w0 * w0 * MG[3] + w1 * w1 * MG[6] + w2 * w2 * MG[8] +
             2.f * (w0 * w1 * MG[4] + w0 * w2 * MG[5] + w1 * w2 * MG[7]);
  for (int m = 1; m < 16; m <<= 1) {
    s1 += __shfl_xor(s1, m);
    s2 += __shfl_xor(s2, m);
  }
  if ((c & 15) == 0) {
    int g = c >> 4;
    float invN = 1.f / (16.f * HWP);
    float mu = s1 * invN;
    float var = s2 * invN - mu * mu;
    img_murs[b * 16 + g] = mu;
    img_murs[b * 16 + 8 + g] = rsqrtf(var + EPS_GN);
  }
}

// ---------- enc producer + Gram + enc_frag materialization ----------

__global__ __launch_bounds__(256) void k_gram(
    const float* __restrict__ img, const float* __restrict__ cosT,
    const float* __restrict__ sinT,
    const float* __restrict__ wimg, const float* __restrict__ wimgp,
    const float* __restrict__ img_murs,
    _Float16* __restrict__ encF,
    float* __restrict__ Gpart, float* __restrict__ mpart) {
  __shared__ __align__(16) _Float16 fragP[2080 * 4];   // [kt*4+mt][lane(65 pad)][j]
  __shared__ __align__(16) _Float16 fragC[8192];       // [pk][ct][lane][j]
  __shared__ float sWc[384], sWp[384], sMu[8], sRs[8];
  int t = threadIdx.x, l = t & 63, w = t >> 6;
  int b = blockIdx.x / 98, blk = blockIdx.x % 98;
  for (int i = t; i < 384; i += 256) { sWc[i] = wimg[i]; sWp[i] = wimgp[i]; }
  if (t < 8) { sMu[t] = img_murs[b * 16 + t]; sRs[t] = img_murs[b * 16 + 8 + t]; }
  f32x4 acc[2][8];
  f32x4 macc[2];
  f32x4 z = {0.f, 0.f, 0.f, 0.f};
#pragma unroll
  for (int e = 0; e < 2; ++e) {
    macc[e] = z;
#pragma unroll
    for (int nt = 0; nt < 8; ++nt) acc[e][nt] = z;
  }
  h16x4 hone = {(_Float16)1.f, (_Float16)1.f, (_Float16)1.f, (_Float16)1.f};
  int mt = l >> 4;
  int laneCbase = 16 * ((l & 15) >> 2);
  int jC = (l & 15) & 3;
  for (int s = 0; s < 8; ++s) {
    int sub = blk * 8 + s;
    int tile = sub >> 2, st = sub & 3;
    int py = (tile / 14) * 16 + ((st >> 1) << 3) + (l >> 3);
    int px = (tile % 14) * 16 + ((st & 1) << 3) + (l & 7);
    __syncthreads();
    {
      const float* ip = img + (size_t)b * 3 * HWP + py * 224 + px;
      float x0 = ip[0], x1 = ip[HWP], x2 = ip[2 * HWP];
      const float* cy = cosT + py * 64 + w * 16;
      const float* sy = sinT + py * 64 + w * 16;
      const float* cx = cosT + px * 64 + w * 16;
      const float* sx = sinT + px * 64 + w * 16;
#pragma unroll
      for (int jj = 0; jj < 4; ++jj) {
        f32x4 cyv = *(const f32x4*)(cy + jj * 4);
        f32x4 syv = *(const f32x4*)(sy + jj * 4);
        f32x4 cxv = *(const f32x4*)(cx + jj * 4);
        f32x4 sxv = *(const f32x4*)(sx + jj * 4);
        h16x4 lo4, hi4;
#pragma unroll
        for (int u = 0; u < 4; ++u) {
          int d = w * 16 + jj * 4 + u;
          int c2 = d + 64;
          float y1 = sWc[d * 3] * x0 + sWc[d * 3 + 1] * x1 + sWc[d * 3 + 2] * x2;
          float s1 = sWp[d * 3] * x0 + sWp[d * 3 + 1] * x1 + sWp[d * 3 + 2] * x2;
          float y2 = sWc[c2 * 3] * x0 + sWc[c2 * 3 + 1] * x1 + sWc[c2 * 3 + 2] * x2;
          float s2 = sWp[c2 * 3] * x0 + sWp[c2 * 3 + 1] * x1 + sWp[c2 * 3 + 2] * x2;
          int g1 = d >> 4, g2 = g1 + 4;
          float t1 = silu_f((y1 - sMu[g1]) * sRs[g1]) + s1;
          float t2 = silu_f((y2 - sMu[g2]) * sRs[g2]) + s2;
          lo4[u] = (_Float16)(t1 * cyv[u] - t2 * syv[u]);
          hi4[u] = (_Float16)(t2 * cxv[u] + t1 * sxv[u]);
        }
        int lane = (l & 15) + 16 * jj;
        *(h16x4*)&fragP[((w * 4 + mt) * 65 + lane) * 4]       = lo4;
        *(h16x4*)&fragP[(((w + 4) * 4 + mt) * 65 + lane) * 4] = hi4;
#pragma unroll
        for (int u = 0; u < 4; ++u) {
          int laneC = jj * 4 + u + laneCbase;
          fragC[((mt * 8 + w) * 64 + laneC) * 4 + jC]     = lo4[u];
          fragC[((mt * 8 + w + 4) * 64 + laneC) * 4 + jC] = hi4[u];
        }
      }
    }
    __syncthreads();
    _Float16* ef = encF + ((size_t)(b * 784) + sub) * 8192;
    for (int i = t; i < 2048; i += 256) {
      int kt = i >> 8, m2 = (i >> 6) & 3, ln = i & 63;
      *(h16x4*)(ef + (size_t)i * 4) =
          *(const h16x4*)&fragP[((kt * 4 + m2) * 65 + ln) * 4];
    }
#pragma unroll
    for (int pk = 0; pk < 4; ++pk) {
      h16x4 a0 = *(const h16x4*)&fragC[((pk * 8 + 2 * w) * 64 + l) * 4];
      h16x4 a1 = *(const h16x4*)&fragC[((pk * 8 + 2 * w + 1) * 64 + l) * 4];
      macc[0] = mfma16(a0, hone, macc[0]);
      macc[1] = mfma16(a1, hone, macc[1]);
#pragma unroll
      for (int nt = 0; nt < 8; ++nt) {
        h16x4 bv = *(const h16x4*)&fragC[((pk * 8 + nt) * 64 + l) * 4];
        acc[0][nt] = mfma16(a0, bv, acc[0][nt]);
        acc[1][nt] = mfma16(a1, bv, acc[1][nt]);
      }
    }
  }
  float* gp = Gpart + (size_t)(b * 98 + blk) * 16384;
#pragma unroll
  for (int e = 0; e < 2; ++e)
#pragma unroll
    for (int nt = 0; nt < 8; ++nt)
#pragma unroll
      for (int r = 0; r < 4; ++r) {
        int row = (2 * w + e) * 16 + 4 * (l >> 4) + r;
        int col = nt * 16 + (l & 15);
        gp[row * 128 + col] = acc[e][nt][r];
      }
  if ((l & 15) == 0) {
    float* mp = mpart + (size_t)(b * 98 + blk) * 128;
#pragma unroll
    for (int e = 0; e < 2; ++e)
#pragma unroll
      for (int r = 0; r < 4; ++r)
        mp[(2 * w + e) * 16 + 4 * (l >> 4) + r] = macc[e][r];
  }
}

__global__ void k_gred(const float* __restrict__ Gpart,
                       const float* __restrict__ mpart,
                       float* __restrict__ G, float* __restrict__ mvec) {
  int b = blockIdx.x >> 6, chunk = blockIdx.x & 63;
  int idx = chunk * 256 + threadIdx.x;
  float s = 0.f;
  for (int i = 0; i < 98; ++i) s += Gpart[(size_t)(b * 98 + i) * 16384 + idx];
  G[(size_t)b * 16384 + idx] = s;
  if (idx < 128) {
    float sm = 0.f;
    for (int i = 0; i < 98; ++i) sm += mpart[(size_t)(b * 98 + i) * 128 + idx];
    mvec[b * 128 + idx] = sm;
  }
}

__global__ __launch_bounds__(256) void k_gstats(
    const float* __restrict__ G, const float* __restrict__ mvec,
    const float* __restrict__ qw, const float* __restrict__ kw,
    float* __restrict__ qk_murs) {
  __shared__ float red1[4], red2[4];
  int bi = blockIdx.x;               // conv*32 + b*8 + g
  int conv = bi >> 5, b = (bi >> 3) & 3, g = bi & 7;
  const float* W = conv ? kw : qw;
  int t = threadIdx.x;
  int c = g * 16 + (t >> 4);
  int i0 = (t & 15) * 8;
  const float* wc = W + (size_t)c * 128;
  const float* Gb = G + (size_t)b * 16384;
  const float* mb = mvec + b * 128;
  float s1 = 0.f, s2 = 0.f;
  for (int i = i0; i < i0 + 8; ++i) {
    float gi = 0.f;
    for (int j = 0; j < 128; ++j) gi += Gb[i * 128 + j] * wc[j];
    s2 += wc[i] * gi;
    s1 += wc[i] * mb[i];
  }
  for (int m = 1; m < 64; m <<= 1) { s1 += __shfl_xor(s1, m); s2 += __shfl_xor(s2, m); }
  if ((t & 63) == 0) { red1[t >> 6] = s1; red2[t >> 6] = s2; }
  __syncthreads();
  if (t == 0) {
    float S1 = red1[0] + red1[1] + red1[2] + red1[3];
    float S2 = red2[0] + red2[1] + red2[2] + red2[3];
    float invN = 1.f / 802816.f;
    float mu = S1 * invN;
    float var = S2 * invN - mu * mu;
    qk_murs[bi * 2] = mu;
    qk_murs[bi * 2 + 1] = rsqrtf(var + EPS_GN);
  }
}

// ---------- pass A: q/k enc_blocks from encF, swapped operands ----------

__global__ __launch_bounds__(256) void k_passA2(
    const _Float16* __restrict__ encF, const float* __restrict__ qk_murs,
    const _Float16* __restrict__ WqB, const _Float16* __restrict__ WkB,
    float* __restrict__ q_pool, float* __restrict__ kpp,
    float* __restrict__ Qpart) {
  int t = threadIdx.x, l = t & 63;
  int wu = rfl(t >> 6);
  int bi = blockIdx.x;
  int b = bi / 784, sub = bi % 784;
  int tile = sub >> 2, st = sub & 3;
  int by = (tile / 14) * 16, bx = (tile % 14) * 16;
  float qmu[2], qrs[2], kmu[2], krs[2];
#pragma unroll
  for (int cc = 0; cc < 2; ++cc) {
    int g = 2 * wu + cc;
    qmu[cc] = qk_murs[(b * 8 + g) * 2];
    qrs[cc] = qk_murs[(b * 8 + g) * 2 + 1];
    kmu[cc] = qk_murs[(32 + b * 8 + g) * 2];
    krs[cc] = qk_murs[(32 + b * 8 + g) * 2 + 1];
  }
  const h16x4* EF = (const h16x4*)encF + ((size_t)(b * 784) + sub) * 2048;
  f32x4 z = {0.f, 0.f, 0.f, 0.f};
  f32x4 accQ[4][2], accK[4][2];
  h16x4 sf[2][4];
#pragma unroll
  for (int mt = 0; mt < 4; ++mt)
#pragma unroll
    for (int cc = 0; cc < 2; ++cc) { accQ[mt][cc] = z; accK[mt][cc] = z; }
  for (int kt = 0; kt < 8; ++kt) {
    h16x4 a[4];
#pragma unroll
    for (int mt = 0; mt < 4; ++mt) a[mt] = EF[(kt * 4 + mt) * 64 + l];
    if ((kt >> 1) == wu) {
#pragma unroll
      for (int mt = 0; mt < 4; ++mt) sf[kt & 1][mt] = a[mt];
    }
    int fi = (kt * 8 + 2 * wu) * 64 + l;
    h16x4 bq0 = *(const h16x4*)(WqB + (size_t)fi * 4);
    h16x4 bq1 = *(const h16x4*)(WqB + (size_t)(fi + 64) * 4);
    h16x4 bk0 = *(const h16x4*)(WkB + (size_t)fi * 4);
    h16x4 bk1 = *(const h16x4*)(WkB + (size_t)(fi + 64) * 4);
#pragma unroll
    for (int mt = 0; mt < 4; ++mt) {
      accQ[mt][0] = mfma16(bq0, a[mt], accQ[mt][0]);
      accQ[mt][1] = mfma16(bq1, a[mt], accQ[mt][1]);
      accK[mt][0] = mfma16(bk0, a[mt], accK[mt][0]);
      accK[mt][1] = mfma16(bk1, a[mt], accK[mt][1]);
    }
  }
  int q = l & 15;
  bool act = (q & 9) == 0;
  float kacc[2][4];
  float qs1[2] = {0.f, 0.f}, qs2[2] = {0.f, 0.f};
#pragma unroll
  for (int cc = 0; cc < 2; ++cc)
#pragma unroll
    for (int r = 0; r < 4; ++r) kacc[cc][r] = 0.f;
#pragma unroll
  for (int cc = 0; cc < 2; ++cc) {
    int g = 2 * wu + cc;
#pragma unroll
    for (int mt = 0; mt < 4; ++mt) {
      f32x4 pv;
#pragma unroll
      for (int r = 0; r < 4; ++r) {
        float skip = (float)sf[cc][mt][r];
        pv[r] = silu_f((accQ[mt][cc][r] - qmu[cc]) * qrs[cc]) + skip;
        kacc[cc][r] += silu_f((accK[mt][cc][r] - kmu[cc]) * krs[cc]) + skip;
      }
#pragma unroll
      for (int r = 0; r < 4; ++r) {
        float v = pv[r] + __shfl_xor(pv[r], 1);
        v += __shfl_xor(v, 8);
        pv[r] = v * 0.25f;
      }
      if (act) {
        int p = mt * 16 + q;
        int py = by + (st >> 1) * 8 + (p >> 3);
        int px = bx + (st & 1) * 8 + (p & 7);
        size_t base = ((size_t)(b * NQ) + (py >> 1) * 112 + (px >> 1)) * 128 +
                      g * 16 + 4 * (l >> 4);
        *(f32x4*)(q_pool + base) = pv;
        qs1[cc] += pv[0] + pv[1] + pv[2] + pv[3];
        qs2[cc] += pv[0] * pv[0] + pv[1] * pv[1] + pv[2] * pv[2] + pv[3] * pv[3];
      }
    }
  }
#pragma unroll
  for (int cc = 0; cc < 2; ++cc) {
#pragma unroll
    for (int r = 0; r < 4; ++r) {
      float v = kacc[cc][r];
      v += __shfl_xor(v, 1);
      v += __shfl_xor(v, 2);
      v += __shfl_xor(v, 4);
      v += __shfl_xor(v, 8);
      kacc[cc][r] = v;
    }
    if (q == 0) {
      f32x4 kv = {kacc[cc][0], kacc[cc][1], kacc[cc][2], kacc[cc][3]};
      *(f32x4*)(kpp + (size_t)bi * 128 + (2 * wu + cc) * 16 + 4 * (l >> 4)) = kv;
    }
  }
#pragma unroll
  for (int cc = 0; cc < 2; ++cc) {
    float a1 = qs1[cc], a2 = qs2[cc];
    for (int m = 1; m < 64; m <<= 1) {
      a1 += __shfl_xor(a1, m);
      a2 += __shfl_xor(a2, m);
    }
    if (l == 0) {
      Qpart[(size_t)bi * 16 + (2 * wu + cc) * 2] = a1;
      Qpart[(size_t)bi * 16 + (2 * wu + cc) * 2 + 1] = a2;
    }
  }
}

__global__ __launch_bounds__(256) void k_kpred(
    const float* __restrict__ kpp, float* __restrict__ k_pool) {
  int idx = blockIdx.x * 256 + threadIdx.x;
  if (idx >= BB * 128 * NKk) return;
  int b = idx / (128 * NKk);
  int rem = idx % (128 * NKk);
  int c = rem / NKk, tile = rem % NKk;
  const float* base = kpp + ((size_t)(b * 196 + tile) * 4) * 128 + c;
  float s = base[0] + base[128] + base[256] + base[384];
  k_pool[idx] = s * (1.f / 256.f);
}

__global__ __launch_bounds__(256) void k_qstatfin(
    const float* __restrict__ Qpart, float* __restrict__ murs2) {
  __shared__ float l1[4], l2[4];
  int b = blockIdx.x >> 3, g = blockIdx.x & 7, t = threadIdx.x;
  float s1 = 0.f, s2 = 0.f;
  for (int i = t; i < 784; i += 256) {
    s1 += Qpart[((size_t)(b * 784) + i) * 16 + g * 2];
    s2 += Qpart[((size_t)(b * 784) + i) * 16 + g * 2 + 1];
  }
  for (int m = 1; m < 64; m <<= 1) { s1 += __shfl_xor(s1, m); s2 += __shfl_xor(s2, m); }
  if ((t & 63) == 0) { l1[t >> 6] = s1; l2[t >> 6] = s2; }
  __syncthreads();
  if (t == 0) {
    float a = l1[0] + l1[1] + l1[2] + l1[3];
    float bq = l2[0] + l2[1] + l2[2] + l2[3];
    float invN = 1.f / (16.f * (float)NQ);
    float mu = a * invN;
    float var = bq * invN - mu * mu;
    murs2[blockIdx.x * 2] = mu;
    murs2[blockIdx.x * 2 + 1] = rsqrtf(var + EPS_GN);
  }
}

// ---------- GN stats (channel-major src[b][c][P]) ----------

__global__ __launch_bounds__(256) void k_gnstats(
    const float* __restrict__ src, float* __restrict__ murs, int P, float eps) {
  __shared__ float l1[4], l2[4];
  int b = blockIdx.x >> 3, g = blockIdx.x & 7, t = threadIdx.x;
  const float* base = src + ((size_t)(b * 128) + g * 16) * P;
  float s1 = 0.f, s2 = 0.f;
  for (int i = t; i < 16 * P; i += 256) {
    float v = base[i];
    s1 += v; s2 += v * v;
  }
  for (int m = 1; m < 64; m <<= 1) { s1 += __shfl_xor(s1, m); s2 += __shfl_xor(s2, m); }
  if ((t & 63) == 0) { l1[t >> 6] = s1; l2[t >> 6] = s2; }
  __syncthreads();
  if (t == 0) {
    float invN = 1.f / (16.f * (float)P);
    float a = l1[0] + l1[1] + l1[2] + l1[3];
    float bq = l2[0] + l2[1] + l2[2] + l2[3];
    float mu = a * invN;
    float var = bq * invN - mu * mu;
    murs[blockIdx.x * 2] = mu;
    murs[blockIdx.x * 2 + 1] = rsqrtf(var + eps);
  }
}

// ---------- kf branch: fused L2-norm + 384->128 conv+proj (MFMA) ----------

__global__ __launch_bounds__(256) void k_kf(
    const float* __restrict__ feat,
    const _Float16* __restrict__ KFB, const _Float16* __restrict__ KFPB,
    float* __restrict__ y_kf, float* __restrict__ skip_kf) {
  __shared__ __align__(16) _Float16 fnF[24 * 4 * 64 * 4];  // 48KB, A-frags
  __shared__ float ssqL[4][64];
  __shared__ float rsqL[64];
  int t = threadIdx.x, l = t & 63, w = t >> 6;
  int b = blockIdx.x >> 2, tile = blockIdx.x & 3;
  int p0 = tile * 49;
  const float* fb = feat + (size_t)b * VD * NKk;
  {
    float s = 0.f;
    if (l < 49) {
#pragma unroll 4
      for (int k = w; k < VD; k += 4) {
        float v = fb[(size_t)k * NKk + p0 + l];
        s += v * v;
      }
    }
    ssqL[w][l] = s;
  }
  __syncthreads();
  if (t < 64) {
    float s = ssqL[0][t] + ssqL[1][t] + ssqL[2][t] + ssqL[3][t];
    rsqL[t] = rsqrtf(fmaxf(s, 1e-24f));
  }
  __syncthreads();
  for (int i = t; i < VD * 64; i += 256) {
    int k = i >> 6, p = i & 63;
    float v = 0.f;
    if (p < 49) v = fb[(size_t)k * NKk + p0 + p] * rsqL[p];
    int kt = k >> 4, kr = k & 15, u = kr >> 2, j = kr & 3, mt = p >> 4;
    fnF[(((kt * 4 + mt) * 64) + (p & 15) + 16 * u) * 4 + j] = (_Float16)v;
  }
  __syncthreads();
  f32x4 z = {0.f, 0.f, 0.f, 0.f};
  f32x4 accY[4][2], accS[4][2];
#pragma unroll
  for (int mt = 0; mt < 4; ++mt)
#pragma unroll
    for (int cc = 0; cc < 2; ++cc) { accY[mt][cc] = z; accS[mt][cc] = z; }
  for (int kt = 0; kt < 24; ++kt) {
    h16x4 a[4];
#pragma unroll
    for (int mt = 0; mt < 4; ++mt)
      a[mt] = *(const h16x4*)&fnF[((kt * 4 + mt) * 64 + l) * 4];
    int fi = (kt * 8 + 2 * w) * 64 + l;
    h16x4 by0 = *(const h16x4*)(KFB + (size_t)fi * 4);
    h16x4 by1 = *(const h16x4*)(KFB + (size_t)(fi + 64) * 4);
    h16x4 bs0 = *(const h16x4*)(KFPB + (size_t)fi * 4);
    h16x4 bs1 = *(const h16x4*)(KFPB + (size_t)(fi + 64) * 4);
#pragma unroll
    for (int mt = 0; mt < 4; ++mt) {
      accY[mt][0] = mfma16(a[mt], by0, accY[mt][0]);
      accY[mt][1] = mfma16(a[mt], by1, accY[mt][1]);
      accS[mt][0] = mfma16(a[mt], bs0, accS[mt][0]);
      accS[mt][1] = mfma16(a[mt], bs1, accS[mt][1]);
    }
  }
#pragma unroll
  for (int cc = 0; cc < 2; ++cc) {
    int co = (2 * w + cc) * 16 + (l & 15);
#pragma unroll
    for (int mt = 0; mt < 4; ++mt)
#pragma unroll
      for (int r = 0; r < 4; ++r) {
        int pix = mt * 16 + 4 * (l >> 4) + r;
        if (pix < 49) {
          size_t off = ((size_t)(b * 128) + co) * NKk + p0 + pix;
          y_kf[off] = accY[mt][cc][r];
          skip_kf[off] = accS[mt][cc][r];
        }
      }
  }
}

// ---------- merged SFT + RMSNorm + k-proj (MFMA) ----------

__global__ __launch_bounds__(256) void k_ksft(
    const float* __restrict__ y_kf, const float* __restrict__ skip_kf,
    const float* __restrict__ kf_murs, const float* __restrict__ kgn_murs,
    const _Float16* __restrict__ GB, const _Float16* __restrict__ BBf,
    const _Float16* __restrict__ KPB,
    const float* __restrict__ k_pool, const float* __restrict__ k_proj_b,
    float* __restrict__ kpb) {
  __shared__ __align__(16) _Float16 kfF[8 * 4 * 64 * 4];  // 16KB A-frags
  __shared__ float msL[4][64];
  __shared__ float sMu[8], sRs[8], sGmu[8], sGrs[8];
  int t = threadIdx.x, l = t & 63, w = t >> 6;
  int b = blockIdx.x >> 2, tile = blockIdx.x & 3;
  int p0 = tile * 49;
  if (t < 8) {
    sMu[t] = kf_murs[(b * 8 + t) * 2];
    sRs[t] = kf_murs[(b * 8 + t) * 2 + 1];
    sGmu[t] = kgn_murs[(b * 8 + t) * 2];
    sGrs[t] = kgn_murs[(b * 8 + t) * 2 + 1];
  }
  __syncthreads();
  for (int i = t; i < 128 * 64; i += 256) {
    int c = i >> 6, p = i & 63;
    float v = 0.f;
    if (p < 49) {
      size_t off = ((size_t)(b * 128) + c) * NKk + p0 + p;
      int g = c >> 4;
      v = silu_f((y_kf[off] - sMu[g]) * sRs[g]) + skip_kf[off];
    }
    int kt = c >> 4, kr = c & 15, u = kr >> 2, j = kr & 3, mt = p >> 4;
    kfF[(((kt * 4 + mt) * 64) + (p & 15) + 16 * u) * 4 + j] = (_Float16)v;
  }
  __syncthreads();
  f32x4 z = {0.f, 0.f, 0.f, 0.f};
  f32x4 accG[4][2], accB[4][2];
#pragma unroll
  for (int mt = 0; mt < 4; ++mt)
#pragma unroll
    for (int cc = 0; cc < 2; ++cc) { accG[mt][cc] = z; accB[mt][cc] = z; }
  for (int kt = 0; kt < 8; ++kt) {
    h16x4 a[4];
#pragma unroll
    for (int mt = 0; mt < 4; ++mt)
      a[mt] = *(const h16x4*)&kfF[((kt * 4 + mt) * 64 + l) * 4];
    int fi = (kt * 8 + 2 * w) * 64 + l;
    h16x4 bg0 = *(const h16x4*)(GB + (size_t)fi * 4);
    h16x4 bg1 = *(const h16x4*)(GB + (size_t)(fi + 64) * 4);
    h16x4 bb0 = *(const h16x4*)(BBf + (size_t)fi * 4);
    h16x4 bb1 = *(const h16x4*)(BBf + (size_t)(fi + 64) * 4);
#pragma unroll
    for (int mt = 0; mt < 4; ++mt) {
      accG[mt][0] = mfma16(a[mt], bg0, accG[mt][0]);
      accG[mt][1] = mfma16(a[mt], bg1, accG[mt][1]);
      accB[mt][0] = mfma16(a[mt], bb0, accB[mt][0]);
      accB[mt][1] = mfma16(a[mt], bb1, accB[mt][1]);
    }
  }
  float kfin[4][2][4];
#pragma unroll
  for (int cc = 0; cc < 2; ++cc) {
    int g = 2 * w + cc;
    int co = g * 16 + (l & 15);
    float gmu = sGmu[g], grs = sGrs[g];
#pragma unroll
    for (int mt = 0; mt < 4; ++mt)
#pragma unroll
      for (int r = 0; r < 4; ++r) {
        int pix = mt * 16 + 4 * (l >> 4) + r;
        float v = 0.f;
        if (pix < 49) {
          float kn = (k_pool[((size_t)(b * 128) + co) * NKk + p0 + pix] - gmu) * grs;
          v = fmaf(accG[mt][cc][r], kn, accB[mt][cc][r]);
        }
        kfin[mt][cc][r] = v;
      }
  }
#pragma unroll
  for (int mt = 0; mt < 4; ++mt)
#pragma unroll
    for (int r = 0; r < 4; ++r) {
      float s2 = kfin[mt][0][r] * kfin[mt][0][r] + kfin[mt][1][r] * kfin[mt][1][r];
      for (int m = 1; m < 16; m <<= 1) s2 += __shfl_xor(s2, m);
      if ((l & 15) == 0) msL[w][mt * 16 + 4 * (l >> 4) + r] = s2;
    }
  __syncthreads();
#pragma unroll
  for (int cc = 0; cc < 2; ++cc) {
    int ktn = 2 * w + cc;
    int u = (l & 15) >> 2, j = (l & 15) & 3;
#pragma unroll
    for (int mt = 0; mt < 4; ++mt)
#pragma unroll
      for (int r = 0; r < 4; ++r) {
        int lane = (4 * (l >> 4) + r) + 16 * u;
        kfF[((ktn * 4 + mt) * 64 + lane) * 4 + j] = (_Float16)kfin[mt][cc][r];
      }
  }
  __syncthreads();
  f32x4 accP[4][2];
#pragma unroll
  for (int mt = 0; mt < 4; ++mt)
#pragma unroll
    for (int cc = 0; cc < 2; ++cc) accP[mt][cc] = z;
  for (int kt = 0; kt < 8; ++kt) {
    h16x4 a[4];
#pragma unroll
    for (int mt = 0; mt < 4; ++mt)
      a[mt] = *(const h16x4*)&kfF[((kt * 4 + mt) * 64 + l) * 4];
    int fi = (kt * 8 + 2 * w) * 64 + l;
    h16x4 b0 = *(const h16x4*)(KPB + (size_t)fi * 4);
    h16x4 b1 = *(const h16x4*)(KPB + (size_t)(fi + 64) * 4);
#pragma unroll
    for (int mt = 0; mt < 4; ++mt) {
      accP[mt][0] = mfma16(a[mt], b0, accP[mt][0]);
      accP[mt][1] = mfma16(a[mt], b1, accP[mt][1]);
    }
  }
#pragma unroll
  for (int mt = 0; mt < 4; ++mt)
#pragma unroll
    for (int r = 0; r < 4; ++r) {
      int pix = mt * 16 + 4 * (l >> 4) + r;
      if (pix >= 49) continue;
      float ms = msL[0][pix] + msL[1][pix] + msL[2][pix] + msL[3][pix];
      float rr = rsqrtf(ms * (1.f / 128.f) + EPS_RMS);
#pragma unroll
      for (int cc = 0; cc < 2; ++cc) {
        int co = (2 * w + cc) * 16 + (l & 15);
        kpb[((size_t)(b * 196) + p0 + pix) * 128 + co] =
            accP[mt][cc][r] * rr + k_proj_b[co];
      }
    }
}

// ---------- fused 3x3 conv + RMSNorm + q-proj (MFMA, barrier-free) ----------
// grid = BB*98. Block covers 8 rows x 16 cols of output. Per wave: 2 rows
// (32 px as 2 tiles of 16). Conv weights read from global (L2). After conv,
// wave stages its own result as fp16 A-frags in LDS (wave-local) and runs
// the projection MFMA; RMS scale applied from in-register sumsq.
__global__ __launch_bounds__(256) void k_conv3f(
    const float* __restrict__ q_pool, const float* __restrict__ murs2,
    const _Float16* __restrict__ W3B, const _Float16* __restrict__ QPB,
    const float* __restrict__ bias, float* __restrict__ qp) {
  __shared__ __align__(16) _Float16 qF[8][8][256];  // [tile][kt][lane*4+j] 32KB
  __shared__ float msqL[4][32];                     // [wave][pixel-in-2-rows]
  __shared__ float sMu[8], sRs[8];
  int t = threadIdx.x, l = t & 63, w = t >> 6;
  int b = blockIdx.x / 98, reg = blockIdx.x % 98;
  int y0 = (reg / 7) * 8, x0 = (reg % 7) * 16;
  if (t < 8) { sMu[t] = murs2[(b * 8 + t) * 2]; sRs[t] = murs2[(b * 8 + t) * 2 + 1]; }
  __syncthreads();
  f32x4 z = {0.f, 0.f, 0.f, 0.f};
  f32x4 acc[2][8];
#pragma unroll
  for (int rx = 0; rx < 2; ++rx)
#pragma unroll
    for (int ct = 0; ct < 8; ++ct) acc[rx][ct] = z;
  int lm = l & 15;
  int mrow = lm >> 3, mcol = lm & 7;
  const h16x4* W3 = (const h16x4*)W3B;
  for (int tap = 0; tap < 9; ++tap) {
    int dy = tap / 3 - 1, dx = tap % 3 - 1;
    int py = y0 + 2 * w + mrow + dy;
    int pxb = x0 + mcol + dx;
    bool oky = (py >= 0) && (py < 112);
    const h16x4* wt = W3 + tap * 4096 + l;
#pragma unroll
    for (int kt = 0; kt < 8; ++kt) {
      float mu = sMu[kt], rs = sRs[kt];
      h16x4 a[2];
#pragma unroll
      for (int rx = 0; rx < 2; ++rx) {
        int px = pxb + rx * 8;
        bool ok = oky && (px >= 0) && (px < 112);
        h16x4 ah = {(_Float16)0.f, (_Float16)0.f, (_Float16)0.f, (_Float16)0.f};
        if (ok) {
          f32x4 v = *(const f32x4*)(q_pool + ((size_t)(b * NQ) + py * 112 + px) * 128 +
                                    kt * 16 + 4 * (l >> 4));
#pragma unroll
          for (int j = 0; j < 4; ++j) ah[j] = (_Float16)((v[j] - mu) * rs);
        }
        a[rx] = ah;
      }
#pragma unroll
      for (int ct = 0; ct < 8; ++ct) {
        h16x4 bf = wt[(kt * 8 + ct) * 64];
        acc[0][ct] = mfma16(a[0], bf, acc[0][ct]);
        acc[1][ct] = mfma16(a[1], bf, acc[1][ct]);
      }
    }
  }
  // per-pixel sumsq (full 128 channels) + stage conv result as fp16 A-frags.
  // All LDS traffic below is wave-local: wave w owns tiles 2w, 2w+1 and
  // msqL[w][*]; no block barrier needed.
  int uu = lm >> 2, jj = lm & 3;
#pragma unroll
  for (int rx = 0; rx < 2; ++rx) {
    float sq[4] = {0.f, 0.f, 0.f, 0.f};
#pragma unroll
    for (int ct = 0; ct < 8; ++ct) {
#pragma unroll
      for (int r = 0; r < 4; ++r) sq[r] += acc[rx][ct][r] * acc[rx][ct][r];
      // value (pixel mm = 4*(l>>4)+r, klo = lm) -> frag lane mm+16*(lm>>2), j=lm&3
#pragma unroll
      for (int r = 0; r < 4; ++r) {
        int lane = 4 * (l >> 4) + r + 16 * uu;
        qF[w * 2 + rx][ct][lane * 4 + jj] = (_Float16)acc[rx][ct][r];
      }
    }
#pragma unroll
    for (int r = 0; r < 4; ++r) {
      for (int m = 1; m < 16; m <<= 1) sq[r] += __shfl_xor(sq[r], m);
      if (lm == 0) msqL[w][rx * 16 + 4 * (l >> 4) + r] = sq[r];
    }
  }
  // projection MFMA: A = staged conv frags (own wave's tiles), B = QPB
  f32x4 accP[2][8];
#pragma unroll
  for (int rx = 0; rx < 2; ++rx)
#pragma unroll
    for (int ct = 0; ct < 8; ++ct) accP[rx][ct] = z;
  const h16x4* QP = (const h16x4*)QPB + l;
#pragma unroll
  for (int kt = 0; kt < 8; ++kt) {
    h16x4 a0 = *(const h16x4*)&qF[w * 2][kt][l * 4];
    h16x4 a1 = *(const h16x4*)&qF[w * 2 + 1][kt][l * 4];
#pragma unroll
    for (int ct = 0; ct < 8; ++ct) {
      h16x4 bf = QP[(kt * 8 + ct) * 64];
      accP[0][ct] = mfma16(a0, bf, accP[0][ct]);
      accP[1][ct] = mfma16(a1, bf, accP[1][ct]);
    }
  }
  // epilogue: rr from msqL, write qp[(b*NQ+pix)*128 + ch]
#pragma unroll
  for (int rx = 0; rx < 2; ++rx) {
#pragma unroll
    for (int r = 0; r < 4; ++r) {
      int mm = 4 * (l >> 4) + r;
      float rr = rsqrtf(msqL[w][rx * 16 + mm] * (1.f / 128.f) + EPS_RMS);
      int py = y0 + 2 * w + (mm >> 3), px = x0 + rx * 8 + (mm & 7);
      size_t pb = ((size_t)(b * NQ) + py * 112 + px) * 128;
#pragma unroll
      for (int ct = 0; ct < 8; ++ct) {
        int ch = ct * 16 + lm;
        qp[pb + ch] = accP[rx][ct][r] * rr + bias[ch];
      }
    }
  }
}

// ---------- attention: QK^T + softmax + head-mean -> packed fp16 P ----------

__global__ __launch_bounds__(256) void k_attn1m(
    const float* __restrict__ qp, const float* __restrict__ kpb,
    _Float16* __restrict__ Ph) {
  __shared__ float sP[4][16][212];
  int t = threadIdx.x, l = t & 63, h = t >> 6;
  int b = blockIdx.x / 784, qt = blockIdx.x % 784;
  int q0 = qt * 16;
  constexpr float SC = 0.17677669529663687f;  // 1/sqrt(32)
  h16x4 aq[2];
#pragma unroll
  for (int kt = 0; kt < 2; ++kt) {
    f32x4 v = *(const f32x4*)(qp + ((size_t)(b * NQ) + q0 + (l & 15)) * 128 +
                              h * 32 + kt * 16 + 4 * (l >> 4));
    h16x4 ah;
#pragma unroll
    for (int j = 0; j < 4; ++j) ah[j] = (_Float16)v[j];
    aq[kt] = ah;
  }
  f32x4 z = {0.f, 0.f, 0.f, 0.f};
  f32x4 acc[13];
#pragma unroll
  for (int nt = 0; nt < 13; ++nt) acc[nt] = z;
#pragma unroll
  for (int nt = 0; nt < 13; ++nt) {
    int key = nt * 16 + (l & 15);
    bool ok = key < 196;
#pragma unroll
    for (int kt = 0; kt < 2; ++kt) {
      h16x4 bf = {(_Float16)0.f, (_Float16)0.f, (_Float16)0.f, (_Float16)0.f};
      if (ok) {
        f32x4 v = *(const f32x4*)(kpb + ((size_t)(b * 196) + key) * 128 +
                                  h * 32 + kt * 16 + 4 * (l >> 4));
#pragma unroll
        for (int j = 0; j < 4; ++j) bf[j] = (_Float16)v[j];
      }
      acc[nt] = mfma16(aq[kt], bf, acc[nt]);
    }
  }
#pragma unroll
  for (int r = 0; r < 4; ++r) {
    float mx = -3e38f;
#pragma unroll
    for (int nt = 0; nt < 13; ++nt) {
      bool ok = nt * 16 + (l & 15) < 196;
      float v = ok ? acc[nt][r] * SC : -3e38f;
      acc[nt][r] = v;
      mx = fmaxf(mx, v);
    }
    for (int m = 1; m < 16; m <<= 1) mx = fmaxf(mx, __shfl_xor(mx, m));
    float sum = 0.f;
#pragma unroll
    for (int nt = 0; nt < 13; ++nt) {
      bool ok = nt * 16 + (l & 15) < 196;
      float e = ok ? __expf(acc[nt][r] - mx) : 0.f;
      acc[nt][r] = e;
      sum += e;
    }
    for (int m = 1; m < 16; m <<= 1) sum += __shfl_xor(sum, m);
    float inv = 1.f / sum;
#pragma unroll
    for (int nt = 0; nt < 13; ++nt)
      sP[h][4 * (l >> 4) + r][nt * 16 + (l & 15)] = acc[nt][r] * inv;
  }
  __syncthreads();
  _Float16* pb = Ph + (size_t)(b * 784 + qt) * 13 * 256;
  for (int i = t; i < 832; i += 256) {
    int kt = i >> 6, ll = i & 63;
    int q = ll & 15, kb = kt * 16 + 4 * (ll >> 4);
    h16x4 v;
#pragma unroll
    for (int j = 0; j < 4; ++j) {
      int k = kb + j;
      float s = 0.25f * (sP[0][q][k] + sP[1][q][k] + sP[2][q][k] + sP[3][q][k]);
      v[j] = (_Float16)s;
    }
    *(h16x4*)(pb + (size_t)i * 4) = v;
  }
}

// ---------- attention PV: pure fragment streaming, no LDS ----------

__global__ __launch_bounds__(256) void k_attn2m(
    const _Float16* __restrict__ Ph, const _Float16* __restrict__ featB,
    float* __restrict__ out) {
  int t = threadIdx.x, l = t & 63, w = t >> 6;
  int b = blockIdx.x / 196, qt = blockIdx.x % 196;
  int q16 = qt * 4 + w;
  f32x4 z = {0.f, 0.f, 0.f, 0.f};
  f32x4 acc[24];
#pragma unroll
  for (int dt = 0; dt < 24; ++dt) acc[dt] = z;
  const h16x4* PB = (const h16x4*)Ph + ((size_t)(b * 784 + q16) * 13) * 64 + l;
  const h16x4* FB = (const h16x4*)featB + (size_t)b * 13 * 24 * 64 + l;
  for (int kt = 0; kt < 13; ++kt) {
    h16x4 bp = PB[kt * 64];
    const h16x4* fb = FB + kt * 24 * 64;
#pragma unroll
    for (int dt = 0; dt < 24; ++dt)
      acc[dt] = mfma16(fb[(size_t)dt * 64], bp, acc[dt]);
  }
  int qg = q16 * 16 + (l & 15);
#pragma unroll
  for (int dt = 0; dt < 24; ++dt)
#pragma unroll
    for (int r = 0; r < 4; ++r) {
      int d = dt * 16 + 4 * (l >> 4) + r;
      out[((size_t)(b * 384) + d) * NQ + qg] = acc[dt][r];
    }
}

}  // namespace

extern "C" void kernel_launch(void* const* d_in, const int* in_sizes, int n_in,
                              void* d_out, int out_size, void* d_ws,
                              size_t ws_size, hipStream_t stream) {
  (void)in_sizes; (void)n_in; (void)out_size; (void)ws_size;
  const float* image        = (const float*)d_in[0];
  const float* features     = (const float*)d_in[1];
  const float* rope_f       = (const float*)d_in[2];
  const float* img_conv_w   = (const float*)d_in[3];
  const float* img_proj_w   = (const float*)d_in[4];
  const float* qenc_w       = (const float*)d_in[5];
  const float* kenc_w       = (const float*)d_in[6];
  const float* kfeat_conv_w = (const float*)d_in[7];
  const float* kfeat_proj_w = (const float*)d_in[8];
  const float* sft_gamma_w  = (const float*)d_in[9];
  const float* sft_beta_w   = (const float*)d_in[10];
  const float* block_conv_w = (const float*)d_in[11];
  const float* rms_q_w      = (const float*)d_in[12];
  const float* rms_k_w      = (const float*)d_in[13];
  const float* q_proj_w     = (const float*)d_in[14];
  const float* q_proj_b     = (const float*)d_in[15];
  const float* k_proj_w     = (const float*)d_in[16];
  const float* k_proj_b     = (const float*)d_in[17];
  float* out = (float*)d_out;
  float* ws = (float*)d_ws;

  size_t off = 0;
  auto alloc = [&](size_t n) {
    size_t r = off;
    off += (n + 63) & ~(size_t)63;
    return r;
  };
  _Float16* WqB  = (_Float16*)(ws + alloc(8192));
  _Float16* WkB  = (_Float16*)(ws + alloc(8192));
  _Float16* QPB  = (_Float16*)(ws + alloc(8192));
  _Float16* W3B  = (_Float16*)(ws + alloc(73728));
  _Float16* KFB  = (_Float16*)(ws + alloc(24576));
  _Float16* KFPB = (_Float16*)(ws + alloc(24576));
  _Float16* GB   = (_Float16*)(ws + alloc(8192));
  _Float16* BBf  = (_Float16*)(ws + alloc(8192));
  _Float16* KPB  = (_Float16*)(ws + alloc(8192));
  float* cosT     = ws + alloc(14336);
  float* sinT     = ws + alloc(14336);
  _Float16* featB = (_Float16*)(ws + alloc(159744));
  float* imgpart  = ws + alloc(2304);
  float* img_murs = ws + alloc(64);
  float* qk_murs  = ws + alloc(128);
  float* murs2    = ws + alloc(64);
  float* kgn_murs = ws + alloc(64);
  float* kf_murs  = ws + alloc(64);
  float* G        = ws + alloc(65536);
  float* mvec     = ws + alloc(512);
  float* mpart    = ws + alloc(392 * 128);
  float* Qpart    = ws + alloc((size_t)BB * 784 * 16);
  float* kpp      = ws + alloc((size_t)BB * 784 * 128);
  float* y_kf     = ws + alloc(100352);
  float* skip_kf  = ws + alloc(100352);
  float* k_pool   = ws + alloc(100352);
  float* kpb      = ws + alloc(100352);
  // RA (25.7MB): Gpart -> q_pool
  float* RA = ws + alloc((size_t)BB * NQ * 128);
  // ENC (51.4MB): encF -> (qp, Ph)
  float* ENCp = ws + alloc((size_t)BB * 784 * 8192 / 2);
  float* Gpart  = RA;
  float* q_pool = RA;
  _Float16* encF = (_Float16*)ENCp;
  float* qp      = ENCp;                                      // after encF dead
  _Float16* Ph   = (_Float16*)(ENCp + (size_t)BB * NQ * 128); // after qp

  k_prep<<<2648, 256, 0, stream>>>(qenc_w, kenc_w, q_proj_w, rms_q_w,
                                   block_conv_w, kfeat_conv_w, kfeat_proj_w,
                                   sft_gamma_w, sft_beta_w, k_proj_w, rms_k_w,
                                   rope_f, features,
                                   WqB, WkB, QPB, W3B, KFB, KFPB, GB, BBf, KPB,
                                   cosT, sinT, featB);

  k_imgstat1<<<BB * 64, 256, 0, stream>>>(image, imgpart);
  k_imgstat2<<<BB, 128, 0, stream>>>(imgpart, img_conv_w, img_murs);

  k_kf<<<BB * 4, 256, 0, stream>>>(features, KFB, KFPB, y_kf, skip_kf);
  k_gnstats<<<32, 256, 0, stream>>>(y_kf, kf_murs, NKk, EPS_GN);

  k_gram<<<BB * 98, 256, 0, stream>>>(image, cosT, sinT, img_conv_w,
                                      img_proj_w, img_murs, encF, Gpart, mpart);
  k_gred<<<BB * 64, 256, 0, stream>>>(Gpart, mpart, G, mvec);
  k_gstats<<<64, 256, 0, stream>>>(G, mvec, qenc_w, kenc_w, qk_murs);

  k_passA2<<<BB * 784, 256, 0, stream>>>(encF, qk_murs, WqB, WkB,
                                         q_pool, kpp, Qpart);
  k_qstatfin<<<32, 256, 0, stream>>>(Qpart, murs2);
  k_kpred<<<392, 256, 0, stream>>>(kpp, k_pool);
  k_gnstats<<<32, 256, 0, stream>>>(k_pool, kgn_murs, NKk, EPS_GN);

  k_ksft<<<BB * 4, 256, 0, stream>>>(y_kf, skip_kf, kf_murs, kgn_murs,
                                     GB, BBf, KPB, k_pool, k_proj_b, kpb);

  // fused 3x3 conv + RMS + q-proj (writes qp into ENC region; encF is dead)
  k_conv3f<<<BB * 98, 256, 0, stream>>>(q_pool, murs2, W3B, QPB, q_proj_b, qp);

  k_attn1m<<<BB * 784, 256, 0, stream>>>(qp, kpb, Ph);
  k_attn2m<<<BB * 196, 256, 0, stream>>>(Ph, featB, out);
}